// Round 1
// baseline (4035.197 us; speedup 1.0000x reference)
//
#include <hip/hip_runtime.h>
#include <cstdint>
#include <cstddef>

#define B_ 2
#define T_ 2048
#define D_ 1024
#define H_ 16
#define HD_ 64

// ---------------- GEMM: C[M,N] = A[M,K] @ B[N,K]^T  (fp32) ----------------
__global__ __launch_bounds__(256) void gemm128(const float* __restrict__ A,
    const float* __restrict__ Bw, float* __restrict__ C, int M, int N, int K)
{
  __shared__ float As[16][132];
  __shared__ float Bs[16][132];
  const int tid = threadIdx.x;
  const int row0 = blockIdx.x * 128;
  const int col0 = blockIdx.y * 128;
  const int lr = tid >> 1;          // 0..127 tile row
  const int lk = (tid & 1) << 3;    // 0 or 8
  const float* Ap = A + (size_t)(row0 + lr) * K + lk;
  const float* Bp = Bw + (size_t)(col0 + lr) * K + lk;
  const int tx = tid & 15, ty = tid >> 4;

  float acc[8][8];
  #pragma unroll
  for (int i = 0; i < 8; ++i)
    #pragma unroll
    for (int j = 0; j < 8; ++j) acc[i][j] = 0.f;

  float4 a0 = *(const float4*)(Ap);
  float4 a1 = *(const float4*)(Ap + 4);
  float4 b0 = *(const float4*)(Bp);
  float4 b1 = *(const float4*)(Bp + 4);

  const int KT = K >> 4;
  for (int t0 = 0; t0 < KT; ++t0) {
    As[lk+0][lr]=a0.x; As[lk+1][lr]=a0.y; As[lk+2][lr]=a0.z; As[lk+3][lr]=a0.w;
    As[lk+4][lr]=a1.x; As[lk+5][lr]=a1.y; As[lk+6][lr]=a1.z; As[lk+7][lr]=a1.w;
    Bs[lk+0][lr]=b0.x; Bs[lk+1][lr]=b0.y; Bs[lk+2][lr]=b0.z; Bs[lk+3][lr]=b0.w;
    Bs[lk+4][lr]=b1.x; Bs[lk+5][lr]=b1.y; Bs[lk+6][lr]=b1.z; Bs[lk+7][lr]=b1.w;
    __syncthreads();
    if (t0 + 1 < KT) {
      const float* Ap2 = Ap + (size_t)(t0 + 1) * 16;
      const float* Bp2 = Bp + (size_t)(t0 + 1) * 16;
      a0 = *(const float4*)(Ap2); a1 = *(const float4*)(Ap2 + 4);
      b0 = *(const float4*)(Bp2); b1 = *(const float4*)(Bp2 + 4);
    }
    #pragma unroll
    for (int k = 0; k < 16; ++k) {
      float4 af0 = *(const float4*)&As[k][ty*8];
      float4 af1 = *(const float4*)&As[k][ty*8+4];
      float4 bf0 = *(const float4*)&Bs[k][tx*8];
      float4 bf1 = *(const float4*)&Bs[k][tx*8+4];
      float av[8] = {af0.x,af0.y,af0.z,af0.w,af1.x,af1.y,af1.z,af1.w};
      float bv[8] = {bf0.x,bf0.y,bf0.z,bf0.w,bf1.x,bf1.y,bf1.z,bf1.w};
      #pragma unroll
      for (int i = 0; i < 8; ++i)
        #pragma unroll
        for (int j = 0; j < 8; ++j) acc[i][j] = fmaf(av[i], bv[j], acc[i][j]);
    }
    __syncthreads();
  }
  #pragma unroll
  for (int i = 0; i < 8; ++i) {
    size_t r = (size_t)(row0 + ty*8 + i) * N + col0 + tx*8;
    float4 c0 = {acc[i][0],acc[i][1],acc[i][2],acc[i][3]};
    float4 c1 = {acc[i][4],acc[i][5],acc[i][6],acc[i][7]};
    *(float4*)(C + r)     = c0;
    *(float4*)(C + r + 4) = c1;
  }
}

// ---------------- beta / g small projections ----------------
__global__ __launch_bounds__(256) void smallproj(const float* __restrict__ Hs,
    const float* __restrict__ Wa, const float* __restrict__ Wb,
    const float* __restrict__ Alog, const float* __restrict__ dtb,
    float* __restrict__ Gout, float* __restrict__ Bout)
{
  __shared__ float hs[D_];
  const int bt = blockIdx.x;
  for (int i = threadIdx.x; i < D_; i += 256) hs[i] = Hs[(size_t)bt * D_ + i];
  __syncthreads();
  const int grp = threadIdx.x >> 3, p = threadIdx.x & 7;
  const int head = grp & 15, which = grp >> 4;   // 0 -> Wa/g, 1 -> Wb/beta
  const float* Wr = (which ? Wb : Wa) + head * D_;
  float s = 0.f;
  for (int i = p; i < D_; i += 8) s = fmaf(hs[i], Wr[i], s);
  s += __shfl_xor(s, 1); s += __shfl_xor(s, 2); s += __shfl_xor(s, 4);
  if (p == 0) {
    if (which) {
      Bout[(size_t)bt * H_ + head] = 1.f / (1.f + __expf(-s));
    } else {
      float x = s + dtb[head];
      float sp = fmaxf(x, 0.f) + log1pf(__expf(-fabsf(x)));  // stable softplus
      Gout[(size_t)bt * H_ + head] = -__expf(Alog[head]) * sp;
    }
  }
}

// ---------------- causal depthwise conv (K=4) + SiLU ----------------
__global__ __launch_bounds__(256) void conv_silu(const float* __restrict__ X,
    const float* __restrict__ W, float* __restrict__ Y)
{
  const size_t idx = (size_t)blockIdx.x * 256 + threadIdx.x;
  if (idx >= (size_t)B_ * T_ * D_) return;
  const int c = (int)(idx & (D_ - 1));
  const int t = (int)((idx >> 10) & (T_ - 1));
  const float4 w = *(const float4*)(W + c * 4);  // w[c][0..3]
  float acc = w.w * X[idx];                      // j=3 -> x[t]
  if (t >= 1) acc = fmaf(w.z, X[idx - D_],     acc);
  if (t >= 2) acc = fmaf(w.y, X[idx - 2*D_],   acc);
  if (t >= 3) acc = fmaf(w.x, X[idx - 3*D_],   acc);
  Y[idx] = acc / (1.f + __expf(-acc));           // SiLU
}

// ---------------- per-head RMSNorm then L2-norm (in-place) ----------------
__global__ __launch_bounds__(256) void headnorm(float* __restrict__ X,
    const float* __restrict__ w, float fs)
{
  const size_t gid = (size_t)blockIdx.x * 256 + threadIdx.x;
  if (gid >= (size_t)B_ * T_ * D_) return;
  const size_t vec = gid >> 6;
  const int lane = threadIdx.x & 63;
  float x = X[vec * 64 + lane];
  float ss = x * x;
  #pragma unroll
  for (int m = 1; m < 64; m <<= 1) ss += __shfl_xor(ss, m);
  float y = x * rsqrtf(ss * (1.f/64.f) + 1e-6f) * w[lane];
  float s2 = y * y;
  #pragma unroll
  for (int m = 1; m < 64; m <<= 1) s2 += __shfl_xor(s2, m);
  X[vec * 64 + lane] = y * rsqrtf(s2 + 1e-6f) * fs;
}

// ---------------- sequential gated delta-rule scan ----------------
// one wave per (b,h); lane = value-dim column v; S[64] = rows of that column
__global__ __launch_bounds__(64) void scan_kernel(
    const float* __restrict__ Qn, const float* __restrict__ Kn,
    const float* __restrict__ Vc, const float* __restrict__ Gg,
    const float* __restrict__ Bb, float* __restrict__ O)
{
  const int bh = blockIdx.x;           // 0..B*H-1
  const int lane = threadIdx.x;        // column v
  const size_t tbase0 = (size_t)(bh >> 4) * (size_t)T_ * H_ + (bh & 15);
  float S[64];
  #pragma unroll
  for (int j = 0; j < 64; ++j) S[j] = 0.f;

  size_t rb = tbase0;
  float gt = Gg[rb], bt = Bb[rb], vt = Vc[rb * 64 + lane];
  for (int t = 0; t < T_; ++t) {
    const size_t base = rb * 64;
    // prefetch next step's per-lane/scalar inputs
    float gt_n = 0.f, bt_n = 0.f, vt_n = 0.f;
    const size_t rb_n = rb + H_;
    if (t + 1 < T_) { gt_n = Gg[rb_n]; bt_n = Bb[rb_n]; vt_n = Vc[rb_n * 64 + lane]; }

    const float eg = __expf(gt);
    float kv0 = 0.f, kv1 = 0.f, kv2 = 0.f, kv3 = 0.f;
    #pragma unroll
    for (int j = 0; j < 64; j += 4) {
      float k0 = Kn[base+j], k1 = Kn[base+j+1], k2 = Kn[base+j+2], k3 = Kn[base+j+3];
      S[j]   *= eg; S[j+1] *= eg; S[j+2] *= eg; S[j+3] *= eg;
      kv0 = fmaf(k0, S[j],   kv0); kv1 = fmaf(k1, S[j+1], kv1);
      kv2 = fmaf(k2, S[j+2], kv2); kv3 = fmaf(k3, S[j+3], kv3);
    }
    const float kv = (kv0 + kv1) + (kv2 + kv3);
    const float delta = (vt - kv) * bt;

    float o0 = 0.f, o1 = 0.f, o2 = 0.f, o3 = 0.f;
    #pragma unroll
    for (int j = 0; j < 64; j += 4) {
      float k0 = Kn[base+j], k1 = Kn[base+j+1], k2 = Kn[base+j+2], k3 = Kn[base+j+3];
      float q0 = Qn[base+j], q1 = Qn[base+j+1], q2 = Qn[base+j+2], q3 = Qn[base+j+3];
      S[j]   = fmaf(k0, delta, S[j]);   o0 = fmaf(q0, S[j],   o0);
      S[j+1] = fmaf(k1, delta, S[j+1]); o1 = fmaf(q1, S[j+1], o1);
      S[j+2] = fmaf(k2, delta, S[j+2]); o2 = fmaf(q2, S[j+2], o2);
      S[j+3] = fmaf(k3, delta, S[j+3]); o3 = fmaf(q3, S[j+3], o3);
    }
    O[base + lane] = (o0 + o1) + (o2 + o3);   // scale folded into q

    rb = rb_n; gt = gt_n; bt = bt_n; vt = vt_n;
  }
}

// ---------------- o-norm * swish(gv) ----------------
__global__ __launch_bounds__(256) void ogate(const float* __restrict__ O,
    const float* __restrict__ GV, const float* __restrict__ w,
    float* __restrict__ OG)
{
  const size_t gid = (size_t)blockIdx.x * 256 + threadIdx.x;
  if (gid >= (size_t)B_ * T_ * D_) return;
  const size_t vec = gid >> 6;
  const int lane = threadIdx.x & 63;
  float x = O[vec * 64 + lane];
  float ss = x * x;
  #pragma unroll
  for (int m = 1; m < 64; m <<= 1) ss += __shfl_xor(ss, m);
  float y = x * rsqrtf(ss * (1.f/64.f) + 1e-6f) * w[lane];
  float gv = GV[vec * 64 + lane];
  OG[vec * 64 + lane] = y * gv / (1.f + __expf(-gv));
}

extern "C" void kernel_launch(void* const* d_in, const int* in_sizes, int n_in,
                              void* d_out, int out_size, void* d_ws, size_t ws_size,
                              hipStream_t stream) {
  const float* h    = (const float*)d_in[0];
  const float* Wq   = (const float*)d_in[1];
  const float* Wk   = (const float*)d_in[2];
  const float* Wv   = (const float*)d_in[3];
  const float* Wa   = (const float*)d_in[4];
  const float* Wb   = (const float*)d_in[5];
  const float* Wg   = (const float*)d_in[6];
  const float* Wo   = (const float*)d_in[7];
  const float* qnw  = (const float*)d_in[8];
  const float* knw  = (const float*)d_in[9];
  const float* onw  = (const float*)d_in[10];
  const float* Alog = (const float*)d_in[11];
  const float* dtb  = (const float*)d_in[12];
  const float* cqw  = (const float*)d_in[13];
  const float* ckw  = (const float*)d_in[14];
  const float* cvw  = (const float*)d_in[15];
  float* out = (float*)d_out;
  float* ws  = (float*)d_ws;

  const size_t NB = (size_t)B_ * T_ * D_;     // 4,194,304 elements
  float* qp  = ws;
  float* kp  = ws + 1*NB;
  float* vp  = ws + 2*NB;
  float* gvp = ws + 3*NB;
  float* qc  = ws + 4*NB;
  float* kc  = ws + 5*NB;
  float* vc  = ws + 6*NB;
  float* og  = ws + 7*NB;
  float* gb  = ws + 8*NB;                     // [B,T,H]
  float* bb  = gb + (size_t)B_ * T_ * H_;     // [B,T,H]

  const int M = B_ * T_;                      // 4096
  dim3 gg(M / 128, D_ / 128);                 // (32, 8)
  const int EW = (int)(NB / 256);             // elementwise grid = 16384

  gemm128<<<gg, 256, 0, stream>>>(h, Wq, qp, M, D_, D_);
  gemm128<<<gg, 256, 0, stream>>>(h, Wk, kp, M, D_, D_);
  gemm128<<<gg, 256, 0, stream>>>(h, Wv, vp, M, D_, D_);
  gemm128<<<gg, 256, 0, stream>>>(h, Wg, gvp, M, D_, D_);
  smallproj<<<B_ * T_, 256, 0, stream>>>(h, Wa, Wb, Alog, dtb, gb, bb);

  conv_silu<<<EW, 256, 0, stream>>>(qp, cqw, qc);
  conv_silu<<<EW, 256, 0, stream>>>(kp, ckw, kc);
  conv_silu<<<EW, 256, 0, stream>>>(vp, cvw, vc);

  headnorm<<<EW, 256, 0, stream>>>(qc, qnw, 0.125f);  // fold HD^-0.5 into q
  headnorm<<<EW, 256, 0, stream>>>(kc, knw, 1.0f);

  scan_kernel<<<B_ * H_, 64, 0, stream>>>(qc, kc, vc, gb, bb, out);

  ogate<<<EW, 256, 0, stream>>>(out, gvp, onw, og);
  gemm128<<<gg, 256, 0, stream>>>(og, Wo, out, M, D_, D_);
}

// Round 2
// 1072.770 us; speedup vs baseline: 3.7615x; 3.7615x over previous
//
#include <hip/hip_runtime.h>
#include <cstdint>
#include <cstddef>

#define B_ 2
#define T_ 2048
#define D_ 1024
#define H_ 16
#define HD_ 64
#define NC_ 32

__device__ __forceinline__ float dot4(float4 a, float4 b, float acc) {
  return fmaf(a.x, b.x, fmaf(a.y, b.y, fmaf(a.z, b.z, fmaf(a.w, b.w, acc))));
}

// ---------------- GEMM: C[M,N] = A[M,K] @ B[N,K]^T  (fp32) ----------------
__global__ __launch_bounds__(256) void gemm128(const float* __restrict__ A,
    const float* __restrict__ Bw, float* __restrict__ C, int M, int N, int K)
{
  __shared__ float As[16][132];
  __shared__ float Bs[16][132];
  const int tid = threadIdx.x;
  const int row0 = blockIdx.x * 128;
  const int col0 = blockIdx.y * 128;
  const int lr = tid >> 1;
  const int lk = (tid & 1) << 3;
  const float* Ap = A + (size_t)(row0 + lr) * K + lk;
  const float* Bp = Bw + (size_t)(col0 + lr) * K + lk;
  const int tx = tid & 15, ty = tid >> 4;

  float acc[8][8];
  #pragma unroll
  for (int i = 0; i < 8; ++i)
    #pragma unroll
    for (int j = 0; j < 8; ++j) acc[i][j] = 0.f;

  float4 a0 = *(const float4*)(Ap);
  float4 a1 = *(const float4*)(Ap + 4);
  float4 b0 = *(const float4*)(Bp);
  float4 b1 = *(const float4*)(Bp + 4);

  const int KT = K >> 4;
  for (int t0 = 0; t0 < KT; ++t0) {
    As[lk+0][lr]=a0.x; As[lk+1][lr]=a0.y; As[lk+2][lr]=a0.z; As[lk+3][lr]=a0.w;
    As[lk+4][lr]=a1.x; As[lk+5][lr]=a1.y; As[lk+6][lr]=a1.z; As[lk+7][lr]=a1.w;
    Bs[lk+0][lr]=b0.x; Bs[lk+1][lr]=b0.y; Bs[lk+2][lr]=b0.z; Bs[lk+3][lr]=b0.w;
    Bs[lk+4][lr]=b1.x; Bs[lk+5][lr]=b1.y; Bs[lk+6][lr]=b1.z; Bs[lk+7][lr]=b1.w;
    __syncthreads();
    if (t0 + 1 < KT) {
      const float* Ap2 = Ap + (size_t)(t0 + 1) * 16;
      const float* Bp2 = Bp + (size_t)(t0 + 1) * 16;
      a0 = *(const float4*)(Ap2); a1 = *(const float4*)(Ap2 + 4);
      b0 = *(const float4*)(Bp2); b1 = *(const float4*)(Bp2 + 4);
    }
    #pragma unroll
    for (int k = 0; k < 16; ++k) {
      float4 af0 = *(const float4*)&As[k][ty*8];
      float4 af1 = *(const float4*)&As[k][ty*8+4];
      float4 bf0 = *(const float4*)&Bs[k][tx*8];
      float4 bf1 = *(const float4*)&Bs[k][tx*8+4];
      float av[8] = {af0.x,af0.y,af0.z,af0.w,af1.x,af1.y,af1.z,af1.w};
      float bv[8] = {bf0.x,bf0.y,bf0.z,bf0.w,bf1.x,bf1.y,bf1.z,bf1.w};
      #pragma unroll
      for (int i = 0; i < 8; ++i)
        #pragma unroll
        for (int j = 0; j < 8; ++j) acc[i][j] = fmaf(av[i], bv[j], acc[i][j]);
    }
    __syncthreads();
  }
  #pragma unroll
  for (int i = 0; i < 8; ++i) {
    size_t r = (size_t)(row0 + ty*8 + i) * N + col0 + tx*8;
    float4 c0 = {acc[i][0],acc[i][1],acc[i][2],acc[i][3]};
    float4 c1 = {acc[i][4],acc[i][5],acc[i][6],acc[i][7]};
    *(float4*)(C + r)     = c0;
    *(float4*)(C + r + 4) = c1;
  }
}

// ---------------- beta / g small projections ----------------
__global__ __launch_bounds__(256) void smallproj(const float* __restrict__ Hs,
    const float* __restrict__ Wa, const float* __restrict__ Wb,
    const float* __restrict__ Alog, const float* __restrict__ dtb,
    float* __restrict__ Gout, float* __restrict__ Bout)
{
  __shared__ float hs[D_];
  const int bt = blockIdx.x;
  for (int i = threadIdx.x; i < D_; i += 256) hs[i] = Hs[(size_t)bt * D_ + i];
  __syncthreads();
  const int grp = threadIdx.x >> 3, p = threadIdx.x & 7;
  const int head = grp & 15, which = grp >> 4;
  const float* Wr = (which ? Wb : Wa) + head * D_;
  float s = 0.f;
  for (int i = p; i < D_; i += 8) s = fmaf(hs[i], Wr[i], s);
  s += __shfl_xor(s, 1); s += __shfl_xor(s, 2); s += __shfl_xor(s, 4);
  if (p == 0) {
    if (which) {
      Bout[(size_t)bt * H_ + head] = 1.f / (1.f + __expf(-s));
    } else {
      float x = s + dtb[head];
      float sp = fmaxf(x, 0.f) + log1pf(__expf(-fabsf(x)));
      Gout[(size_t)bt * H_ + head] = -__expf(Alog[head]) * sp;
    }
  }
}

// ---------------- causal depthwise conv (K=4) + SiLU ----------------
__global__ __launch_bounds__(256) void conv_silu(const float* __restrict__ X,
    const float* __restrict__ W, float* __restrict__ Y)
{
  const size_t idx = (size_t)blockIdx.x * 256 + threadIdx.x;
  if (idx >= (size_t)B_ * T_ * D_) return;
  const int c = (int)(idx & (D_ - 1));
  const int t = (int)((idx >> 10) & (T_ - 1));
  const float4 w = *(const float4*)(W + c * 4);
  float acc = w.w * X[idx];
  if (t >= 1) acc = fmaf(w.z, X[idx - D_],     acc);
  if (t >= 2) acc = fmaf(w.y, X[idx - 2*D_],   acc);
  if (t >= 3) acc = fmaf(w.x, X[idx - 3*D_],   acc);
  Y[idx] = acc / (1.f + __expf(-acc));
}

// ---------------- per-head RMSNorm then L2-norm (in-place) ----------------
__global__ __launch_bounds__(256) void headnorm(float* __restrict__ X,
    const float* __restrict__ w, float fs)
{
  const size_t gid = (size_t)blockIdx.x * 256 + threadIdx.x;
  if (gid >= (size_t)B_ * T_ * D_) return;
  const size_t vec = gid >> 6;
  const int lane = threadIdx.x & 63;
  float x = X[vec * 64 + lane];
  float ss = x * x;
  #pragma unroll
  for (int m = 1; m < 64; m <<= 1) ss += __shfl_xor(ss, m);
  float y = x * rsqrtf(ss * (1.f/64.f) + 1e-6f) * w[lane];
  float s2 = y * y;
  #pragma unroll
  for (int m = 1; m < 64; m <<= 1) s2 += __shfl_xor(s2, m);
  X[vec * 64 + lane] = y * rsqrtf(s2 + 1e-6f) * fs;
}

// ---------------- P1: per-chunk A, triangular solve -> U, W ----------------
// U = (I+A)^-1 (beta*V), W = (I+A)^-1 (beta*b_t*K); A[t][s]=beta_t e^{gc_t-gc_s} k_t.k_s (s<t)
__global__ __launch_bounds__(256) void p1_chunk(
    const float* __restrict__ Kc, const float* __restrict__ Vc,
    const float* __restrict__ Gg, const float* __restrict__ Bb,
    float* __restrict__ Ubuf, float* __restrict__ Wbuf, float* __restrict__ Gcum)
{
  __shared__ float Ks[64][68];
  __shared__ float Am[64][68];
  __shared__ float XT[128][68];   // XT[col][t]; cols 0..63 = U-rhs, 64..127 = W-rhs
  __shared__ float gc[64], bet[64];
  const int bhc = blockIdx.x;
  const int bh = bhc >> 5, c = bhc & 31;
  const int b = bh >> 4, h = bh & 15;
  const int tid = threadIdx.x;
  const size_t rowbase = ((size_t)b*T_ + c*64)*H_ + h;

  if (tid < 64) {
    float gv = Gg[rowbase + (size_t)tid*H_];
    #pragma unroll
    for (int off = 1; off < 64; off <<= 1) {
      float up = __shfl_up(gv, off, 64);
      if (tid >= off) gv += up;
    }
    gc[tid] = gv;
    Gcum[(size_t)bhc*64 + tid] = gv;
    bet[tid] = Bb[rowbase + (size_t)tid*H_];
  }
  for (int e = tid; e < 4096; e += 256) {
    int t = e >> 6, d = e & 63;
    Ks[t][d] = Kc[(rowbase + (size_t)t*H_)*64 + d];
  }
  __syncthreads();

  // A[t][s]
  {
    const int t = tid & 63, s0 = (tid >> 6) << 4;
    float acc[16];
    #pragma unroll
    for (int m = 0; m < 16; ++m) acc[m] = 0.f;
    for (int i = 0; i < 64; i += 4) {
      float4 kt = *(const float4*)&Ks[t][i];
      #pragma unroll
      for (int m = 0; m < 16; ++m) {
        float4 ks = *(const float4*)&Ks[s0+m][i];
        acc[m] = dot4(kt, ks, acc[m]);
      }
    }
    const float bt = bet[t], gt = gc[t];
    #pragma unroll
    for (int m = 0; m < 16; ++m) {
      int s = s0 + m;
      Am[t][s] = (s < t) ? bt * __expf(gt - gc[s]) * acc[m] : 0.f;
    }
  }
  // rhs fill
  for (int e = tid; e < 4096; e += 256) {
    int t = e >> 6, j = e & 63;
    float btv = bet[t];
    XT[j][t]    = btv * Vc[(rowbase + (size_t)t*H_)*64 + j];
    XT[64+j][t] = btv * __expf(gc[t]) * Ks[t][j];
  }
  __syncthreads();

  // forward substitution per column (zero-padded A rows make quad loop safe)
  if (tid < 128) {
    for (int t = 1; t < 64; ++t) {
      float a0=0,a1=0,a2=0,a3=0;
      const int qmax = t >> 2;
      for (int q = 0; q <= qmax; ++q) {
        float4 av = *(const float4*)&Am[t][q*4];
        float4 xv = *(const float4*)&XT[tid][q*4];
        a0 = fmaf(av.x, xv.x, a0);
        a1 = fmaf(av.y, xv.y, a1);
        a2 = fmaf(av.z, xv.z, a2);
        a3 = fmaf(av.w, xv.w, a3);
      }
      XT[tid][t] -= (a0+a1)+(a2+a3);
    }
  }
  __syncthreads();
  for (int e = tid; e < 4096; e += 256) {
    int t = e >> 6, j = e & 63;
    Ubuf[(size_t)bhc*4096 + e] = XT[j][t];
    Wbuf[(size_t)bhc*4096 + e] = XT[64+j][t];
  }
}

// ---------------- P2: sequential inter-chunk state; split by value-dim ----------------
// grid = 32 bh * 4 j-slices; S0buf/Dbuf stored [bhc][j][i-or-t] (j-major)
__global__ __launch_bounds__(256) void p2_state(
    const float* __restrict__ Kc, const float* __restrict__ Gcum,
    const float* __restrict__ Ubuf, const float* __restrict__ Wbuf,
    float* __restrict__ S0buf, float* __restrict__ Dbuf)
{
  __shared__ float SsT[16][68];   // SsT[jj][i] = S[i][j0+jj]
  __shared__ float DsT[16][68];   // DsT[jj][t] = delta[t][j0+jj]
  __shared__ float KscT[64][68];  // KscT[i][t] = e^{gC-gc_t} k_t[i]
  __shared__ float Wls[64][68];   // W[t][i]
  __shared__ float gcs[64];
  const int bh = blockIdx.x >> 2;
  const int j0 = (blockIdx.x & 3) << 4;
  const int b = bh >> 4, h = bh & 15;
  const int tid = threadIdx.x;
  const int jj = tid & 15, tq = tid >> 4;

  for (int e = tid; e < 16*68; e += 256) ((float*)SsT)[e] = 0.f;

  for (int c = 0; c < NC_; ++c) {
    const int bhc = bh * NC_ + c;
    const size_t rowbase = ((size_t)b*T_ + c*64)*H_ + h;
    if (tid < 64) gcs[tid] = Gcum[(size_t)bhc*64 + tid];
    __syncthreads();
    const float gC = gcs[63];
    for (int e = tid; e < 4096; e += 256) {
      int t = e >> 6, i = e & 63;
      float kv = Kc[(rowbase + (size_t)t*H_)*64 + i];
      KscT[i][t] = __expf(gC - gcs[t]) * kv;
      Wls[t][i] = Wbuf[(size_t)bhc*4096 + e];
    }
    for (int e = tid; e < 1024; e += 256) {
      int j = e >> 6, i = e & 63;
      S0buf[(size_t)bhc*4096 + (size_t)(j0 + j)*64 + i] = SsT[j][i];
    }
    __syncthreads();
    // delta = U - W @ S0   (4 rows per thread, shared S column in float4)
    float d0, d1, d2, d3;
    {
      float a0=0,a1=0,a2=0,a3=0;
      for (int i = 0; i < 64; i += 4) {
        float4 sv = *(const float4*)&SsT[jj][i];
        float4 w0 = *(const float4*)&Wls[tq   ][i];
        float4 w1 = *(const float4*)&Wls[tq+16][i];
        float4 w2 = *(const float4*)&Wls[tq+32][i];
        float4 w3 = *(const float4*)&Wls[tq+48][i];
        a0 = dot4(w0, sv, a0); a1 = dot4(w1, sv, a1);
        a2 = dot4(w2, sv, a2); a3 = dot4(w3, sv, a3);
      }
      const size_t ub = (size_t)bhc*4096 + j0 + jj;
      d0 = Ubuf[ub + (size_t)(tq   )*64] - a0;
      d1 = Ubuf[ub + (size_t)(tq+16)*64] - a1;
      d2 = Ubuf[ub + (size_t)(tq+32)*64] - a2;
      d3 = Ubuf[ub + (size_t)(tq+48)*64] - a3;
    }
    DsT[jj][tq] = d0; DsT[jj][tq+16] = d1; DsT[jj][tq+32] = d2; DsT[jj][tq+48] = d3;
    __syncthreads();
    // S = bC*S + Ksc^T @ delta
    {
      const float bC = __expf(gC);
      float a0=0,a1=0,a2=0,a3=0;
      for (int t4 = 0; t4 < 64; t4 += 4) {
        float4 dv = *(const float4*)&DsT[jj][t4];
        float4 k0 = *(const float4*)&KscT[tq   ][t4];
        float4 k1 = *(const float4*)&KscT[tq+16][t4];
        float4 k2 = *(const float4*)&KscT[tq+32][t4];
        float4 k3 = *(const float4*)&KscT[tq+48][t4];
        a0 = dot4(k0, dv, a0); a1 = dot4(k1, dv, a1);
        a2 = dot4(k2, dv, a2); a3 = dot4(k3, dv, a3);
      }
      SsT[jj][tq]    = fmaf(bC, SsT[jj][tq],    a0);
      SsT[jj][tq+16] = fmaf(bC, SsT[jj][tq+16], a1);
      SsT[jj][tq+32] = fmaf(bC, SsT[jj][tq+32], a2);
      SsT[jj][tq+48] = fmaf(bC, SsT[jj][tq+48], a3);
    }
    for (int e = tid; e < 1024; e += 256) {
      int j = e >> 6, t = e & 63;
      Dbuf[(size_t)bhc*4096 + (size_t)(j0 + j)*64 + t] = DsT[j][t];
    }
    __syncthreads();
  }
}

// ---------------- P3: outputs ----------------
__global__ __launch_bounds__(256) void p3_out(
    const float* __restrict__ Qc, const float* __restrict__ Kc,
    const float* __restrict__ Gcum, const float* __restrict__ S0buf,
    const float* __restrict__ Dbuf, float* __restrict__ O)
{
  __shared__ float Qs[64][68];
  __shared__ float Ks[64][68];
  __shared__ float PT[64][68];    // first S0T[j][i], then P[t][s]
  __shared__ float DsT[64][68];   // [j][t]
  __shared__ float gcs[64];
  const int bhc = blockIdx.x;
  const int bh = bhc >> 5, c = bhc & 31;
  const int b = bh >> 4, h = bh & 15;
  const int tid = threadIdx.x;
  const size_t rowbase = ((size_t)b*T_ + c*64)*H_ + h;
  if (tid < 64) gcs[tid] = Gcum[(size_t)bhc*64 + tid];
  for (int e = tid; e < 4096; e += 256) {
    int r = e >> 6, d = e & 63;
    size_t ga = (rowbase + (size_t)r*H_)*64 + d;
    Qs[r][d]  = Qc[ga];
    Ks[r][d]  = Kc[ga];
    PT[r][d]  = S0buf[(size_t)bhc*4096 + e];
    DsT[r][d] = Dbuf[(size_t)bhc*4096 + e];
  }
  __syncthreads();
  const int lane = tid & 63, wq = tid >> 6;
  float oacc[16], preg[16];
  #pragma unroll
  for (int it = 0; it < 16; ++it) { oacc[it] = 0.f; preg[it] = 0.f; }

  // Phase A: oacc[t] = sum_i Q[t][i] * S0[i][lane]
  for (int i = 0; i < 64; i += 4) {
    float4 sv = *(const float4*)&PT[lane][i];
    #pragma unroll
    for (int it = 0; it < 16; ++it) {
      float4 qv = *(const float4*)&Qs[it*4 + wq][i];
      oacc[it] = dot4(qv, sv, oacc[it]);
    }
  }
  #pragma unroll
  for (int it = 0; it < 16; ++it) oacc[it] *= __expf(gcs[it*4 + wq]);

  // Phase B: P[t][lane] = (lane<=t) ? e^{gc_t-gc_lane} * q_t.k_lane : 0
  for (int i = 0; i < 64; i += 4) {
    float4 kv = *(const float4*)&Ks[lane][i];
    #pragma unroll
    for (int it = 0; it < 16; ++it) {
      float4 qv = *(const float4*)&Qs[it*4 + wq][i];
      preg[it] = dot4(qv, kv, preg[it]);
    }
  }
  {
    const float gs = gcs[lane];
    #pragma unroll
    for (int it = 0; it < 16; ++it) {
      int t = it*4 + wq;
      preg[it] = (lane <= t) ? __expf(gcs[t] - gs) * preg[it] : 0.f;
    }
  }
  __syncthreads();   // all Phase-A reads of PT done
  #pragma unroll
  for (int it = 0; it < 16; ++it) PT[it*4 + wq][lane] = preg[it];
  __syncthreads();

  // Phase C: oacc[t] += sum_s P[t][s] * delta[s][lane]
  for (int s = 0; s < 64; s += 4) {
    float4 dv = *(const float4*)&DsT[lane][s];
    #pragma unroll
    for (int it = 0; it < 16; ++it) {
      float4 pv = *(const float4*)&PT[it*4 + wq][s];
      oacc[it] = dot4(pv, dv, oacc[it]);
    }
  }
  #pragma unroll
  for (int it = 0; it < 16; ++it) {
    int t = it*4 + wq;
    O[(rowbase + (size_t)t*H_)*64 + lane] = oacc[it];
  }
}

// ---------------- o-norm * swish(gv) ----------------
__global__ __launch_bounds__(256) void ogate(const float* __restrict__ O,
    const float* __restrict__ GV, const float* __restrict__ w,
    float* __restrict__ OG)
{
  const size_t gid = (size_t)blockIdx.x * 256 + threadIdx.x;
  if (gid >= (size_t)B_ * T_ * D_) return;
  const size_t vec = gid >> 6;
  const int lane = threadIdx.x & 63;
  float x = O[vec * 64 + lane];
  float ss = x * x;
  #pragma unroll
  for (int m = 1; m < 64; m <<= 1) ss += __shfl_xor(ss, m);
  float y = x * rsqrtf(ss * (1.f/64.f) + 1e-6f) * w[lane];
  float gv = GV[vec * 64 + lane];
  OG[vec * 64 + lane] = y * gv / (1.f + __expf(-gv));
}

extern "C" void kernel_launch(void* const* d_in, const int* in_sizes, int n_in,
                              void* d_out, int out_size, void* d_ws, size_t ws_size,
                              hipStream_t stream) {
  const float* h    = (const float*)d_in[0];
  const float* Wq   = (const float*)d_in[1];
  const float* Wk   = (const float*)d_in[2];
  const float* Wv   = (const float*)d_in[3];
  const float* Wa   = (const float*)d_in[4];
  const float* Wb   = (const float*)d_in[5];
  const float* Wg   = (const float*)d_in[6];
  const float* Wo   = (const float*)d_in[7];
  const float* qnw  = (const float*)d_in[8];
  const float* knw  = (const float*)d_in[9];
  const float* onw  = (const float*)d_in[10];
  const float* Alog = (const float*)d_in[11];
  const float* dtb  = (const float*)d_in[12];
  const float* cqw  = (const float*)d_in[13];
  const float* ckw  = (const float*)d_in[14];
  const float* cvw  = (const float*)d_in[15];
  float* out = (float*)d_out;
  float* ws  = (float*)d_ws;

  const size_t NB = (size_t)B_ * T_ * D_;
  float* qp  = ws;            // -> U after conv consumes qp
  float* kp  = ws + 1*NB;     // -> W
  float* vp  = ws + 2*NB;     // -> S0
  float* gvp = ws + 3*NB;
  float* qc  = ws + 4*NB;
  float* kc  = ws + 5*NB;
  float* vc  = ws + 6*NB;
  float* og  = ws + 7*NB;     // -> delta, then ogate output
  float* gb  = ws + 8*NB;
  float* bb  = gb + (size_t)B_ * T_ * H_;
  float* Gc  = bb + (size_t)B_ * T_ * H_;   // [1024][64] chunk gcum

  const int M = B_ * T_;
  dim3 gg(M / 128, D_ / 128);
  const int EW = (int)(NB / 256);

  gemm128<<<gg, 256, 0, stream>>>(h, Wq, qp, M, D_, D_);
  gemm128<<<gg, 256, 0, stream>>>(h, Wk, kp, M, D_, D_);
  gemm128<<<gg, 256, 0, stream>>>(h, Wv, vp, M, D_, D_);
  gemm128<<<gg, 256, 0, stream>>>(h, Wg, gvp, M, D_, D_);
  smallproj<<<B_ * T_, 256, 0, stream>>>(h, Wa, Wb, Alog, dtb, gb, bb);

  conv_silu<<<EW, 256, 0, stream>>>(qp, cqw, qc);
  conv_silu<<<EW, 256, 0, stream>>>(kp, ckw, kc);
  conv_silu<<<EW, 256, 0, stream>>>(vp, cvw, vc);

  headnorm<<<EW, 256, 0, stream>>>(qc, qnw, 0.125f);
  headnorm<<<EW, 256, 0, stream>>>(kc, knw, 1.0f);

  float* Ubuf = qp;
  float* Wbuf = kp;
  float* S0b  = vp;
  float* Dbuf = og;
  p1_chunk<<<B_*H_*NC_, 256, 0, stream>>>(kc, vc, gb, bb, Ubuf, Wbuf, Gc);
  p2_state<<<B_*H_*4, 256, 0, stream>>>(kc, Gc, Ubuf, Wbuf, S0b, Dbuf);
  p3_out<<<B_*H_*NC_, 256, 0, stream>>>(qc, kc, Gc, S0b, Dbuf, out);

  ogate<<<EW, 256, 0, stream>>>(out, gvp, onw, og);
  gemm128<<<gg, 256, 0, stream>>>(og, Wo, out, M, D_, D_);
}

// Round 3
// 513.684 us; speedup vs baseline: 7.8554x; 2.0884x over previous
//
#include <hip/hip_runtime.h>
#include <cstdint>
#include <cstddef>

#define B_ 2
#define T_ 2048
#define D_ 1024
#define H_ 16
#define HD_ 64
#define NC_ 32

typedef unsigned short u16;
typedef __attribute__((ext_vector_type(8))) short bf16x8;
typedef __attribute__((ext_vector_type(4))) float f32x4;

__device__ __forceinline__ float dot4(float4 a, float4 b, float acc) {
  return fmaf(a.x, b.x, fmaf(a.y, b.y, fmaf(a.z, b.z, fmaf(a.w, b.w, acc))));
}
__device__ __forceinline__ float ndot4(float4 a, float4 b, float acc) {
  return fmaf(-a.x, b.x, fmaf(-a.y, b.y, fmaf(-a.z, b.z, fmaf(-a.w, b.w, acc))));
}
__device__ __forceinline__ u16 f2bf(float f) {
  unsigned u = __float_as_uint(f);
  u += 0x7fffu + ((u >> 16) & 1u);
  return (u16)(u >> 16);
}

// ---------------- fp32 -> bf16 conversion ----------------
__global__ __launch_bounds__(256) void cvt_bf16(const float* __restrict__ x,
    u16* __restrict__ y, int n)
{
  int i = (blockIdx.x * 256 + threadIdx.x) * 8;
  if (i >= n) return;
  float4 v0 = *(const float4*)(x + i);
  float4 v1 = *(const float4*)(x + i + 4);
  union { u16 us[8]; uint4 u4; } p;
  p.us[0] = f2bf(v0.x); p.us[1] = f2bf(v0.y); p.us[2] = f2bf(v0.z); p.us[3] = f2bf(v0.w);
  p.us[4] = f2bf(v1.x); p.us[5] = f2bf(v1.y); p.us[6] = f2bf(v1.z); p.us[7] = f2bf(v1.w);
  *(uint4*)(y + i) = p.u4;
}

// ---------------- bf16 MFMA GEMM core: C[M,N] = A[M,K] @ Bw[N,K]^T ----------------
// 128x128 tile, BK=32, 256 threads (4 waves, 2x2 quadrants), LDS rows padded to 40
__device__ __forceinline__ void gemm_core(const u16* __restrict__ A,
    const u16* __restrict__ Bw, float* __restrict__ C,
    u16* As, u16* Bs, int row0, int col0, int K, int N)
{
  const int tid = threadIdx.x;
  const u16* Ap = A + (size_t)(row0 + (tid >> 2)) * K + (tid & 3) * 8;
  const u16* Bp = Bw + (size_t)(col0 + (tid >> 2)) * K + (tid & 3) * 8;
  const int wA = (tid >> 2) * 40 + (tid & 3) * 8;
  const int lane = tid & 63, wave = tid >> 6;
  const int wr = (wave >> 1) * 64, wc = (wave & 1) * 64;
  const int lr = lane & 15, lk = (lane >> 4) * 8;

  f32x4 acc[4][4];
  #pragma unroll
  for (int i = 0; i < 4; ++i)
    #pragma unroll
    for (int j = 0; j < 4; ++j) acc[i][j] = f32x4{0.f, 0.f, 0.f, 0.f};

  uint4 ra0 = *(const uint4*)(Ap);
  uint4 ra1 = *(const uint4*)(Ap + 64 * K);
  uint4 rb0 = *(const uint4*)(Bp);
  uint4 rb1 = *(const uint4*)(Bp + 64 * K);

  const int KT = K >> 5;
  for (int kt = 0; kt < KT; ++kt) {
    *(uint4*)&As[wA] = ra0; *(uint4*)&As[wA + 64 * 40] = ra1;
    *(uint4*)&Bs[wA] = rb0; *(uint4*)&Bs[wA + 64 * 40] = rb1;
    __syncthreads();
    if (kt + 1 < KT) {
      const u16* Ap2 = Ap + (kt + 1) * 32;
      const u16* Bp2 = Bp + (kt + 1) * 32;
      ra0 = *(const uint4*)(Ap2); ra1 = *(const uint4*)(Ap2 + 64 * K);
      rb0 = *(const uint4*)(Bp2); rb1 = *(const uint4*)(Bp2 + 64 * K);
    }
    bf16x8 af[4], bf[4];
    #pragma unroll
    for (int i = 0; i < 4; ++i) af[i] = *(const bf16x8*)&As[(wr + i * 16 + lr) * 40 + lk];
    #pragma unroll
    for (int j = 0; j < 4; ++j) bf[j] = *(const bf16x8*)&Bs[(wc + j * 16 + lr) * 40 + lk];
    #pragma unroll
    for (int i = 0; i < 4; ++i)
      #pragma unroll
      for (int j = 0; j < 4; ++j)
        acc[i][j] = __builtin_amdgcn_mfma_f32_16x16x32_bf16(af[i], bf[j], acc[i][j], 0, 0, 0);
    __syncthreads();
  }
  const int orow = row0 + wr + (lane >> 4) * 4;
  const int ocol = col0 + wc + lr;
  #pragma unroll
  for (int i = 0; i < 4; ++i)
    #pragma unroll
    for (int j = 0; j < 4; ++j)
      #pragma unroll
      for (int r = 0; r < 4; ++r)
        C[(size_t)(orow + i * 16 + r) * N + ocol + j * 16] = acc[i][j][r];
}

// 4 projection GEMMs fused (same A), N=K=1024 each
__global__ __launch_bounds__(256) void gemm_bf16_4(const u16* __restrict__ A,
    const u16* __restrict__ W0, const u16* __restrict__ W1,
    const u16* __restrict__ W2, const u16* __restrict__ W3,
    float* __restrict__ C0, float* __restrict__ C1,
    float* __restrict__ C2, float* __restrict__ C3)
{
  __shared__ u16 As[128 * 40];
  __shared__ u16 Bs[128 * 40];
  const int sel = blockIdx.y >> 3;
  const u16* Bw = sel == 0 ? W0 : sel == 1 ? W1 : sel == 2 ? W2 : W3;
  float* C = sel == 0 ? C0 : sel == 1 ? C1 : sel == 2 ? C2 : C3;
  gemm_core(A, Bw, C, As, Bs, blockIdx.x * 128, (blockIdx.y & 7) * 128, 1024, 1024);
}

__global__ __launch_bounds__(256) void gemm_bf16_1(const u16* __restrict__ A,
    const u16* __restrict__ Bw, float* __restrict__ C)
{
  __shared__ u16 As[128 * 40];
  __shared__ u16 Bs[128 * 40];
  gemm_core(A, Bw, C, As, Bs, blockIdx.x * 128, blockIdx.y * 128, 1024, 1024);
}

// ---------------- beta / g small projections ----------------
__global__ __launch_bounds__(256) void smallproj(const float* __restrict__ Hs,
    const float* __restrict__ Wa, const float* __restrict__ Wb,
    const float* __restrict__ Alog, const float* __restrict__ dtb,
    float* __restrict__ Gout, float* __restrict__ Bout)
{
  __shared__ float hs[D_];
  const int bt = blockIdx.x;
  for (int i = threadIdx.x; i < D_; i += 256) hs[i] = Hs[(size_t)bt * D_ + i];
  __syncthreads();
  const int grp = threadIdx.x >> 3, p = threadIdx.x & 7;
  const int head = grp & 15, which = grp >> 4;
  const float* Wr = (which ? Wb : Wa) + head * D_;
  float s = 0.f;
  for (int i = p; i < D_; i += 8) s = fmaf(hs[i], Wr[i], s);
  s += __shfl_xor(s, 1); s += __shfl_xor(s, 2); s += __shfl_xor(s, 4);
  if (p == 0) {
    if (which) {
      Bout[(size_t)bt * H_ + head] = 1.f / (1.f + __expf(-s));
    } else {
      float x = s + dtb[head];
      float sp = fmaxf(x, 0.f) + log1pf(__expf(-fabsf(x)));
      Gout[(size_t)bt * H_ + head] = -__expf(Alog[head]) * sp;
    }
  }
}

// ---------------- causal depthwise conv (K=4) + SiLU ----------------
__global__ __launch_bounds__(256) void conv_silu(const float* __restrict__ X,
    const float* __restrict__ W, float* __restrict__ Y)
{
  const size_t idx = (size_t)blockIdx.x * 256 + threadIdx.x;
  if (idx >= (size_t)B_ * T_ * D_) return;
  const int c = (int)(idx & (D_ - 1));
  const int t = (int)((idx >> 10) & (T_ - 1));
  const float4 w = *(const float4*)(W + c * 4);
  float acc = w.w * X[idx];
  if (t >= 1) acc = fmaf(w.z, X[idx - D_],     acc);
  if (t >= 2) acc = fmaf(w.y, X[idx - 2*D_],   acc);
  if (t >= 3) acc = fmaf(w.x, X[idx - 3*D_],   acc);
  Y[idx] = acc / (1.f + __expf(-acc));
}

// ---------------- per-head RMSNorm then L2-norm (in-place) ----------------
__global__ __launch_bounds__(256) void headnorm(float* __restrict__ X,
    const float* __restrict__ w, float fs)
{
  const size_t gid = (size_t)blockIdx.x * 256 + threadIdx.x;
  if (gid >= (size_t)B_ * T_ * D_) return;
  const size_t vec = gid >> 6;
  const int lane = threadIdx.x & 63;
  float x = X[vec * 64 + lane];
  float ss = x * x;
  #pragma unroll
  for (int m = 1; m < 64; m <<= 1) ss += __shfl_xor(ss, m);
  float y = x * rsqrtf(ss * (1.f/64.f) + 1e-6f) * w[lane];
  float s2 = y * y;
  #pragma unroll
  for (int m = 1; m < 64; m <<= 1) s2 += __shfl_xor(s2, m);
  X[vec * 64 + lane] = y * rsqrtf(s2 + 1e-6f) * fs;
}

// ---------------- P1: per-chunk A, triangular solve -> U, W ----------------
__global__ __launch_bounds__(256) void p1_chunk(
    const float* __restrict__ Kc, const float* __restrict__ Vc,
    const float* __restrict__ Gg, const float* __restrict__ Bb,
    float* __restrict__ Ubuf, float* __restrict__ Wbuf, float* __restrict__ Gcum)
{
  __shared__ float Ks[64][68];
  __shared__ float Am[64][68];
  __shared__ float XT[128][68];
  __shared__ float gc[64], bet[64];
  const int bhc = blockIdx.x;
  const int bh = bhc >> 5, c = bhc & 31;
  const int b = bh >> 4, h = bh & 15;
  const int tid = threadIdx.x;
  const size_t rowbase = ((size_t)b*T_ + c*64)*H_ + h;

  if (tid < 64) {
    float gv = Gg[rowbase + (size_t)tid*H_];
    #pragma unroll
    for (int off = 1; off < 64; off <<= 1) {
      float up = __shfl_up(gv, off, 64);
      if (tid >= off) gv += up;
    }
    gc[tid] = gv;
    Gcum[(size_t)bhc*64 + tid] = gv;
    bet[tid] = Bb[rowbase + (size_t)tid*H_];
  }
  for (int e = tid; e < 4096; e += 256) {
    int t = e >> 6, d = e & 63;
    Ks[t][d] = Kc[(rowbase + (size_t)t*H_)*64 + d];
  }
  __syncthreads();

  {
    const int t = tid & 63, s0 = (tid >> 6) << 4;
    float acc[16];
    #pragma unroll
    for (int m = 0; m < 16; ++m) acc[m] = 0.f;
    for (int i = 0; i < 64; i += 4) {
      float4 kt = *(const float4*)&Ks[t][i];
      #pragma unroll
      for (int m = 0; m < 16; ++m) {
        float4 ks = *(const float4*)&Ks[s0+m][i];
        acc[m] = dot4(kt, ks, acc[m]);
      }
    }
    const float bt = bet[t], gt = gc[t];
    #pragma unroll
    for (int m = 0; m < 16; ++m) {
      int s = s0 + m;
      Am[t][s] = (s < t) ? bt * __expf(gt - gc[s]) * acc[m] : 0.f;
    }
  }
  for (int e = tid; e < 4096; e += 256) {
    int t = e >> 6, j = e & 63;
    float btv = bet[t];
    XT[j][t]    = btv * Vc[(rowbase + (size_t)t*H_)*64 + j];
    XT[64+j][t] = btv * __expf(gc[t]) * Ks[t][j];
  }
  __syncthreads();

  if (tid < 128) {
    for (int t = 1; t < 64; ++t) {
      float a0=0,a1=0,a2=0,a3=0;
      const int qmax = t >> 2;
      for (int q = 0; q <= qmax; ++q) {
        float4 av = *(const float4*)&Am[t][q*4];
        float4 xv = *(const float4*)&XT[tid][q*4];
        a0 = fmaf(av.x, xv.x, a0);
        a1 = fmaf(av.y, xv.y, a1);
        a2 = fmaf(av.z, xv.z, a2);
        a3 = fmaf(av.w, xv.w, a3);
      }
      XT[tid][t] -= (a0+a1)+(a2+a3);
    }
  }
  __syncthreads();
  for (int e = tid; e < 4096; e += 256) {
    int t = e >> 6, j = e & 63;
    Ubuf[(size_t)bhc*4096 + e] = XT[j][t];
    Wbuf[(size_t)bhc*4096 + e] = XT[64+j][t];
  }
}

// ---------------- P1b: per-chunk transition M = bC*I - Ksc^T W, N = Ksc^T U ----------------
__global__ __launch_bounds__(256) void p1b_mn(
    const float* __restrict__ Kc, const float* __restrict__ Gcum,
    const float* __restrict__ Ubuf, const float* __restrict__ Wbuf,
    float* __restrict__ Mbuf, float* __restrict__ Nbuf)
{
  __shared__ float Ksc[64][68];
  __shared__ float Wl[64][68];
  __shared__ float Ul[64][68];
  __shared__ float gcs[64];
  const int bhc = blockIdx.x;
  const int bh = bhc >> 5, c = bhc & 31;
  const int b = bh >> 4, h = bh & 15;
  const int tid = threadIdx.x;
  const size_t rowbase = ((size_t)b*T_ + c*64)*H_ + h;
  if (tid < 64) gcs[tid] = Gcum[(size_t)bhc*64 + tid];
  __syncthreads();
  const float gC = gcs[63];
  for (int e = tid; e < 4096; e += 256) {
    int t = e >> 6, i = e & 63;
    Ksc[t][i] = __expf(gC - gcs[t]) * Kc[(rowbase + (size_t)t*H_)*64 + i];
  }
  for (int e4 = tid; e4 < 1024; e4 += 256) {
    int t = e4 >> 4, i4 = (e4 & 15) * 4;
    *(float4*)&Wl[t][i4] = *(const float4*)&Wbuf[(size_t)bhc*4096 + (size_t)t*64 + i4];
    *(float4*)&Ul[t][i4] = *(const float4*)&Ubuf[(size_t)bhc*4096 + (size_t)t*64 + i4];
  }
  __syncthreads();
  const int a0 = (tid >> 4) * 4, c0 = (tid & 15) * 4;
  float accM[4][4] = {}, accN[4][4] = {};
  for (int t = 0; t < 64; ++t) {
    float4 kv = *(const float4*)&Ksc[t][a0];
    float4 wv = *(const float4*)&Wl[t][c0];
    float4 uv = *(const float4*)&Ul[t][c0];
    const float ka[4] = {kv.x, kv.y, kv.z, kv.w};
    const float wa[4] = {wv.x, wv.y, wv.z, wv.w};
    const float ua[4] = {uv.x, uv.y, uv.z, uv.w};
    #pragma unroll
    for (int r = 0; r < 4; ++r)
      #pragma unroll
      for (int m = 0; m < 4; ++m) {
        accM[r][m] = fmaf(ka[r], wa[m], accM[r][m]);
        accN[r][m] = fmaf(ka[r], ua[m], accN[r][m]);
      }
  }
  const float bC = __expf(gC);
  const size_t ob = (size_t)bhc * 4096;
  #pragma unroll
  for (int r = 0; r < 4; ++r) {
    int a = a0 + r;
    float4 mo = { (a==c0+0?bC:0.f)-accM[r][0], (a==c0+1?bC:0.f)-accM[r][1],
                  (a==c0+2?bC:0.f)-accM[r][2], (a==c0+3?bC:0.f)-accM[r][3] };
    float4 no = { accN[r][0], accN[r][1], accN[r][2], accN[r][3] };
    *(float4*)&Mbuf[ob + (size_t)a*64 + c0] = mo;
    *(float4*)&Nbuf[ob + (size_t)a*64 + c0] = no;
  }
}

// ---------------- P2: serial state recurrence S <- M@S + N (j-split x2) ----------------
__global__ __launch_bounds__(256) void p2_state(
    const float* __restrict__ Mbuf, const float* __restrict__ Nbuf,
    float* __restrict__ S0b)
{
  __shared__ float ST[2][32][68];   // S^T slice: ST[jl][i], XOR-swizzled on i-group
  __shared__ float Mm[2][64][68];
  const int bh = blockIdx.x >> 1, js = blockIdx.x & 1;
  const int tid = threadIdx.x;
  const int a0 = (tid >> 4) * 4;
  const int jl0 = (tid & 15) * 2;
  for (int e4 = tid; e4 < 32 * 17; e4 += 256)
    ((float4*)&ST[0][0][0])[e4] = float4{0.f, 0.f, 0.f, 0.f};
  #pragma unroll
  for (int r = 0; r < 4; ++r) {
    int e4 = tid + r * 256;
    int t = e4 >> 4, i4 = (e4 & 15) * 4;
    *(float4*)&Mm[0][t][i4] = *(const float4*)&Mbuf[(size_t)bh*32*4096 + (size_t)t*64 + i4];
  }
  __syncthreads();
  for (int c = 0; c < NC_; ++c) {
    const int cur = c & 1, nxt = cur ^ 1;
    const size_t bhc = (size_t)bh * NC_ + c;
    float4 mreg[4];
    const bool hn = (c + 1 < NC_);
    if (hn) {
      #pragma unroll
      for (int r = 0; r < 4; ++r) {
        int e4 = tid + r * 256;
        int t = e4 >> 4, i4 = (e4 & 15) * 4;
        mreg[r] = *(const float4*)&Mbuf[(bhc+1)*4096 + (size_t)t*64 + i4];
      }
    }
    float2 nreg[4];
    #pragma unroll
    for (int r = 0; r < 4; ++r)
      nreg[r] = *(const float2*)&Nbuf[bhc*4096 + (size_t)(a0+r)*64 + js*32 + jl0];
    // write out S0 (state entering chunk c), global layout [j][i]
    #pragma unroll
    for (int r = 0; r < 2; ++r) {
      int e4 = tid + r * 256;
      int jl = e4 >> 4, i4 = (e4 & 15) * 4;
      int gs = (((i4 >> 2) ^ ((jl >> 1) & 7))) * 4;
      *(float4*)&S0b[bhc*4096 + (size_t)(js*32 + jl)*64 + i4] = *(const float4*)&ST[cur][jl][gs];
    }
    float acc[4][2];
    #pragma unroll
    for (int r = 0; r < 4; ++r) { acc[r][0] = nreg[r].x; acc[r][1] = nreg[r].y; }
    for (int i4 = 0; i4 < 64; i4 += 4) {
      float4 mv[4], sv[2];
      #pragma unroll
      for (int r = 0; r < 4; ++r) mv[r] = *(const float4*)&Mm[cur][a0+r][i4];
      #pragma unroll
      for (int m = 0; m < 2; ++m) {
        int jl = jl0 + m;
        sv[m] = *(const float4*)&ST[cur][jl][(((i4 >> 2) ^ ((jl >> 1) & 7))) * 4];
      }
      #pragma unroll
      for (int r = 0; r < 4; ++r) {
        acc[r][0] = dot4(mv[r], sv[0], acc[r][0]);
        acc[r][1] = dot4(mv[r], sv[1], acc[r][1]);
      }
    }
    #pragma unroll
    for (int r = 0; r < 4; ++r)
      #pragma unroll
      for (int m = 0; m < 2; ++m) {
        int jl = jl0 + m, a = a0 + r;
        ST[nxt][jl][((((a >> 2) ^ ((jl >> 1) & 7))) << 2) + (a & 3)] = acc[r][m];
      }
    if (hn) {
      #pragma unroll
      for (int r = 0; r < 4; ++r) {
        int e4 = tid + r * 256;
        int t = e4 >> 4, i4 = (e4 & 15) * 4;
        *(float4*)&Mm[nxt][t][i4] = mreg[r];
      }
    }
    __syncthreads();
  }
}

// ---------------- P3: delta + outputs ----------------
__global__ __launch_bounds__(256) void p3_out(
    const float* __restrict__ Qc, const float* __restrict__ Kc,
    const float* __restrict__ Gcum, const float* __restrict__ S0b,
    const float* __restrict__ Ubuf, const float* __restrict__ Wbuf,
    float* __restrict__ O)
{
  __shared__ float Qs[64][68];
  __shared__ float KDs[64][68];   // K, then delta^T [j][t]
  __shared__ float PT[64][68];    // S0T [j][i], then P [t][s]
  __shared__ float Ws[64][68];
  __shared__ float gcs[64];
  const int bhc = blockIdx.x;
  const int bh = bhc >> 5, c = bhc & 31;
  const int b = bh >> 4, h = bh & 15;
  const int tid = threadIdx.x;
  const size_t rowbase = ((size_t)b*T_ + c*64)*H_ + h;
  if (tid < 64) gcs[tid] = Gcum[(size_t)bhc*64 + tid];
  for (int e = tid; e < 4096; e += 256) {
    int r = e >> 6, d = e & 63;
    size_t ga = (rowbase + (size_t)r*H_)*64 + d;
    Qs[r][d]  = Qc[ga];
    KDs[r][d] = Kc[ga];
    PT[r][d]  = S0b[(size_t)bhc*4096 + e];
    Ws[r][d]  = Wbuf[(size_t)bhc*4096 + e];
  }
  __syncthreads();
  const int lane = tid & 63, wq = tid >> 6;
  float oacc[16], preg[16];
  #pragma unroll
  for (int it = 0; it < 16; ++it) { oacc[it] = 0.f; preg[it] = 0.f; }

  // A: q_t . S0[:,lane]
  for (int i = 0; i < 64; i += 4) {
    float4 sv = *(const float4*)&PT[lane][i];
    #pragma unroll
    for (int it = 0; it < 16; ++it) {
      float4 qv = *(const float4*)&Qs[it*4 + wq][i];
      oacc[it] = dot4(qv, sv, oacc[it]);
    }
  }
  #pragma unroll
  for (int it = 0; it < 16; ++it) oacc[it] *= __expf(gcs[it*4 + wq]);

  // B: P[t][lane] = (lane<=t) e^{gc_t-gc_lane} q_t.k_lane
  for (int i = 0; i < 64; i += 4) {
    float4 kv = *(const float4*)&KDs[lane][i];
    #pragma unroll
    for (int it = 0; it < 16; ++it) {
      float4 qv = *(const float4*)&Qs[it*4 + wq][i];
      preg[it] = dot4(qv, kv, preg[it]);
    }
  }
  {
    const float gsl = gcs[lane];
    #pragma unroll
    for (int it = 0; it < 16; ++it) {
      int t = it*4 + wq;
      preg[it] = (lane <= t) ? __expf(gcs[t] - gsl) * preg[it] : 0.f;
    }
  }

  // delta = U - W @ S0
  const int dt0 = (tid >> 4) << 2, dj0 = (tid & 15) << 2;
  float dacc[4][4];
  #pragma unroll
  for (int r = 0; r < 4; ++r) {
    float4 uv = *(const float4*)&Ubuf[(size_t)bhc*4096 + (size_t)(dt0+r)*64 + dj0];
    dacc[r][0] = uv.x; dacc[r][1] = uv.y; dacc[r][2] = uv.z; dacc[r][3] = uv.w;
  }
  for (int i = 0; i < 64; i += 4) {
    float4 wv[4], sv[4];
    #pragma unroll
    for (int r = 0; r < 4; ++r) wv[r] = *(const float4*)&Ws[dt0+r][i];
    #pragma unroll
    for (int m = 0; m < 4; ++m) sv[m] = *(const float4*)&PT[dj0+m][i];
    #pragma unroll
    for (int r = 0; r < 4; ++r)
      #pragma unroll
      for (int m = 0; m < 4; ++m)
        dacc[r][m] = ndot4(wv[r], sv[m], dacc[r][m]);
  }
  __syncthreads();
  #pragma unroll
  for (int it = 0; it < 16; ++it) PT[it*4 + wq][lane] = preg[it];
  #pragma unroll
  for (int r = 0; r < 4; ++r)
    #pragma unroll
    for (int m = 0; m < 4; ++m)
      KDs[dj0+m][dt0+r] = dacc[r][m];
  __syncthreads();

  // C: oacc[t] += sum_s P[t][s] * delta[s][lane]
  for (int s = 0; s < 64; s += 4) {
    float4 dv = *(const float4*)&KDs[lane][s];
    #pragma unroll
    for (int it = 0; it < 16; ++it) {
      float4 pv = *(const float4*)&PT[it*4 + wq][s];
      oacc[it] = dot4(pv, dv, oacc[it]);
    }
  }
  #pragma unroll
  for (int it = 0; it < 16; ++it) {
    int t = it*4 + wq;
    O[(rowbase + (size_t)t*H_)*64 + lane] = oacc[it];
  }
}

// ---------------- o-norm * swish(gv) -> bf16 ----------------
__global__ __launch_bounds__(256) void ogate(const float* __restrict__ O,
    const float* __restrict__ GV, const float* __restrict__ w,
    u16* __restrict__ OG)
{
  const size_t gid = (size_t)blockIdx.x * 256 + threadIdx.x;
  if (gid >= (size_t)B_ * T_ * D_) return;
  const size_t vec = gid >> 6;
  const int lane = threadIdx.x & 63;
  float x = O[vec * 64 + lane];
  float ss = x * x;
  #pragma unroll
  for (int m = 1; m < 64; m <<= 1) ss += __shfl_xor(ss, m);
  float y = x * rsqrtf(ss * (1.f/64.f) + 1e-6f) * w[lane];
  float gv = GV[vec * 64 + lane];
  OG[vec * 64 + lane] = f2bf(y * gv / (1.f + __expf(-gv)));
}

extern "C" void kernel_launch(void* const* d_in, const int* in_sizes, int n_in,
                              void* d_out, int out_size, void* d_ws, size_t ws_size,
                              hipStream_t stream) {
  const float* h    = (const float*)d_in[0];
  const float* Wq   = (const float*)d_in[1];
  const float* Wk   = (const float*)d_in[2];
  const float* Wv   = (const float*)d_in[3];
  const float* Wa   = (const float*)d_in[4];
  const float* Wb   = (const float*)d_in[5];
  const float* Wg   = (const float*)d_in[6];
  const float* Wo   = (const float*)d_in[7];
  const float* qnw  = (const float*)d_in[8];
  const float* knw  = (const float*)d_in[9];
  const float* onw  = (const float*)d_in[10];
  const float* Alog = (const float*)d_in[11];
  const float* dtb  = (const float*)d_in[12];
  const float* cqw  = (const float*)d_in[13];
  const float* ckw  = (const float*)d_in[14];
  const float* cvw  = (const float*)d_in[15];
  float* out = (float*)d_out;
  float* ws  = (float*)d_ws;

  const size_t NB = (size_t)B_ * T_ * D_;     // 4,194,304
  float* qp   = ws;
  float* kp   = ws + 1*NB;
  float* vp   = ws + 2*NB;
  float* gvp  = ws + 3*NB;
  float* qc   = ws + 4*NB;
  float* kc   = ws + 5*NB;
  float* vc   = ws + 6*NB;                    // later: Nbuf
  float* mb   = ws + 7*NB;                    // Mbuf; earlier h_bf; later og_bf
  float* wbf  = ws + 8*NB;                    // 5 x 524288 floats of bf16 weights
  float* gb   = ws + 8*NB + 5*524288;
  float* bb   = gb + (size_t)B_*T_*H_;
  float* Gc   = bb + (size_t)B_*T_*H_;

  u16* h_bf  = (u16*)mb;
  u16* og_bf = (u16*)mb;
  u16* wq_bf = (u16*)(wbf + 0*524288);
  u16* wk_bf = (u16*)(wbf + 1*524288);
  u16* wv_bf = (u16*)(wbf + 2*524288);
  u16* wg_bf = (u16*)(wbf + 3*524288);
  u16* wo_bf = (u16*)(wbf + 4*524288);

  float* Ubuf = qp;
  float* Wbuf = kp;
  float* S0b  = vp;
  float* Mbuf = mb;
  float* Nbuf = vc;

  const int EW = (int)(NB / 256);             // 16384

  // convert inputs to bf16
  cvt_bf16<<<2048, 256, 0, stream>>>(h, h_bf, (int)NB);
  cvt_bf16<<<512, 256, 0, stream>>>(Wq, wq_bf, 1048576);
  cvt_bf16<<<512, 256, 0, stream>>>(Wk, wk_bf, 1048576);
  cvt_bf16<<<512, 256, 0, stream>>>(Wv, wv_bf, 1048576);
  cvt_bf16<<<512, 256, 0, stream>>>(Wg, wg_bf, 1048576);
  cvt_bf16<<<512, 256, 0, stream>>>(Wo, wo_bf, 1048576);

  // 4 projection GEMMs (MFMA bf16)
  gemm_bf16_4<<<dim3(32, 32), 256, 0, stream>>>(h_bf, wq_bf, wk_bf, wv_bf, wg_bf,
                                                 qp, kp, vp, gvp);
  smallproj<<<B_ * T_, 256, 0, stream>>>(h, Wa, Wb, Alog, dtb, gb, bb);

  conv_silu<<<EW, 256, 0, stream>>>(qp, cqw, qc);
  conv_silu<<<EW, 256, 0, stream>>>(kp, ckw, kc);
  conv_silu<<<EW, 256, 0, stream>>>(vp, cvw, vc);

  headnorm<<<EW, 256, 0, stream>>>(qc, qnw, 0.125f);
  headnorm<<<EW, 256, 0, stream>>>(kc, knw, 1.0f);

  p1_chunk<<<B_*H_*NC_, 256, 0, stream>>>(kc, vc, gb, bb, Ubuf, Wbuf, Gc);
  p1b_mn<<<B_*H_*NC_, 256, 0, stream>>>(kc, Gc, Ubuf, Wbuf, Mbuf, Nbuf);
  p2_state<<<B_*H_*2, 256, 0, stream>>>(Mbuf, Nbuf, S0b);
  p3_out<<<B_*H_*NC_, 256, 0, stream>>>(qc, kc, Gc, S0b, Ubuf, Wbuf, out);

  ogate<<<EW, 256, 0, stream>>>(out, gvp, onw, og_bf);
  gemm_bf16_1<<<dim3(32, 8), 256, 0, stream>>>(og_bf, wo_bf, out);
}

// Round 5
// 483.083 us; speedup vs baseline: 8.3530x; 1.0633x over previous
//
#include <hip/hip_runtime.h>
#include <cstdint>
#include <cstddef>

#define B_ 2
#define T_ 2048
#define D_ 1024
#define H_ 16
#define HD_ 64
#define NC_ 32

typedef unsigned short u16;
typedef __attribute__((ext_vector_type(8))) short bf16x8;
typedef __attribute__((ext_vector_type(4))) float f32x4;

__device__ __forceinline__ float dot4(float4 a, float4 b, float acc) {
  return fmaf(a.x, b.x, fmaf(a.y, b.y, fmaf(a.z, b.z, fmaf(a.w, b.w, acc))));
}
__device__ __forceinline__ float ndot4(float4 a, float4 b, float acc) {
  return fmaf(-a.x, b.x, fmaf(-a.y, b.y, fmaf(-a.z, b.z, fmaf(-a.w, b.w, acc))));
}
__device__ __forceinline__ u16 f2bf(float f) {
  unsigned u = __float_as_uint(f);
  u += 0x7fffu + ((u >> 16) & 1u);
  return (u16)(u >> 16);
}
__device__ __forceinline__ void glds16(const u16* g, u16* l) {
  __builtin_amdgcn_global_load_lds(
      (const __attribute__((address_space(1))) void*)g,
      (__attribute__((address_space(3))) void*)l, 16, 0, 0);
}

// ---------------- fp32 -> bf16 conversion (h + 5 weights, one launch) ----------------
__global__ __launch_bounds__(256) void cvt_all(
    const float* __restrict__ h, const float* __restrict__ w0,
    const float* __restrict__ w1, const float* __restrict__ w2,
    const float* __restrict__ w3, const float* __restrict__ w4,
    u16* __restrict__ h_bf, u16* __restrict__ wb)
{
  const int blk = blockIdx.x;
  const float* src;
  u16* dst;
  int lb;
  if (blk < 2048) { src = h; dst = h_bf; lb = blk; }
  else {
    int k = (blk - 2048) >> 9, r = (blk - 2048) & 511;
    src = k == 0 ? w0 : k == 1 ? w1 : k == 2 ? w2 : k == 3 ? w3 : w4;
    dst = wb + (size_t)k * 1048576;
    lb = r;
  }
  int i = (lb * 256 + threadIdx.x) * 8;
  float4 v0 = *(const float4*)(src + i);
  float4 v1 = *(const float4*)(src + i + 4);
  union { u16 us[8]; uint4 u4; } p;
  p.us[0] = f2bf(v0.x); p.us[1] = f2bf(v0.y); p.us[2] = f2bf(v0.z); p.us[3] = f2bf(v0.w);
  p.us[4] = f2bf(v1.x); p.us[5] = f2bf(v1.y); p.us[6] = f2bf(v1.z); p.us[7] = f2bf(v1.w);
  *(uint4*)(dst + i) = p.u4;
}

// ---------------- bf16 MFMA GEMM core (m97-style: global_load_lds, linear LDS) ----------------
// 128x128 tile, BK=32, 256 threads (4 waves, 2x2 quadrants)
__device__ __forceinline__ void gemm_core(const u16* __restrict__ A,
    const u16* __restrict__ Bw, float* __restrict__ C,
    u16* As, u16* Bs, int row0, int col0, int K, int N)
{
  const int tid = threadIdx.x;
  const int lane = tid & 63, wave = tid >> 6;
  const int wr = (wave >> 1) * 64, wc = (wave & 1) * 64;
  const int lr = lane & 15, lk = (lane >> 4) * 8;
  // staging: 8 wave-calls of 16 rows each; rb in {wave, wave+4}
  const int rql = (lane >> 2);          // row within 16-row block
  const int cql = (lane & 3) * 8;       // col (u16) within 32-col row
  const u16* gA0 = A + (size_t)(row0 + wave * 16 + rql) * K + cql;
  const u16* gA1 = A + (size_t)(row0 + (wave + 4) * 16 + rql) * K + cql;
  const u16* gB0 = Bw + (size_t)(col0 + wave * 16 + rql) * K + cql;
  const u16* gB1 = Bw + (size_t)(col0 + (wave + 4) * 16 + rql) * K + cql;
  u16* lA0 = As + wave * 16 * 32;
  u16* lA1 = As + (wave + 4) * 16 * 32;
  u16* lB0 = Bs + wave * 16 * 32;
  u16* lB1 = Bs + (wave + 4) * 16 * 32;

  f32x4 acc[4][4];
  #pragma unroll
  for (int i = 0; i < 4; ++i)
    #pragma unroll
    for (int j = 0; j < 4; ++j) acc[i][j] = f32x4{0.f, 0.f, 0.f, 0.f};

  const int KT = K >> 5;
  for (int kt = 0; kt < KT; ++kt) {
    glds16(gA0 + kt * 32, lA0);
    glds16(gA1 + kt * 32, lA1);
    glds16(gB0 + kt * 32, lB0);
    glds16(gB1 + kt * 32, lB1);
    __syncthreads();
    bf16x8 af[4], bf[4];
    #pragma unroll
    for (int i = 0; i < 4; ++i) af[i] = *(const bf16x8*)&As[(wr + i * 16 + lr) * 32 + lk];
    #pragma unroll
    for (int j = 0; j < 4; ++j) bf[j] = *(const bf16x8*)&Bs[(wc + j * 16 + lr) * 32 + lk];
    #pragma unroll
    for (int i = 0; i < 4; ++i)
      #pragma unroll
      for (int j = 0; j < 4; ++j)
        acc[i][j] = __builtin_amdgcn_mfma_f32_16x16x32_bf16(af[i], bf[j], acc[i][j], 0, 0, 0);
    __syncthreads();
  }
  const int orow = row0 + wr + (lane >> 4) * 4;
  const int ocol = col0 + wc + lr;
  #pragma unroll
  for (int i = 0; i < 4; ++i)
    #pragma unroll
    for (int j = 0; j < 4; ++j)
      #pragma unroll
      for (int r = 0; r < 4; ++r)
        C[(size_t)(orow + i * 16 + r) * N + ocol + j * 16] = acc[i][j][r];
}

__global__ __launch_bounds__(256) void gemm_bf16_4(const u16* __restrict__ A,
    const u16* __restrict__ W0, const u16* __restrict__ W1,
    const u16* __restrict__ W2, const u16* __restrict__ W3,
    float* __restrict__ C0, float* __restrict__ C1,
    float* __restrict__ C2, float* __restrict__ C3)
{
  __shared__ u16 As[128 * 32];
  __shared__ u16 Bs[128 * 32];
  const int sel = blockIdx.y >> 3;
  const u16* Bw = sel == 0 ? W0 : sel == 1 ? W1 : sel == 2 ? W2 : W3;
  float* C = sel == 0 ? C0 : sel == 1 ? C1 : sel == 2 ? C2 : C3;
  gemm_core(A, Bw, C, As, Bs, blockIdx.x * 128, (blockIdx.y & 7) * 128, 1024, 1024);
}

__global__ __launch_bounds__(256) void gemm_bf16_1(const u16* __restrict__ A,
    const u16* __restrict__ Bw, float* __restrict__ C)
{
  __shared__ u16 As[128 * 32];
  __shared__ u16 Bs[128 * 32];
  gemm_core(A, Bw, C, As, Bs, blockIdx.x * 128, blockIdx.y * 128, 1024, 1024);
}

// ---------------- beta / g small projections ----------------
__global__ __launch_bounds__(256) void smallproj(const float* __restrict__ Hs,
    const float* __restrict__ Wa, const float* __restrict__ Wb,
    const float* __restrict__ Alog, const float* __restrict__ dtb,
    float* __restrict__ Gout, float* __restrict__ Bout)
{
  __shared__ float hs[D_];
  const int bt = blockIdx.x;
  for (int i = threadIdx.x; i < D_; i += 256) hs[i] = Hs[(size_t)bt * D_ + i];
  __syncthreads();
  const int grp = threadIdx.x >> 3, p = threadIdx.x & 7;
  const int head = grp & 15, which = grp >> 4;
  const float* Wr = (which ? Wb : Wa) + head * D_;
  float s = 0.f;
  for (int i = p; i < D_; i += 8) s = fmaf(hs[i], Wr[i], s);
  s += __shfl_xor(s, 1); s += __shfl_xor(s, 2); s += __shfl_xor(s, 4);
  if (p == 0) {
    if (which) {
      Bout[(size_t)bt * H_ + head] = 1.f / (1.f + __expf(-s));
    } else {
      float x = s + dtb[head];
      float sp = fmaxf(x, 0.f) + log1pf(__expf(-fabsf(x)));
      Gout[(size_t)bt * H_ + head] = -__expf(Alog[head]) * sp;
    }
  }
}

// ---------------- fused causal conv(K=4)+SiLU [+ RMSNorm+L2norm] ----------------
// grid: b*16*32 + h*32 + tt (one block = one head x 64 timesteps)
template<int NORM>
__global__ __launch_bounds__(256) void convnorm(const float* __restrict__ X,
    const float* __restrict__ W, const float* __restrict__ nw, float fs,
    float* __restrict__ Y)
{
  __shared__ float Xs[67][65];
  __shared__ float nwS[64];
  const int blk = blockIdx.x;
  const int tt = blk & 31, hh = (blk >> 5) & 15, b = blk >> 9;
  const int t0 = tt * 64;
  const int d = threadIdx.x & 63, tq = threadIdx.x >> 6;
  for (int e = threadIdx.x; e < 67 * 64; e += 256) {
    int r = e >> 6, dd = e & 63;
    int t = t0 - 3 + r;
    Xs[r][dd] = (t >= 0) ? X[((size_t)b * T_ + t) * D_ + hh * 64 + dd] : 0.f;
  }
  if (NORM && threadIdx.x < 64) nwS[threadIdx.x] = nw[threadIdx.x];
  __syncthreads();
  const float4 w = *(const float4*)(W + (hh * 64 + d) * 4);
  #pragma unroll 4
  for (int it = 0; it < 16; ++it) {
    const int lt = tq * 16 + it;   // local t; x[t] = Xs[lt+3]
    float a = fmaf(w.x, Xs[lt][d], fmaf(w.y, Xs[lt + 1][d],
              fmaf(w.z, Xs[lt + 2][d], w.w * Xs[lt + 3][d])));
    float y = a / (1.f + __expf(-a));
    if (NORM) {
      float ss = y * y;
      #pragma unroll
      for (int m = 1; m < 64; m <<= 1) ss += __shfl_xor(ss, m);
      float z = y * rsqrtf(ss * (1.f / 64.f) + 1e-6f) * nwS[d];
      float s2 = z * z;
      #pragma unroll
      for (int m = 1; m < 64; m <<= 1) s2 += __shfl_xor(s2, m);
      y = z * rsqrtf(s2 + 1e-6f) * fs;
    }
    Y[((size_t)b * T_ + t0 + lt) * D_ + hh * 64 + d] = y;
  }
}

// ---------------- P1: per-chunk A, triangular solve -> U, W ----------------
__global__ __launch_bounds__(256) void p1_chunk(
    const float* __restrict__ Kc, const float* __restrict__ Vc,
    const float* __restrict__ Gg, const float* __restrict__ Bb,
    float* __restrict__ Ubuf, float* __restrict__ Wbuf, float* __restrict__ Gcum)
{
  __shared__ float Ks[64][68];
  __shared__ float Am[64][68];
  __shared__ float XT[128][68];
  __shared__ float gc[64], bet[64];
  const int bhc = blockIdx.x;
  const int bh = bhc >> 5, c = bhc & 31;
  const int b = bh >> 4, h = bh & 15;
  const int tid = threadIdx.x;
  const size_t rowbase = ((size_t)b*T_ + c*64)*H_ + h;

  if (tid < 64) {
    float gv = Gg[rowbase + (size_t)tid*H_];
    #pragma unroll
    for (int off = 1; off < 64; off <<= 1) {
      float up = __shfl_up(gv, off, 64);
      if (tid >= off) gv += up;
    }
    gc[tid] = gv;
    Gcum[(size_t)bhc*64 + tid] = gv;
    bet[tid] = Bb[rowbase + (size_t)tid*H_];
  }
  for (int e = tid; e < 4096; e += 256) {
    int t = e >> 6, d = e & 63;
    Ks[t][d] = Kc[(rowbase + (size_t)t*H_)*64 + d];
  }
  __syncthreads();

  {
    const int t = tid & 63, s0 = (tid >> 6) << 4;
    float acc[16];
    #pragma unroll
    for (int m = 0; m < 16; ++m) acc[m] = 0.f;
    for (int i = 0; i < 64; i += 4) {
      float4 kt = *(const float4*)&Ks[t][i];
      #pragma unroll
      for (int m = 0; m < 16; ++m) {
        float4 ks = *(const float4*)&Ks[s0+m][i];
        acc[m] = dot4(kt, ks, acc[m]);
      }
    }
    const float bt = bet[t], gt = gc[t];
    #pragma unroll
    for (int m = 0; m < 16; ++m) {
      int s = s0 + m;
      Am[t][s] = (s < t) ? bt * __expf(gt - gc[s]) * acc[m] : 0.f;
    }
  }
  for (int e = tid; e < 4096; e += 256) {
    int t = e >> 6, j = e & 63;
    float btv = bet[t];
    XT[j][t]    = btv * Vc[(rowbase + (size_t)t*H_)*64 + j];
    XT[64+j][t] = btv * __expf(gc[t]) * Ks[t][j];
  }
  __syncthreads();

  if (tid < 128) {
    for (int t = 1; t < 64; ++t) {
      float a0=0,a1=0,a2=0,a3=0;
      const int qmax = t >> 2;
      for (int q = 0; q <= qmax; ++q) {
        float4 av = *(const float4*)&Am[t][q*4];
        float4 xv = *(const float4*)&XT[tid][q*4];
        a0 = fmaf(av.x, xv.x, a0);
        a1 = fmaf(av.y, xv.y, a1);
        a2 = fmaf(av.z, xv.z, a2);
        a3 = fmaf(av.w, xv.w, a3);
      }
      XT[tid][t] -= (a0+a1)+(a2+a3);
    }
  }
  __syncthreads();
  for (int e = tid; e < 4096; e += 256) {
    int t = e >> 6, j = e & 63;
    Ubuf[(size_t)bhc*4096 + e] = XT[j][t];
    Wbuf[(size_t)bhc*4096 + e] = XT[64+j][t];
  }
}

// ---------------- P1b: per-chunk transition M = bC*I - Ksc^T W, N = Ksc^T U ----------------
__global__ __launch_bounds__(256) void p1b_mn(
    const float* __restrict__ Kc, const float* __restrict__ Gcum,
    const float* __restrict__ Ubuf, const float* __restrict__ Wbuf,
    float* __restrict__ Mbuf, float* __restrict__ Nbuf)
{
  __shared__ float Ksc[64][68];
  __shared__ float Wl[64][68];
  __shared__ float Ul[64][68];
  __shared__ float gcs[64];
  const int bhc = blockIdx.x;
  const int bh = bhc >> 5, c = bhc & 31;
  const int b = bh >> 4, h = bh & 15;
  const int tid = threadIdx.x;
  const size_t rowbase = ((size_t)b*T_ + c*64)*H_ + h;
  if (tid < 64) gcs[tid] = Gcum[(size_t)bhc*64 + tid];
  __syncthreads();
  const float gC = gcs[63];
  for (int e = tid; e < 4096; e += 256) {
    int t = e >> 6, i = e & 63;
    Ksc[t][i] = __expf(gC - gcs[t]) * Kc[(rowbase + (size_t)t*H_)*64 + i];
  }
  for (int e4 = tid; e4 < 1024; e4 += 256) {
    int t = e4 >> 4, i4 = (e4 & 15) * 4;
    *(float4*)&Wl[t][i4] = *(const float4*)&Wbuf[(size_t)bhc*4096 + (size_t)t*64 + i4];
    *(float4*)&Ul[t][i4] = *(const float4*)&Ubuf[(size_t)bhc*4096 + (size_t)t*64 + i4];
  }
  __syncthreads();
  const int a0 = (tid >> 4) * 4, c0 = (tid & 15) * 4;
  float accM[4][4] = {}, accN[4][4] = {};
  for (int t = 0; t < 64; ++t) {
    float4 kv = *(const float4*)&Ksc[t][a0];
    float4 wv = *(const float4*)&Wl[t][c0];
    float4 uv = *(const float4*)&Ul[t][c0];
    const float ka[4] = {kv.x, kv.y, kv.z, kv.w};
    const float wa[4] = {wv.x, wv.y, wv.z, wv.w};
    const float ua[4] = {uv.x, uv.y, uv.z, uv.w};
    #pragma unroll
    for (int r = 0; r < 4; ++r)
      #pragma unroll
      for (int m = 0; m < 4; ++m) {
        accM[r][m] = fmaf(ka[r], wa[m], accM[r][m]);
        accN[r][m] = fmaf(ka[r], ua[m], accN[r][m]);
      }
  }
  const float bC = __expf(gC);
  const size_t ob = (size_t)bhc * 4096;
  #pragma unroll
  for (int r = 0; r < 4; ++r) {
    int a = a0 + r;
    float4 mo = { (a==c0+0?bC:0.f)-accM[r][0], (a==c0+1?bC:0.f)-accM[r][1],
                  (a==c0+2?bC:0.f)-accM[r][2], (a==c0+3?bC:0.f)-accM[r][3] };
    float4 no = { accN[r][0], accN[r][1], accN[r][2], accN[r][3] };
    *(float4*)&Mbuf[ob + (size_t)a*64 + c0] = mo;
    *(float4*)&Nbuf[ob + (size_t)a*64 + c0] = no;
  }
}

// ---------------- P1c: compose chunk pairs in place (odd slots <- pair) ----------------
// Mbuf[2p+1] <- M[2p+1] @ M[2p];  Nbuf[2p+1] <- M[2p+1] @ N[2p] + N[2p+1]
__global__ __launch_bounds__(256) void p1c_pair(float* __restrict__ Mbuf,
    float* __restrict__ Nbuf)
{
  __shared__ float M2s[64][68];
  __shared__ float Ys[64][68];
  const int bhp = blockIdx.x;
  const int bh = bhp >> 4, p = bhp & 15;
  const size_t c1 = ((size_t)bh * 32 + 2 * p) * 4096, c2 = c1 + 4096;
  const int tid = threadIdx.x;
  const int r0 = (tid >> 4) * 4, c0 = (tid & 15) * 4;
  for (int e4 = tid; e4 < 1024; e4 += 256) {
    int t = e4 >> 4, i4 = (e4 & 15) * 4;
    *(float4*)&M2s[t][i4] = *(const float4*)&Mbuf[c2 + (size_t)t*64 + i4];
    *(float4*)&Ys[t][i4]  = *(const float4*)&Nbuf[c1 + (size_t)t*64 + i4];
  }
  float accN[4][4];
  #pragma unroll
  for (int r = 0; r < 4; ++r) {
    float4 v = *(const float4*)&Nbuf[c2 + (size_t)(r0+r)*64 + c0];
    accN[r][0]=v.x; accN[r][1]=v.y; accN[r][2]=v.z; accN[r][3]=v.w;
  }
  __syncthreads();
  for (int i4 = 0; i4 < 64; i4 += 4) {
    float aa[4][4], ya[4][4];
    #pragma unroll
    for (int r = 0; r < 4; ++r) {
      float4 v = *(const float4*)&M2s[r0+r][i4];
      aa[r][0]=v.x; aa[r][1]=v.y; aa[r][2]=v.z; aa[r][3]=v.w;
    }
    #pragma unroll
    for (int m = 0; m < 4; ++m) {
      float4 v = *(const float4*)&Ys[i4+m][c0];
      ya[m][0]=v.x; ya[m][1]=v.y; ya[m][2]=v.z; ya[m][3]=v.w;
    }
    #pragma unroll
    for (int r = 0; r < 4; ++r)
      #pragma unroll
      for (int m = 0; m < 4; ++m)
        #pragma unroll
        for (int cc = 0; cc < 4; ++cc)
          accN[r][cc] = fmaf(aa[r][m], ya[m][cc], accN[r][cc]);
  }
  #pragma unroll
  for (int r = 0; r < 4; ++r) {
    float4 v = {accN[r][0], accN[r][1], accN[r][2], accN[r][3]};
    *(float4*)&Nbuf[c2 + (size_t)(r0+r)*64 + c0] = v;
  }
  __syncthreads();   // all reads of Ys (N1) done
  for (int e4 = tid; e4 < 1024; e4 += 256) {
    int t = e4 >> 4, i4 = (e4 & 15) * 4;
    *(float4*)&Ys[t][i4] = *(const float4*)&Mbuf[c1 + (size_t)t*64 + i4];
  }
  float accM[4][4] = {};
  __syncthreads();
  for (int i4 = 0; i4 < 64; i4 += 4) {
    float aa[4][4], ya[4][4];
    #pragma unroll
    for (int r = 0; r < 4; ++r) {
      float4 v = *(const float4*)&M2s[r0+r][i4];
      aa[r][0]=v.x; aa[r][1]=v.y; aa[r][2]=v.z; aa[r][3]=v.w;
    }
    #pragma unroll
    for (int m = 0; m < 4; ++m) {
      float4 v = *(const float4*)&Ys[i4+m][c0];
      ya[m][0]=v.x; ya[m][1]=v.y; ya[m][2]=v.z; ya[m][3]=v.w;
    }
    #pragma unroll
    for (int r = 0; r < 4; ++r)
      #pragma unroll
      for (int m = 0; m < 4; ++m)
        #pragma unroll
        for (int cc = 0; cc < 4; ++cc)
          accM[r][cc] = fmaf(aa[r][m], ya[m][cc], accM[r][cc]);
  }
  #pragma unroll
  for (int r = 0; r < 4; ++r) {
    float4 v = {accM[r][0], accM[r][1], accM[r][2], accM[r][3]};
    *(float4*)&Mbuf[c2 + (size_t)(r0+r)*64 + c0] = v;
  }
}

// ---------------- P2: 16 serial pair-steps; carry + off-path mid state ----------------
__global__ __launch_bounds__(256) void p2_state(
    const float* __restrict__ Mbuf, const float* __restrict__ Nbuf,
    float* __restrict__ S0b)
{
  __shared__ float ST[2][32][68];   // S^T slice [jl][i], XOR-swizzled i-groups
  __shared__ float Mp_s[64][68];    // composed pair M (carry)
  __shared__ float M1_s[64][68];    // first-of-pair M (mid)
  const int bh = blockIdx.x >> 1, js = blockIdx.x & 1;
  const int tid = threadIdx.x;
  const int a0 = (tid >> 4) * 4;
  const int jl0 = (tid & 15) * 2;
  const size_t base = (size_t)bh * NC_ * 4096;
  for (int e4 = tid; e4 < 32 * 17; e4 += 256)
    ((float4*)&ST[0][0][0])[e4] = float4{0.f, 0.f, 0.f, 0.f};
  #pragma unroll
  for (int r = 0; r < 4; ++r) {
    int e4 = tid + r * 256;
    int t = e4 >> 4, i4 = (e4 & 15) * 4;
    *(float4*)&Mp_s[t][i4] = *(const float4*)&Mbuf[base + 4096 + (size_t)t*64 + i4];
    *(float4*)&M1_s[t][i4] = *(const float4*)&Mbuf[base + (size_t)t*64 + i4];
  }
  float2 nP[4], n1[4];
  #pragma unroll
  for (int r = 0; r < 4; ++r) {
    nP[r] = *(const float2*)&Nbuf[base + 4096 + (size_t)(a0+r)*64 + js*32 + jl0];
    n1[r] = *(const float2*)&Nbuf[base + (size_t)(a0+r)*64 + js*32 + jl0];
  }
  __syncthreads();
  for (int p = 0; p < 16; ++p) {
    const int cur = p & 1, nxt = cur ^ 1;
    const size_t cb = base + (size_t)(2 * p) * 4096;
    float4 mpre[4], m1pre[4];
    float2 nPn[4], n1n[4];
    const bool hn = (p + 1 < 16);
    if (hn) {
      #pragma unroll
      for (int r = 0; r < 4; ++r) {
        int e4 = tid + r * 256;
        int t = e4 >> 4, i4 = (e4 & 15) * 4;
        mpre[r]  = *(const float4*)&Mbuf[cb + 3*4096 + (size_t)t*64 + i4];
        m1pre[r] = *(const float4*)&Mbuf[cb + 2*4096 + (size_t)t*64 + i4];
        nPn[r] = *(const float2*)&Nbuf[cb + 3*4096 + (size_t)(a0+r)*64 + js*32 + jl0];
        n1n[r] = *(const float2*)&Nbuf[cb + 2*4096 + (size_t)(a0+r)*64 + js*32 + jl0];
      }
    }
    // write S0 of even chunk (current carry state)
    #pragma unroll
    for (int r = 0; r < 2; ++r) {
      int e4 = tid + r * 256;
      int jl = e4 >> 4, i4 = (e4 & 15) * 4;
      int gs = ((i4 >> 2) ^ ((jl >> 1) & 7)) * 4;
      *(float4*)&S0b[cb + (size_t)(js*32 + jl)*64 + i4] = *(const float4*)&ST[cur][jl][gs];
    }
    // carry = Mp@S + Np ; mid = M1@S + N1 (shared S reads)
    float ca[4][2], mi[4][2];
    #pragma unroll
    for (int r = 0; r < 4; ++r) {
      ca[r][0] = nP[r].x; ca[r][1] = nP[r].y;
      mi[r][0] = n1[r].x; mi[r][1] = n1[r].y;
    }
    for (int i4 = 0; i4 < 64; i4 += 4) {
      float4 sv[2];
      #pragma unroll
      for (int m = 0; m < 2; ++m) {
        int jl = jl0 + m;
        sv[m] = *(const float4*)&ST[cur][jl][((i4 >> 2) ^ ((jl >> 1) & 7)) * 4];
      }
      #pragma unroll
      for (int r = 0; r < 4; ++r) {
        float4 mp  = *(const float4*)&Mp_s[a0 + r][i4];
        float4 m1v = *(const float4*)&M1_s[a0 + r][i4];
        ca[r][0] = dot4(mp, sv[0], ca[r][0]);
        ca[r][1] = dot4(mp, sv[1], ca[r][1]);
        mi[r][0] = dot4(m1v, sv[0], mi[r][0]);
        mi[r][1] = dot4(m1v, sv[1], mi[r][1]);
      }
    }
    // write S0 of odd chunk (mid state), coalesced float4 along i
    #pragma unroll
    for (int m = 0; m < 2; ++m) {
      float4 v = {mi[0][m], mi[1][m], mi[2][m], mi[3][m]};
      *(float4*)&S0b[cb + 4096 + (size_t)(js*32 + jl0 + m)*64 + a0] = v;
    }
    // write carry into ST[nxt] (swizzled)
    #pragma unroll
    for (int r = 0; r < 4; ++r)
      #pragma unroll
      for (int m = 0; m < 2; ++m) {
        int jl = jl0 + m, a = a0 + r;
        ST[nxt][jl][(((a >> 2) ^ ((jl >> 1) & 7)) << 2) + (a & 3)] = ca[r][m];
      }
    __syncthreads();   // B1: Mp_s/M1_s/ST[cur] reads complete
    if (hn) {
      #pragma unroll
      for (int r = 0; r < 4; ++r) {
        int e4 = tid + r * 256;
        int t = e4 >> 4, i4 = (e4 & 15) * 4;
        *(float4*)&Mp_s[t][i4] = mpre[r];
        *(float4*)&M1_s[t][i4] = m1pre[r];
        nP[r] = nPn[r]; n1[r] = n1n[r];
      }
    }
    __syncthreads();   // B2: new M's visible
  }
}

// ---------------- P3: delta + outputs ----------------
__global__ __launch_bounds__(256) void p3_out(
    const float* __restrict__ Qc, const float* __restrict__ Kc,
    const float* __restrict__ Gcum, const float* __restrict__ S0b,
    const float* __restrict__ Ubuf, const float* __restrict__ Wbuf,
    float* __restrict__ O)
{
  __shared__ float Qs[64][68];
  __shared__ float KDs[64][68];
  __shared__ float PT[64][68];
  __shared__ float Ws[64][68];
  __shared__ float gcs[64];
  const int bhc = blockIdx.x;
  const int bh = bhc >> 5, c = bhc & 31;
  const int b = bh >> 4, h = bh & 15;
  const int tid = threadIdx.x;
  const size_t rowbase = ((size_t)b*T_ + c*64)*H_ + h;
  if (tid < 64) gcs[tid] = Gcum[(size_t)bhc*64 + tid];
  for (int e = tid; e < 4096; e += 256) {
    int r = e >> 6, d = e & 63;
    size_t ga = (rowbase + (size_t)r*H_)*64 + d;
    Qs[r][d]  = Qc[ga];
    KDs[r][d] = Kc[ga];
    PT[r][d]  = S0b[(size_t)bhc*4096 + e];
    Ws[r][d]  = Wbuf[(size_t)bhc*4096 + e];
  }
  __syncthreads();
  const int lane = tid & 63, wq = tid >> 6;
  float oacc[16], preg[16];
  #pragma unroll
  for (int it = 0; it < 16; ++it) { oacc[it] = 0.f; preg[it] = 0.f; }

  for (int i = 0; i < 64; i += 4) {
    float4 sv = *(const float4*)&PT[lane][i];
    #pragma unroll
    for (int it = 0; it < 16; ++it) {
      float4 qv = *(const float4*)&Qs[it*4 + wq][i];
      oacc[it] = dot4(qv, sv, oacc[it]);
    }
  }
  #pragma unroll
  for (int it = 0; it < 16; ++it) oacc[it] *= __expf(gcs[it*4 + wq]);

  for (int i = 0; i < 64; i += 4) {
    float4 kv = *(const float4*)&KDs[lane][i];
    #pragma unroll
    for (int it = 0; it < 16; ++it) {
      float4 qv = *(const float4*)&Qs[it*4 + wq][i];
      preg[it] = dot4(qv, kv, preg[it]);
    }
  }
  {
    const float gsl = gcs[lane];
    #pragma unroll
    for (int it = 0; it < 16; ++it) {
      int t = it*4 + wq;
      preg[it] = (lane <= t) ? __expf(gcs[t] - gsl) * preg[it] : 0.f;
    }
  }

  const int dt0 = (tid >> 4) << 2, dj0 = (tid & 15) << 2;
  float dacc[4][4];
  #pragma unroll
  for (int r = 0; r < 4; ++r) {
    float4 uv = *(const float4*)&Ubuf[(size_t)bhc*4096 + (size_t)(dt0+r)*64 + dj0];
    dacc[r][0] = uv.x; dacc[r][1] = uv.y; dacc[r][2] = uv.z; dacc[r][3] = uv.w;
  }
  for (int i = 0; i < 64; i += 4) {
    float4 wv[4], sv[4];
    #pragma unroll
    for (int r = 0; r < 4; ++r) wv[r] = *(const float4*)&Ws[dt0+r][i];
    #pragma unroll
    for (int m = 0; m < 4; ++m) sv[m] = *(const float4*)&PT[dj0+m][i];
    #pragma unroll
    for (int r = 0; r < 4; ++r)
      #pragma unroll
      for (int m = 0; m < 4; ++m)
        dacc[r][m] = ndot4(wv[r], sv[m], dacc[r][m]);
  }
  __syncthreads();
  #pragma unroll
  for (int it = 0; it < 16; ++it) PT[it*4 + wq][lane] = preg[it];
  #pragma unroll
  for (int r = 0; r < 4; ++r)
    #pragma unroll
    for (int m = 0; m < 4; ++m)
      KDs[dj0+m][dt0+r] = dacc[r][m];
  __syncthreads();

  for (int s = 0; s < 64; s += 4) {
    float4 dv = *(const float4*)&KDs[lane][s];
    #pragma unroll
    for (int it = 0; it < 16; ++it) {
      float4 pv = *(const float4*)&PT[it*4 + wq][s];
      oacc[it] = dot4(pv, dv, oacc[it]);
    }
  }
  #pragma unroll
  for (int it = 0; it < 16; ++it) {
    int t = it*4 + wq;
    O[(rowbase + (size_t)t*H_)*64 + lane] = oacc[it];
  }
}

// ---------------- o-norm * swish(gv) -> bf16 ----------------
__global__ __launch_bounds__(256) void ogate(const float* __restrict__ O,
    const float* __restrict__ GV, const float* __restrict__ w,
    u16* __restrict__ OG)
{
  const size_t gid = (size_t)blockIdx.x * 256 + threadIdx.x;
  const size_t vec = gid >> 6;
  const int lane = threadIdx.x & 63;
  float x = O[vec * 64 + lane];
  float ss = x * x;
  #pragma unroll
  for (int m = 1; m < 64; m <<= 1) ss += __shfl_xor(ss, m);
  float y = x * rsqrtf(ss * (1.f/64.f) + 1e-6f) * w[lane];
  float gv = GV[vec * 64 + lane];
  OG[vec * 64 + lane] = f2bf(y * gv / (1.f + __expf(-gv)));
}

extern "C" void kernel_launch(void* const* d_in, const int* in_sizes, int n_in,
                              void* d_out, int out_size, void* d_ws, size_t ws_size,
                              hipStream_t stream) {
  const float* h    = (const float*)d_in[0];
  const float* Wq   = (const float*)d_in[1];
  const float* Wk   = (const float*)d_in[2];
  const float* Wv   = (const float*)d_in[3];
  const float* Wa   = (const float*)d_in[4];
  const float* Wb   = (const float*)d_in[5];
  const float* Wg   = (const float*)d_in[6];
  const float* Wo   = (const float*)d_in[7];
  const float* qnw  = (const float*)d_in[8];
  const float* knw  = (const float*)d_in[9];
  const float* onw  = (const float*)d_in[10];
  const float* Alog = (const float*)d_in[11];
  const float* dtb  = (const float*)d_in[12];
  const float* cqw  = (const float*)d_in[13];
  const float* ckw  = (const float*)d_in[14];
  const float* cvw  = (const float*)d_in[15];
  float* out = (float*)d_out;
  float* ws  = (float*)d_ws;

  const size_t NB = (size_t)B_ * T_ * D_;     // 4,194,304
  float* qp   = ws;                           // -> Ubuf
  float* kp   = ws + 1*NB;                    // -> Wbuf
  float* vp   = ws + 2*NB;                    // -> S0b
  float* gvp  = ws + 3*NB;
  float* qc   = ws + 4*NB;
  float* kc   = ws + 5*NB;
  float* vc   = ws + 6*NB;                    // -> Nbuf
  float* mb   = ws + 7*NB;                    // h_bf / Mbuf / og_bf
  float* wbf  = ws + 8*NB;                    // bf16 weights (5 x 1M u16)
  float* gb   = ws + 8*NB + 5*524288;
  float* bb   = gb + (size_t)B_*T_*H_;
  float* Gc   = bb + (size_t)B_*T_*H_;

  u16* h_bf  = (u16*)mb;
  u16* og_bf = (u16*)mb;
  u16* w_bf  = (u16*)wbf;
  u16* wq_bf = w_bf + 0*1048576;
  u16* wk_bf = w_bf + 1*1048576;
  u16* wv_bf = w_bf + 2*1048576;
  u16* wg_bf = w_bf + 3*1048576;
  u16* wo_bf = w_bf + 4*1048576;

  float* Ubuf = qp;
  float* Wbuf = kp;
  float* S0b  = vp;
  float* Mbuf = mb;
  float* Nbuf = vc;

  cvt_all<<<4608, 256, 0, stream>>>(h, Wq, Wk, Wv, Wg, Wo, h_bf, w_bf);

  gemm_bf16_4<<<dim3(32, 32), 256, 0, stream>>>(h_bf, wq_bf, wk_bf, wv_bf, wg_bf,
                                                 qp, kp, vp, gvp);
  smallproj<<<B_ * T_, 256, 0, stream>>>(h, Wa, Wb, Alog, dtb, gb, bb);

  convnorm<1><<<1024, 256, 0, stream>>>(qp, cqw, qnw, 0.125f, qc);
  convnorm<1><<<1024, 256, 0, stream>>>(kp, ckw, knw, 1.0f, kc);
  convnorm<0><<<1024, 256, 0, stream>>>(vp, cvw, qnw, 1.0f, vc);

  p1_chunk<<<B_*H_*NC_, 256, 0, stream>>>(kc, vc, gb, bb, Ubuf, Wbuf, Gc);
  p1b_mn<<<B_*H_*NC_, 256, 0, stream>>>(kc, Gc, Ubuf, Wbuf, Mbuf, Nbuf);
  p1c_pair<<<B_*H_*16, 256, 0, stream>>>(Mbuf, Nbuf);
  p2_state<<<B_*H_*2, 256, 0, stream>>>(Mbuf, Nbuf, S0b);
  p3_out<<<B_*H_*NC_, 256, 0, stream>>>(qc, kc, Gc, S0b, Ubuf, Wbuf, out);

  ogate<<<B_*T_*D_/256, 256, 0, stream>>>(out, gvp, onw, og_bf);
  gemm_bf16_1<<<dim3(32, 8), 256, 0, stream>>>(og_bf, wo_bf, out);
}

// Round 6
// 399.573 us; speedup vs baseline: 10.0988x; 1.2090x over previous
//
#include <hip/hip_runtime.h>
#include <cstdint>
#include <cstddef>

#define B_ 2
#define T_ 2048
#define D_ 1024
#define H_ 16
#define HD_ 64
#define NC_ 32

typedef unsigned short u16;
typedef __attribute__((ext_vector_type(8))) short bf16x8;
typedef __attribute__((ext_vector_type(4))) float f32x4;

__device__ __forceinline__ float dot4(float4 a, float4 b, float acc) {
  return fmaf(a.x, b.x, fmaf(a.y, b.y, fmaf(a.z, b.z, fmaf(a.w, b.w, acc))));
}
__device__ __forceinline__ float ndot4(float4 a, float4 b, float acc) {
  return fmaf(-a.x, b.x, fmaf(-a.y, b.y, fmaf(-a.z, b.z, fmaf(-a.w, b.w, acc))));
}
__device__ __forceinline__ u16 f2bf(float f) {
  unsigned u = __float_as_uint(f);
  u += 0x7fffu + ((u >> 16) & 1u);
  return (u16)(u >> 16);
}
__device__ __forceinline__ float bf2f(u16 v) {
  return __uint_as_float(((unsigned)v) << 16);
}
__device__ __forceinline__ bf16x8 pack8(float4 a, float4 b) {
  union { u16 us[8]; bf16x8 v; } p;
  p.us[0] = f2bf(a.x); p.us[1] = f2bf(a.y); p.us[2] = f2bf(a.z); p.us[3] = f2bf(a.w);
  p.us[4] = f2bf(b.x); p.us[5] = f2bf(b.y); p.us[6] = f2bf(b.z); p.us[7] = f2bf(b.w);
  return p.v;
}
__device__ __forceinline__ void glds16(const u16* g, u16* l) {
  __builtin_amdgcn_global_load_lds(
      (const __attribute__((address_space(1))) void*)g,
      (__attribute__((address_space(3))) void*)l, 16, 0, 0);
}

// ---------------- fp32 -> bf16 conversion (h + 5 weights, one launch) ----------------
__global__ __launch_bounds__(256) void cvt_all(
    const float* __restrict__ h, const float* __restrict__ w0,
    const float* __restrict__ w1, const float* __restrict__ w2,
    const float* __restrict__ w3, const float* __restrict__ w4,
    u16* __restrict__ h_bf, u16* __restrict__ wb)
{
  const int blk = blockIdx.x;
  const float* src;
  u16* dst;
  int lb;
  if (blk < 2048) { src = h; dst = h_bf; lb = blk; }
  else {
    int k = (blk - 2048) >> 9, r = (blk - 2048) & 511;
    src = k == 0 ? w0 : k == 1 ? w1 : k == 2 ? w2 : k == 3 ? w3 : w4;
    dst = wb + (size_t)k * 1048576;
    lb = r;
  }
  int i = (lb * 256 + threadIdx.x) * 8;
  float4 v0 = *(const float4*)(src + i);
  float4 v1 = *(const float4*)(src + i + 4);
  union { u16 us[8]; uint4 u4; } p;
  p.us[0] = f2bf(v0.x); p.us[1] = f2bf(v0.y); p.us[2] = f2bf(v0.z); p.us[3] = f2bf(v0.w);
  p.us[4] = f2bf(v1.x); p.us[5] = f2bf(v1.y); p.us[6] = f2bf(v1.z); p.us[7] = f2bf(v1.w);
  *(uint4*)(dst + i) = p.u4;
}

// ---------------- bf16 MFMA GEMM core (m97-style: global_load_lds, linear LDS) ----------------
__device__ __forceinline__ void gemm_core(const u16* __restrict__ A,
    const u16* __restrict__ Bw, float* __restrict__ C,
    u16* As, u16* Bs, int row0, int col0, int K, int N)
{
  const int tid = threadIdx.x;
  const int lane = tid & 63, wave = tid >> 6;
  const int wr = (wave >> 1) * 64, wc = (wave & 1) * 64;
  const int lr = lane & 15, lk = (lane >> 4) * 8;
  const int rql = (lane >> 2);
  const int cql = (lane & 3) * 8;
  const u16* gA0 = A + (size_t)(row0 + wave * 16 + rql) * K + cql;
  const u16* gA1 = A + (size_t)(row0 + (wave + 4) * 16 + rql) * K + cql;
  const u16* gB0 = Bw + (size_t)(col0 + wave * 16 + rql) * K + cql;
  const u16* gB1 = Bw + (size_t)(col0 + (wave + 4) * 16 + rql) * K + cql;
  u16* lA0 = As + wave * 16 * 32;
  u16* lA1 = As + (wave + 4) * 16 * 32;
  u16* lB0 = Bs + wave * 16 * 32;
  u16* lB1 = Bs + (wave + 4) * 16 * 32;

  f32x4 acc[4][4];
  #pragma unroll
  for (int i = 0; i < 4; ++i)
    #pragma unroll
    for (int j = 0; j < 4; ++j) acc[i][j] = f32x4{0.f, 0.f, 0.f, 0.f};

  const int KT = K >> 5;
  for (int kt = 0; kt < KT; ++kt) {
    glds16(gA0 + kt * 32, lA0);
    glds16(gA1 + kt * 32, lA1);
    glds16(gB0 + kt * 32, lB0);
    glds16(gB1 + kt * 32, lB1);
    __syncthreads();
    bf16x8 af[4], bf[4];
    #pragma unroll
    for (int i = 0; i < 4; ++i) af[i] = *(const bf16x8*)&As[(wr + i * 16 + lr) * 32 + lk];
    #pragma unroll
    for (int j = 0; j < 4; ++j) bf[j] = *(const bf16x8*)&Bs[(wc + j * 16 + lr) * 32 + lk];
    #pragma unroll
    for (int i = 0; i < 4; ++i)
      #pragma unroll
      for (int j = 0; j < 4; ++j)
        acc[i][j] = __builtin_amdgcn_mfma_f32_16x16x32_bf16(af[i], bf[j], acc[i][j], 0, 0, 0);
    __syncthreads();
  }
  const int orow = row0 + wr + (lane >> 4) * 4;
  const int ocol = col0 + wc + lr;
  #pragma unroll
  for (int i = 0; i < 4; ++i)
    #pragma unroll
    for (int j = 0; j < 4; ++j)
      #pragma unroll
      for (int r = 0; r < 4; ++r)
        C[(size_t)(orow + i * 16 + r) * N + ocol + j * 16] = acc[i][j][r];
}

__global__ __launch_bounds__(256) void gemm_bf16_4(const u16* __restrict__ A,
    const u16* __restrict__ W0, const u16* __restrict__ W1,
    const u16* __restrict__ W2, const u16* __restrict__ W3,
    float* __restrict__ C0, float* __restrict__ C1,
    float* __restrict__ C2, float* __restrict__ C3)
{
  __shared__ u16 As[128 * 32];
  __shared__ u16 Bs[128 * 32];
  const int sel = blockIdx.y >> 3;
  const u16* Bw = sel == 0 ? W0 : sel == 1 ? W1 : sel == 2 ? W2 : W3;
  float* C = sel == 0 ? C0 : sel == 1 ? C1 : sel == 2 ? C2 : C3;
  gemm_core(A, Bw, C, As, Bs, blockIdx.x * 128, (blockIdx.y & 7) * 128, 1024, 1024);
}

__global__ __launch_bounds__(256) void gemm_bf16_1(const u16* __restrict__ A,
    const u16* __restrict__ Bw, float* __restrict__ C)
{
  __shared__ u16 As[128 * 32];
  __shared__ u16 Bs[128 * 32];
  gemm_core(A, Bw, C, As, Bs, blockIdx.x * 128, blockIdx.y * 128, 1024, 1024);
}

// ---------------- beta / g small projections ----------------
__global__ __launch_bounds__(256) void smallproj(const float* __restrict__ Hs,
    const float* __restrict__ Wa, const float* __restrict__ Wb,
    const float* __restrict__ Alog, const float* __restrict__ dtb,
    float* __restrict__ Gout, float* __restrict__ Bout)
{
  __shared__ float hs[D_];
  const int bt = blockIdx.x;
  for (int i = threadIdx.x; i < D_; i += 256) hs[i] = Hs[(size_t)bt * D_ + i];
  __syncthreads();
  const int grp = threadIdx.x >> 3, p = threadIdx.x & 7;
  const int head = grp & 15, which = grp >> 4;
  const float* Wr = (which ? Wb : Wa) + head * D_;
  float s = 0.f;
  for (int i = p; i < D_; i += 8) s = fmaf(hs[i], Wr[i], s);
  s += __shfl_xor(s, 1); s += __shfl_xor(s, 2); s += __shfl_xor(s, 4);
  if (p == 0) {
    if (which) {
      Bout[(size_t)bt * H_ + head] = 1.f / (1.f + __expf(-s));
    } else {
      float x = s + dtb[head];
      float sp = fmaxf(x, 0.f) + log1pf(__expf(-fabsf(x)));
      Gout[(size_t)bt * H_ + head] = -__expf(Alog[head]) * sp;
    }
  }
}

// ---------------- fused causal conv(K=4)+SiLU [+ RMSNorm+L2norm] ----------------
template<int NORM>
__global__ __launch_bounds__(256) void convnorm(const float* __restrict__ X,
    const float* __restrict__ W, const float* __restrict__ nw, float fs,
    float* __restrict__ Y)
{
  __shared__ float Xs[67][65];
  __shared__ float nwS[64];
  const int blk = blockIdx.x;
  const int tt = blk & 31, hh = (blk >> 5) & 15, b = blk >> 9;
  const int t0 = tt * 64;
  const int d = threadIdx.x & 63, tq = threadIdx.x >> 6;
  for (int e = threadIdx.x; e < 67 * 64; e += 256) {
    int r = e >> 6, dd = e & 63;
    int t = t0 - 3 + r;
    Xs[r][dd] = (t >= 0) ? X[((size_t)b * T_ + t) * D_ + hh * 64 + dd] : 0.f;
  }
  if (NORM && threadIdx.x < 64) nwS[threadIdx.x] = nw[threadIdx.x];
  __syncthreads();
  const float4 w = *(const float4*)(W + (hh * 64 + d) * 4);
  #pragma unroll 4
  for (int it = 0; it < 16; ++it) {
    const int lt = tq * 16 + it;
    float a = fmaf(w.x, Xs[lt][d], fmaf(w.y, Xs[lt + 1][d],
              fmaf(w.z, Xs[lt + 2][d], w.w * Xs[lt + 3][d])));
    float y = a / (1.f + __expf(-a));
    if (NORM) {
      float ss = y * y;
      #pragma unroll
      for (int m = 1; m < 64; m <<= 1) ss += __shfl_xor(ss, m);
      float z = y * rsqrtf(ss * (1.f / 64.f) + 1e-6f) * nwS[d];
      float s2 = z * z;
      #pragma unroll
      for (int m = 1; m < 64; m <<= 1) s2 += __shfl_xor(s2, m);
      y = z * rsqrtf(s2 + 1e-6f) * fs;
    }
    Y[((size_t)b * T_ + t0 + lt) * D_ + hh * 64 + d] = y;
  }
}

// ---------------- P1: MFMA A = scale(K K^T), blocked MFMA solve -> U, W ----------------
__global__ __launch_bounds__(256) void p1_chunk(
    const float* __restrict__ Kc, const float* __restrict__ Vc,
    const float* __restrict__ Gg, const float* __restrict__ Bb,
    float* __restrict__ Ubuf, float* __restrict__ Wbuf, float* __restrict__ Gcum)
{
  __shared__ u16 Kbf[64][72];
  __shared__ float Am[64][68];
  __shared__ float XT[128][68];   // XT[col][t]; cols 0..63 U-rhs, 64..127 W-rhs
  __shared__ float gc[64], bet[64];
  const int bhc = blockIdx.x;
  const int bh = bhc >> 5, c = bhc & 31;
  const int b = bh >> 4, h = bh & 15;
  const int tid = threadIdx.x;
  const int lane = tid & 63, wave = tid >> 6;
  const int lr = lane & 15, lkq = lane >> 4;
  const size_t rowbase = ((size_t)b*T_ + c*64)*H_ + h;

  if (tid < 64) {
    float gv = Gg[rowbase + (size_t)tid*H_];
    #pragma unroll
    for (int off = 1; off < 64; off <<= 1) {
      float up = __shfl_up(gv, off, 64);
      if (tid >= off) gv += up;
    }
    gc[tid] = gv;
    Gcum[(size_t)bhc*64 + tid] = gv;
    bet[tid] = Bb[rowbase + (size_t)tid*H_];
  }
  // stage K -> bf16 LDS
  for (int e4 = tid; e4 < 1024; e4 += 256) {
    int t = e4 >> 4, d4 = (e4 & 15) * 4;
    float4 v = *(const float4*)&Kc[(rowbase + (size_t)t*H_)*64 + d4];
    u16 tmp[4] = {f2bf(v.x), f2bf(v.y), f2bf(v.z), f2bf(v.w)};
    *(uint2*)&Kbf[t][d4] = *(uint2*)tmp;
  }
  __syncthreads();

  // A-phase: wave w computes t-strip [16w,16w+16) x all s
  {
    bf16x8 afA[2];
    #pragma unroll
    for (int ks = 0; ks < 2; ++ks)
      afA[ks] = *(const bf16x8*)&Kbf[16*wave + lr][ks*32 + lkq*8];
    #pragma unroll
    for (int j = 0; j < 4; ++j) {
      f32x4 accA = f32x4{0.f, 0.f, 0.f, 0.f};
      #pragma unroll
      for (int ks = 0; ks < 2; ++ks) {
        bf16x8 bfr = *(const bf16x8*)&Kbf[16*j + lr][ks*32 + lkq*8];
        accA = __builtin_amdgcn_mfma_f32_16x16x32_bf16(afA[ks], bfr, accA, 0, 0, 0);
      }
      const int s = 16*j + lr;
      #pragma unroll
      for (int r = 0; r < 4; ++r) {
        int t = 16*wave + lkq*4 + r;
        Am[t][s] = (s < t) ? bet[t] * __expf(gc[t] - gc[s]) * accA[r] : 0.f;
      }
    }
  }
  // RHS fill
  for (int e4 = tid; e4 < 1024; e4 += 256) {
    int t = e4 >> 4, j4 = (e4 & 15) * 4;
    float bt = bet[t];
    float ek = bt * __expf(gc[t]);
    float4 vv = *(const float4*)&Vc[(rowbase + (size_t)t*H_)*64 + j4];
    XT[j4+0][t] = bt * vv.x; XT[j4+1][t] = bt * vv.y;
    XT[j4+2][t] = bt * vv.z; XT[j4+3][t] = bt * vv.w;
    XT[64+j4+0][t] = ek * bf2f(Kbf[t][j4+0]);
    XT[64+j4+1][t] = ek * bf2f(Kbf[t][j4+1]);
    XT[64+j4+2][t] = ek * bf2f(Kbf[t][j4+2]);
    XT[64+j4+3][t] = ek * bf2f(Kbf[t][j4+3]);
  }
  __syncthreads();

  // blocked forward substitution: 4 stages of 16 rows
  for (int st = 0; st < 4; ++st) {
    if (st > 0) {
      // off-diag: X_st -= A[st-block][0..16st) @ X[0..16st)
      const int nks = (st == 3) ? 2 : 1;
      f32x4 accU0 = f32x4{0.f,0.f,0.f,0.f}, accU1 = f32x4{0.f,0.f,0.f,0.f};
      for (int ks = 0; ks < nks; ++ks) {
        const int m0 = ks*32 + lkq*8;
        bf16x8 af;
        if (m0 + 8 <= 16*st) {
          float4 a0 = *(const float4*)&Am[16*st + lr][m0];
          float4 a1 = *(const float4*)&Am[16*st + lr][m0 + 4];
          af = pack8(a0, a1);
        } else {
          af = bf16x8{0,0,0,0,0,0,0,0};
        }
        {
          const int cb = (wave*2 + 0) * 16;
          float4 b0 = *(const float4*)&XT[cb + lr][m0];
          float4 b1 = *(const float4*)&XT[cb + lr][m0 + 4];
          accU0 = __builtin_amdgcn_mfma_f32_16x16x32_bf16(af, pack8(b0, b1), accU0, 0, 0, 0);
        }
        {
          const int cb = (wave*2 + 1) * 16;
          float4 b0 = *(const float4*)&XT[cb + lr][m0];
          float4 b1 = *(const float4*)&XT[cb + lr][m0 + 4];
          accU1 = __builtin_amdgcn_mfma_f32_16x16x32_bf16(af, pack8(b0, b1), accU1, 0, 0, 0);
        }
      }
      #pragma unroll
      for (int r = 0; r < 4; ++r) {
        const int t = 16*st + lkq*4 + r;
        XT[(wave*2+0)*16 + lr][t] -= accU0[r];
        XT[(wave*2+1)*16 + lr][t] -= accU1[r];
      }
      __syncthreads();
    }
    // diagonal 16x16 substitution: 128 threads = 128 columns
    if (tid < 128) {
      const int bs = 16*st;
      float x[16];
      #pragma unroll
      for (int q = 0; q < 4; ++q)
        *(float4*)&x[q*4] = *(const float4*)&XT[tid][bs + q*4];
      #pragma unroll
      for (int tau = 1; tau < 16; ++tau) {
        float a = 0.f, a2 = 0.f;
        #pragma unroll
        for (int m = 0; m < tau; m += 2) {
          a = fmaf(Am[bs+tau][bs+m], x[m], a);
          if (m + 1 < tau) a2 = fmaf(Am[bs+tau][bs+m+1], x[m+1], a2);
        }
        x[tau] -= (a + a2);
      }
      #pragma unroll
      for (int q = 0; q < 4; ++q)
        *(float4*)&XT[tid][bs + q*4] = *(const float4*)&x[q*4];
    }
    __syncthreads();
  }

  for (int e = tid; e < 4096; e += 256) {
    int t = e >> 6, j = e & 63;
    Ubuf[(size_t)bhc*4096 + e] = XT[j][t];
    Wbuf[(size_t)bhc*4096 + e] = XT[64+j][t];
  }
}

// ---------------- P1b (MFMA): M = bC*I - Ksc^T W, N = Ksc^T U ----------------
__global__ __launch_bounds__(256) void p1b_mn(
    const float* __restrict__ Kc, const float* __restrict__ Gcum,
    const float* __restrict__ Ubuf, const float* __restrict__ Wbuf,
    float* __restrict__ Mbuf, float* __restrict__ Nbuf)
{
  __shared__ u16 KscT[64][72];   // [a][t] = e^{gC-gc_t} K[t][a]
  __shared__ u16 WT[64][72];     // [c][t] = W[t][c]
  __shared__ u16 UT[64][72];     // [c][t] = U[t][c]
  __shared__ float gcs[64];
  const int bhc = blockIdx.x;
  const int bh = bhc >> 5, c = bhc & 31;
  const int b = bh >> 4, h = bh & 15;
  const int tid = threadIdx.x;
  const int lane = tid & 63, wave = tid >> 6;
  const int lr = lane & 15, lkq = lane >> 4;
  const size_t rowbase = ((size_t)b*T_ + c*64)*H_ + h;
  if (tid < 64) gcs[tid] = Gcum[(size_t)bhc*64 + tid];
  __syncthreads();
  const float gC = gcs[63];
  for (int e4 = tid; e4 < 1024; e4 += 256) {
    int t = e4 >> 4, a4 = (e4 & 15) * 4;
    float sc = __expf(gC - gcs[t]);
    float4 kv = *(const float4*)&Kc[(rowbase + (size_t)t*H_)*64 + a4];
    KscT[a4+0][t] = f2bf(sc*kv.x); KscT[a4+1][t] = f2bf(sc*kv.y);
    KscT[a4+2][t] = f2bf(sc*kv.z); KscT[a4+3][t] = f2bf(sc*kv.w);
    float4 wv = *(const float4*)&Wbuf[(size_t)bhc*4096 + (size_t)t*64 + a4];
    WT[a4+0][t] = f2bf(wv.x); WT[a4+1][t] = f2bf(wv.y);
    WT[a4+2][t] = f2bf(wv.z); WT[a4+3][t] = f2bf(wv.w);
    float4 uv = *(const float4*)&Ubuf[(size_t)bhc*4096 + (size_t)t*64 + a4];
    UT[a4+0][t] = f2bf(uv.x); UT[a4+1][t] = f2bf(uv.y);
    UT[a4+2][t] = f2bf(uv.z); UT[a4+3][t] = f2bf(uv.w);
  }
  __syncthreads();

  bf16x8 af[2];
  #pragma unroll
  for (int ks = 0; ks < 2; ++ks)
    af[ks] = *(const bf16x8*)&KscT[16*wave + lr][ks*32 + lkq*8];
  const float bC = __expf(gC);
  const size_t ob = (size_t)bhc * 4096;
  #pragma unroll
  for (int j = 0; j < 4; ++j) {
    f32x4 aM = f32x4{0.f,0.f,0.f,0.f}, aN = f32x4{0.f,0.f,0.f,0.f};
    #pragma unroll
    for (int ks = 0; ks < 2; ++ks) {
      bf16x8 bw = *(const bf16x8*)&WT[16*j + lr][ks*32 + lkq*8];
      bf16x8 bu = *(const bf16x8*)&UT[16*j + lr][ks*32 + lkq*8];
      aM = __builtin_amdgcn_mfma_f32_16x16x32_bf16(af[ks], bw, aM, 0, 0, 0);
      aN = __builtin_amdgcn_mfma_f32_16x16x32_bf16(af[ks], bu, aN, 0, 0, 0);
    }
    const int cc = 16*j + lr;
    #pragma unroll
    for (int r = 0; r < 4; ++r) {
      const int a = 16*wave + lkq*4 + r;
      Mbuf[ob + (size_t)a*64 + cc] = (a == cc ? bC : 0.f) - aM[r];
      Nbuf[ob + (size_t)a*64 + cc] = aN[r];
    }
  }
}

// ---------------- P1c: compose chunk pairs in place (odd slots <- pair) ----------------
__global__ __launch_bounds__(256) void p1c_pair(float* __restrict__ Mbuf,
    float* __restrict__ Nbuf)
{
  __shared__ float M2s[64][68];
  __shared__ float Ys[64][68];
  const int bhp = blockIdx.x;
  const int bh = bhp >> 4, p = bhp & 15;
  const size_t c1 = ((size_t)bh * 32 + 2 * p) * 4096, c2 = c1 + 4096;
  const int tid = threadIdx.x;
  const int r0 = (tid >> 4) * 4, c0 = (tid & 15) * 4;
  for (int e4 = tid; e4 < 1024; e4 += 256) {
    int t = e4 >> 4, i4 = (e4 & 15) * 4;
    *(float4*)&M2s[t][i4] = *(const float4*)&Mbuf[c2 + (size_t)t*64 + i4];
    *(float4*)&Ys[t][i4]  = *(const float4*)&Nbuf[c1 + (size_t)t*64 + i4];
  }
  float accN[4][4];
  #pragma unroll
  for (int r = 0; r < 4; ++r) {
    float4 v = *(const float4*)&Nbuf[c2 + (size_t)(r0+r)*64 + c0];
    accN[r][0]=v.x; accN[r][1]=v.y; accN[r][2]=v.z; accN[r][3]=v.w;
  }
  __syncthreads();
  for (int i4 = 0; i4 < 64; i4 += 4) {
    float aa[4][4], ya[4][4];
    #pragma unroll
    for (int r = 0; r < 4; ++r) {
      float4 v = *(const float4*)&M2s[r0+r][i4];
      aa[r][0]=v.x; aa[r][1]=v.y; aa[r][2]=v.z; aa[r][3]=v.w;
    }
    #pragma unroll
    for (int m = 0; m < 4; ++m) {
      float4 v = *(const float4*)&Ys[i4+m][c0];
      ya[m][0]=v.x; ya[m][1]=v.y; ya[m][2]=v.z; ya[m][3]=v.w;
    }
    #pragma unroll
    for (int r = 0; r < 4; ++r)
      #pragma unroll
      for (int m = 0; m < 4; ++m)
        #pragma unroll
        for (int cc = 0; cc < 4; ++cc)
          accN[r][cc] = fmaf(aa[r][m], ya[m][cc], accN[r][cc]);
  }
  #pragma unroll
  for (int r = 0; r < 4; ++r) {
    float4 v = {accN[r][0], accN[r][1], accN[r][2], accN[r][3]};
    *(float4*)&Nbuf[c2 + (size_t)(r0+r)*64 + c0] = v;
  }
  __syncthreads();
  for (int e4 = tid; e4 < 1024; e4 += 256) {
    int t = e4 >> 4, i4 = (e4 & 15) * 4;
    *(float4*)&Ys[t][i4] = *(const float4*)&Mbuf[c1 + (size_t)t*64 + i4];
  }
  float accM[4][4] = {};
  __syncthreads();
  for (int i4 = 0; i4 < 64; i4 += 4) {
    float aa[4][4], ya[4][4];
    #pragma unroll
    for (int r = 0; r < 4; ++r) {
      float4 v = *(const float4*)&M2s[r0+r][i4];
      aa[r][0]=v.x; aa[r][1]=v.y; aa[r][2]=v.z; aa[r][3]=v.w;
    }
    #pragma unroll
    for (int m = 0; m < 4; ++m) {
      float4 v = *(const float4*)&Ys[i4+m][c0];
      ya[m][0]=v.x; ya[m][1]=v.y; ya[m][2]=v.z; ya[m][3]=v.w;
    }
    #pragma unroll
    for (int r = 0; r < 4; ++r)
      #pragma unroll
      for (int m = 0; m < 4; ++m)
        #pragma unroll
        for (int cc = 0; cc < 4; ++cc)
          accM[r][cc] = fmaf(aa[r][m], ya[m][cc], accM[r][cc]);
  }
  #pragma unroll
  for (int r = 0; r < 4; ++r) {
    float4 v = {accM[r][0], accM[r][1], accM[r][2], accM[r][3]};
    *(float4*)&Mbuf[c2 + (size_t)(r0+r)*64 + c0] = v;
  }
}

// ---------------- P2: 16 serial pair-steps; carry + off-path mid state ----------------
__global__ __launch_bounds__(256) void p2_state(
    const float* __restrict__ Mbuf, const float* __restrict__ Nbuf,
    float* __restrict__ S0b)
{
  __shared__ float ST[2][32][68];
  __shared__ float Mp_s[64][68];
  __shared__ float M1_s[64][68];
  const int bh = blockIdx.x >> 1, js = blockIdx.x & 1;
  const int tid = threadIdx.x;
  const int a0 = (tid >> 4) * 4;
  const int jl0 = (tid & 15) * 2;
  const size_t base = (size_t)bh * NC_ * 4096;
  for (int e4 = tid; e4 < 32 * 17; e4 += 256)
    ((float4*)&ST[0][0][0])[e4] = float4{0.f, 0.f, 0.f, 0.f};
  #pragma unroll
  for (int r = 0; r < 4; ++r) {
    int e4 = tid + r * 256;
    int t = e4 >> 4, i4 = (e4 & 15) * 4;
    *(float4*)&Mp_s[t][i4] = *(const float4*)&Mbuf[base + 4096 + (size_t)t*64 + i4];
    *(float4*)&M1_s[t][i4] = *(const float4*)&Mbuf[base + (size_t)t*64 + i4];
  }
  float2 nP[4], n1[4];
  #pragma unroll
  for (int r = 0; r < 4; ++r) {
    nP[r] = *(const float2*)&Nbuf[base + 4096 + (size_t)(a0+r)*64 + js*32 + jl0];
    n1[r] = *(const float2*)&Nbuf[base + (size_t)(a0+r)*64 + js*32 + jl0];
  }
  __syncthreads();
  for (int p = 0; p < 16; ++p) {
    const int cur = p & 1, nxt = cur ^ 1;
    const size_t cb = base + (size_t)(2 * p) * 4096;
    float4 mpre[4], m1pre[4];
    float2 nPn[4], n1n[4];
    const bool hn = (p + 1 < 16);
    if (hn) {
      #pragma unroll
      for (int r = 0; r < 4; ++r) {
        int e4 = tid + r * 256;
        int t = e4 >> 4, i4 = (e4 & 15) * 4;
        mpre[r]  = *(const float4*)&Mbuf[cb + 3*4096 + (size_t)t*64 + i4];
        m1pre[r] = *(const float4*)&Mbuf[cb + 2*4096 + (size_t)t*64 + i4];
        nPn[r] = *(const float2*)&Nbuf[cb + 3*4096 + (size_t)(a0+r)*64 + js*32 + jl0];
        n1n[r] = *(const float2*)&Nbuf[cb + 2*4096 + (size_t)(a0+r)*64 + js*32 + jl0];
      }
    }
    #pragma unroll
    for (int r = 0; r < 2; ++r) {
      int e4 = tid + r * 256;
      int jl = e4 >> 4, i4 = (e4 & 15) * 4;
      int gs = ((i4 >> 2) ^ ((jl >> 1) & 7)) * 4;
      *(float4*)&S0b[cb + (size_t)(js*32 + jl)*64 + i4] = *(const float4*)&ST[cur][jl][gs];
    }
    float ca[4][2], mi[4][2];
    #pragma unroll
    for (int r = 0; r < 4; ++r) {
      ca[r][0] = nP[r].x; ca[r][1] = nP[r].y;
      mi[r][0] = n1[r].x; mi[r][1] = n1[r].y;
    }
    for (int i4 = 0; i4 < 64; i4 += 4) {
      float4 sv[2];
      #pragma unroll
      for (int m = 0; m < 2; ++m) {
        int jl = jl0 + m;
        sv[m] = *(const float4*)&ST[cur][jl][((i4 >> 2) ^ ((jl >> 1) & 7)) * 4];
      }
      #pragma unroll
      for (int r = 0; r < 4; ++r) {
        float4 mp  = *(const float4*)&Mp_s[a0 + r][i4];
        float4 m1v = *(const float4*)&M1_s[a0 + r][i4];
        ca[r][0] = dot4(mp, sv[0], ca[r][0]);
        ca[r][1] = dot4(mp, sv[1], ca[r][1]);
        mi[r][0] = dot4(m1v, sv[0], mi[r][0]);
        mi[r][1] = dot4(m1v, sv[1], mi[r][1]);
      }
    }
    #pragma unroll
    for (int m = 0; m < 2; ++m) {
      float4 v = {mi[0][m], mi[1][m], mi[2][m], mi[3][m]};
      *(float4*)&S0b[cb + 4096 + (size_t)(js*32 + jl0 + m)*64 + a0] = v;
    }
    #pragma unroll
    for (int r = 0; r < 4; ++r)
      #pragma unroll
      for (int m = 0; m < 2; ++m) {
        int jl = jl0 + m, a = a0 + r;
        ST[nxt][jl][(((a >> 2) ^ ((jl >> 1) & 7)) << 2) + (a & 3)] = ca[r][m];
      }
    __syncthreads();
    if (hn) {
      #pragma unroll
      for (int r = 0; r < 4; ++r) {
        int e4 = tid + r * 256;
        int t = e4 >> 4, i4 = (e4 & 15) * 4;
        *(float4*)&Mp_s[t][i4] = mpre[r];
        *(float4*)&M1_s[t][i4] = m1pre[r];
        nP[r] = nPn[r]; n1[r] = n1n[r];
      }
    }
    __syncthreads();
  }
}

// ---------------- P3: delta + outputs ----------------
__global__ __launch_bounds__(256) void p3_out(
    const float* __restrict__ Qc, const float* __restrict__ Kc,
    const float* __restrict__ Gcum, const float* __restrict__ S0b,
    const float* __restrict__ Ubuf, const float* __restrict__ Wbuf,
    float* __restrict__ O)
{
  __shared__ float Qs[64][68];
  __shared__ float KDs[64][68];
  __shared__ float PT[64][68];
  __shared__ float Ws[64][68];
  __shared__ float gcs[64];
  const int bhc = blockIdx.x;
  const int bh = bhc >> 5, c = bhc & 31;
  const int b = bh >> 4, h = bh & 15;
  const int tid = threadIdx.x;
  const size_t rowbase = ((size_t)b*T_ + c*64)*H_ + h;
  if (tid < 64) gcs[tid] = Gcum[(size_t)bhc*64 + tid];
  for (int e = tid; e < 4096; e += 256) {
    int r = e >> 6, d = e & 63;
    size_t ga = (rowbase + (size_t)r*H_)*64 + d;
    Qs[r][d]  = Qc[ga];
    KDs[r][d] = Kc[ga];
    PT[r][d]  = S0b[(size_t)bhc*4096 + e];
    Ws[r][d]  = Wbuf[(size_t)bhc*4096 + e];
  }
  __syncthreads();
  const int lane = tid & 63, wq = tid >> 6;
  float oacc[16], preg[16];
  #pragma unroll
  for (int it = 0; it < 16; ++it) { oacc[it] = 0.f; preg[it] = 0.f; }

  for (int i = 0; i < 64; i += 4) {
    float4 sv = *(const float4*)&PT[lane][i];
    #pragma unroll
    for (int it = 0; it < 16; ++it) {
      float4 qv = *(const float4*)&Qs[it*4 + wq][i];
      oacc[it] = dot4(qv, sv, oacc[it]);
    }
  }
  #pragma unroll
  for (int it = 0; it < 16; ++it) oacc[it] *= __expf(gcs[it*4 + wq]);

  for (int i = 0; i < 64; i += 4) {
    float4 kv = *(const float4*)&KDs[lane][i];
    #pragma unroll
    for (int it = 0; it < 16; ++it) {
      float4 qv = *(const float4*)&Qs[it*4 + wq][i];
      preg[it] = dot4(qv, kv, preg[it]);
    }
  }
  {
    const float gsl = gcs[lane];
    #pragma unroll
    for (int it = 0; it < 16; ++it) {
      int t = it*4 + wq;
      preg[it] = (lane <= t) ? __expf(gcs[t] - gsl) * preg[it] : 0.f;
    }
  }

  const int dt0 = (tid >> 4) << 2, dj0 = (tid & 15) << 2;
  float dacc[4][4];
  #pragma unroll
  for (int r = 0; r < 4; ++r) {
    float4 uv = *(const float4*)&Ubuf[(size_t)bhc*4096 + (size_t)(dt0+r)*64 + dj0];
    dacc[r][0] = uv.x; dacc[r][1] = uv.y; dacc[r][2] = uv.z; dacc[r][3] = uv.w;
  }
  for (int i = 0; i < 64; i += 4) {
    float4 wv[4], sv[4];
    #pragma unroll
    for (int r = 0; r < 4; ++r) wv[r] = *(const float4*)&Ws[dt0+r][i];
    #pragma unroll
    for (int m = 0; m < 4; ++m) sv[m] = *(const float4*)&PT[dj0+m][i];
    #pragma unroll
    for (int r = 0; r < 4; ++r)
      #pragma unroll
      for (int m = 0; m < 4; ++m)
        dacc[r][m] = ndot4(wv[r], sv[m], dacc[r][m]);
  }
  __syncthreads();
  #pragma unroll
  for (int it = 0; it < 16; ++it) PT[it*4 + wq][lane] = preg[it];
  #pragma unroll
  for (int r = 0; r < 4; ++r)
    #pragma unroll
    for (int m = 0; m < 4; ++m)
      KDs[dj0+m][dt0+r] = dacc[r][m];
  __syncthreads();

  for (int s = 0; s < 64; s += 4) {
    float4 dv = *(const float4*)&KDs[lane][s];
    #pragma unroll
    for (int it = 0; it < 16; ++it) {
      float4 pv = *(const float4*)&PT[it*4 + wq][s];
      oacc[it] = dot4(pv, dv, oacc[it]);
    }
  }
  #pragma unroll
  for (int it = 0; it < 16; ++it) {
    int t = it*4 + wq;
    O[(rowbase + (size_t)t*H_)*64 + lane] = oacc[it];
  }
}

// ---------------- o-norm * swish(gv) -> bf16 ----------------
__global__ __launch_bounds__(256) void ogate(const float* __restrict__ O,
    const float* __restrict__ GV, const float* __restrict__ w,
    u16* __restrict__ OG)
{
  const size_t gid = (size_t)blockIdx.x * 256 + threadIdx.x;
  const size_t vec = gid >> 6;
  const int lane = threadIdx.x & 63;
  float x = O[vec * 64 + lane];
  float ss = x * x;
  #pragma unroll
  for (int m = 1; m < 64; m <<= 1) ss += __shfl_xor(ss, m);
  float y = x * rsqrtf(ss * (1.f/64.f) + 1e-6f) * w[lane];
  float gv = GV[vec * 64 + lane];
  OG[vec * 64 + lane] = f2bf(y * gv / (1.f + __expf(-gv)));
}

extern "C" void kernel_launch(void* const* d_in, const int* in_sizes, int n_in,
                              void* d_out, int out_size, void* d_ws, size_t ws_size,
                              hipStream_t stream) {
  const float* h    = (const float*)d_in[0];
  const float* Wq   = (const float*)d_in[1];
  const float* Wk   = (const float*)d_in[2];
  const float* Wv   = (const float*)d_in[3];
  const float* Wa   = (const float*)d_in[4];
  const float* Wb   = (const float*)d_in[5];
  const float* Wg   = (const float*)d_in[6];
  const float* Wo   = (const float*)d_in[7];
  const float* qnw  = (const float*)d_in[8];
  const float* knw  = (const float*)d_in[9];
  const float* onw  = (const float*)d_in[10];
  const float* Alog = (const float*)d_in[11];
  const float* dtb  = (const float*)d_in[12];
  const float* cqw  = (const float*)d_in[13];
  const float* ckw  = (const float*)d_in[14];
  const float* cvw  = (const float*)d_in[15];
  float* out = (float*)d_out;
  float* ws  = (float*)d_ws;

  const size_t NB = (size_t)B_ * T_ * D_;
  float* qp   = ws;
  float* kp   = ws + 1*NB;
  float* vp   = ws + 2*NB;
  float* gvp  = ws + 3*NB;
  float* qc   = ws + 4*NB;
  float* kc   = ws + 5*NB;
  float* vc   = ws + 6*NB;
  float* mb   = ws + 7*NB;
  float* wbf  = ws + 8*NB;
  float* gb   = ws + 8*NB + 5*524288;
  float* bb   = gb + (size_t)B_*T_*H_;
  float* Gc   = bb + (size_t)B_*T_*H_;

  u16* h_bf  = (u16*)mb;
  u16* og_bf = (u16*)mb;
  u16* w_bf  = (u16*)wbf;
  u16* wq_bf = w_bf + 0*1048576;
  u16* wk_bf = w_bf + 1*1048576;
  u16* wv_bf = w_bf + 2*1048576;
  u16* wg_bf = w_bf + 3*1048576;
  u16* wo_bf = w_bf + 4*1048576;

  float* Ubuf = qp;
  float* Wbuf = kp;
  float* S0b  = vp;
  float* Mbuf = mb;
  float* Nbuf = vc;

  cvt_all<<<4608, 256, 0, stream>>>(h, Wq, Wk, Wv, Wg, Wo, h_bf, w_bf);

  gemm_bf16_4<<<dim3(32, 32), 256, 0, stream>>>(h_bf, wq_bf, wk_bf, wv_bf, wg_bf,
                                                 qp, kp, vp, gvp);
  smallproj<<<B_ * T_, 256, 0, stream>>>(h, Wa, Wb, Alog, dtb, gb, bb);

  convnorm<1><<<1024, 256, 0, stream>>>(qp, cqw, qnw, 0.125f, qc);
  convnorm<1><<<1024, 256, 0, stream>>>(kp, ckw, knw, 1.0f, kc);
  convnorm<0><<<1024, 256, 0, stream>>>(vp, cvw, qnw, 1.0f, vc);

  p1_chunk<<<B_*H_*NC_, 256, 0, stream>>>(kc, vc, gb, bb, Ubuf, Wbuf, Gc);
  p1b_mn<<<B_*H_*NC_, 256, 0, stream>>>(kc, Gc, Ubuf, Wbuf, Mbuf, Nbuf);
  p1c_pair<<<B_*H_*16, 256, 0, stream>>>(Mbuf, Nbuf);
  p2_state<<<B_*H_*2, 256, 0, stream>>>(Mbuf, Nbuf, S0b);
  p3_out<<<B_*H_*NC_, 256, 0, stream>>>(qc, kc, Gc, S0b, Ubuf, Wbuf, out);

  ogate<<<B_*T_*D_/256, 256, 0, stream>>>(out, gvp, onw, og_bf);
  gemm_bf16_1<<<dim3(32, 8), 256, 0, stream>>>(og_bf, wo_bf, out);
}

// Round 7
// 360.506 us; speedup vs baseline: 11.1931x; 1.1084x over previous
//
#include <hip/hip_runtime.h>
#include <cstdint>
#include <cstddef>

#define B_ 2
#define T_ 2048
#define D_ 1024
#define H_ 16
#define HD_ 64
#define NC_ 32

typedef unsigned short u16;
typedef __attribute__((ext_vector_type(8))) short bf16x8;
typedef __attribute__((ext_vector_type(4))) float f32x4;

__device__ __forceinline__ float dot4(float4 a, float4 b, float acc) {
  return fmaf(a.x, b.x, fmaf(a.y, b.y, fmaf(a.z, b.z, fmaf(a.w, b.w, acc))));
}
__device__ __forceinline__ float ndot4(float4 a, float4 b, float acc) {
  return fmaf(-a.x, b.x, fmaf(-a.y, b.y, fmaf(-a.z, b.z, fmaf(-a.w, b.w, acc))));
}
__device__ __forceinline__ u16 f2bf(float f) {
  unsigned u = __float_as_uint(f);
  u += 0x7fffu + ((u >> 16) & 1u);
  return (u16)(u >> 16);
}
__device__ __forceinline__ float bf2f(u16 v) {
  return __uint_as_float(((unsigned)v) << 16);
}
__device__ __forceinline__ bf16x8 pack8(float4 a, float4 b) {
  union { u16 us[8]; bf16x8 v; } p;
  p.us[0] = f2bf(a.x); p.us[1] = f2bf(a.y); p.us[2] = f2bf(a.z); p.us[3] = f2bf(a.w);
  p.us[4] = f2bf(b.x); p.us[5] = f2bf(b.y); p.us[6] = f2bf(b.z); p.us[7] = f2bf(b.w);
  return p.v;
}
__device__ __forceinline__ void glds16(const u16* g, u16* l) {
  __builtin_amdgcn_global_load_lds(
      (const __attribute__((address_space(1))) void*)g,
      (__attribute__((address_space(3))) void*)l, 16, 0, 0);
}

// ---------------- fp32 -> bf16 conversion (h + 5 weights, one launch) ----------------
__global__ __launch_bounds__(256) void cvt_all(
    const float* __restrict__ h, const float* __restrict__ w0,
    const float* __restrict__ w1, const float* __restrict__ w2,
    const float* __restrict__ w3, const float* __restrict__ w4,
    u16* __restrict__ h_bf, u16* __restrict__ wb)
{
  const int blk = blockIdx.x;
  const float* src;
  u16* dst;
  int lb;
  if (blk < 2048) { src = h; dst = h_bf; lb = blk; }
  else {
    int k = (blk - 2048) >> 9, r = (blk - 2048) & 511;
    src = k == 0 ? w0 : k == 1 ? w1 : k == 2 ? w2 : k == 3 ? w3 : w4;
    dst = wb + (size_t)k * 1048576;
    lb = r;
  }
  int i = (lb * 256 + threadIdx.x) * 8;
  float4 v0 = *(const float4*)(src + i);
  float4 v1 = *(const float4*)(src + i + 4);
  union { u16 us[8]; uint4 u4; } p;
  p.us[0] = f2bf(v0.x); p.us[1] = f2bf(v0.y); p.us[2] = f2bf(v0.z); p.us[3] = f2bf(v0.w);
  p.us[4] = f2bf(v1.x); p.us[5] = f2bf(v1.y); p.us[6] = f2bf(v1.z); p.us[7] = f2bf(v1.w);
  *(uint4*)(dst + i) = p.u4;
}

// ---------------- bf16 MFMA GEMM core (m97-style: global_load_lds, linear LDS) ----------------
__device__ __forceinline__ void gemm_core(const u16* __restrict__ A,
    const u16* __restrict__ Bw, float* __restrict__ C,
    u16* As, u16* Bs, int row0, int col0, int K, int N)
{
  const int tid = threadIdx.x;
  const int lane = tid & 63, wave = tid >> 6;
  const int wr = (wave >> 1) * 64, wc = (wave & 1) * 64;
  const int lr = lane & 15, lk = (lane >> 4) * 8;
  const int rql = (lane >> 2);
  const int cql = (lane & 3) * 8;
  const u16* gA0 = A + (size_t)(row0 + wave * 16 + rql) * K + cql;
  const u16* gA1 = A + (size_t)(row0 + (wave + 4) * 16 + rql) * K + cql;
  const u16* gB0 = Bw + (size_t)(col0 + wave * 16 + rql) * K + cql;
  const u16* gB1 = Bw + (size_t)(col0 + (wave + 4) * 16 + rql) * K + cql;
  u16* lA0 = As + wave * 16 * 32;
  u16* lA1 = As + (wave + 4) * 16 * 32;
  u16* lB0 = Bs + wave * 16 * 32;
  u16* lB1 = Bs + (wave + 4) * 16 * 32;

  f32x4 acc[4][4];
  #pragma unroll
  for (int i = 0; i < 4; ++i)
    #pragma unroll
    for (int j = 0; j < 4; ++j) acc[i][j] = f32x4{0.f, 0.f, 0.f, 0.f};

  const int KT = K >> 5;
  for (int kt = 0; kt < KT; ++kt) {
    glds16(gA0 + kt * 32, lA0);
    glds16(gA1 + kt * 32, lA1);
    glds16(gB0 + kt * 32, lB0);
    glds16(gB1 + kt * 32, lB1);
    __syncthreads();
    bf16x8 af[4], bf[4];
    #pragma unroll
    for (int i = 0; i < 4; ++i) af[i] = *(const bf16x8*)&As[(wr + i * 16 + lr) * 32 + lk];
    #pragma unroll
    for (int j = 0; j < 4; ++j) bf[j] = *(const bf16x8*)&Bs[(wc + j * 16 + lr) * 32 + lk];
    #pragma unroll
    for (int i = 0; i < 4; ++i)
      #pragma unroll
      for (int j = 0; j < 4; ++j)
        acc[i][j] = __builtin_amdgcn_mfma_f32_16x16x32_bf16(af[i], bf[j], acc[i][j], 0, 0, 0);
    __syncthreads();
  }
  const int orow = row0 + wr + (lane >> 4) * 4;
  const int ocol = col0 + wc + lr;
  #pragma unroll
  for (int i = 0; i < 4; ++i)
    #pragma unroll
    for (int j = 0; j < 4; ++j)
      #pragma unroll
      for (int r = 0; r < 4; ++r)
        C[(size_t)(orow + i * 16 + r) * N + ocol + j * 16] = acc[i][j][r];
}

__global__ __launch_bounds__(256) void gemm_bf16_4(const u16* __restrict__ A,
    const u16* __restrict__ W0, const u16* __restrict__ W1,
    const u16* __restrict__ W2, const u16* __restrict__ W3,
    float* __restrict__ C0, float* __restrict__ C1,
    float* __restrict__ C2, float* __restrict__ C3)
{
  __shared__ u16 As[128 * 32];
  __shared__ u16 Bs[128 * 32];
  const int sel = blockIdx.y >> 3;
  const u16* Bw = sel == 0 ? W0 : sel == 1 ? W1 : sel == 2 ? W2 : W3;
  float* C = sel == 0 ? C0 : sel == 1 ? C1 : sel == 2 ? C2 : C3;
  gemm_core(A, Bw, C, As, Bs, blockIdx.x * 128, (blockIdx.y & 7) * 128, 1024, 1024);
}

__global__ __launch_bounds__(256) void gemm_bf16_1(const u16* __restrict__ A,
    const u16* __restrict__ Bw, float* __restrict__ C)
{
  __shared__ u16 As[128 * 32];
  __shared__ u16 Bs[128 * 32];
  gemm_core(A, Bw, C, As, Bs, blockIdx.x * 128, blockIdx.y * 128, 1024, 1024);
}

// ---------------- beta / g small projections ----------------
__global__ __launch_bounds__(256) void smallproj(const float* __restrict__ Hs,
    const float* __restrict__ Wa, const float* __restrict__ Wb,
    const float* __restrict__ Alog, const float* __restrict__ dtb,
    float* __restrict__ Gout, float* __restrict__ Bout)
{
  __shared__ float hs[D_];
  const int bt = blockIdx.x;
  for (int i = threadIdx.x; i < D_; i += 256) hs[i] = Hs[(size_t)bt * D_ + i];
  __syncthreads();
  const int grp = threadIdx.x >> 3, p = threadIdx.x & 7;
  const int head = grp & 15, which = grp >> 4;
  const float* Wr = (which ? Wb : Wa) + head * D_;
  float s = 0.f;
  for (int i = p; i < D_; i += 8) s = fmaf(hs[i], Wr[i], s);
  s += __shfl_xor(s, 1); s += __shfl_xor(s, 2); s += __shfl_xor(s, 4);
  if (p == 0) {
    if (which) {
      Bout[(size_t)bt * H_ + head] = 1.f / (1.f + __expf(-s));
    } else {
      float x = s + dtb[head];
      float sp = fmaxf(x, 0.f) + log1pf(__expf(-fabsf(x)));
      Gout[(size_t)bt * H_ + head] = -__expf(Alog[head]) * sp;
    }
  }
}

// ---------------- fused causal conv(K=4)+SiLU [+ RMSNorm+L2norm] ----------------
template<int NORM>
__global__ __launch_bounds__(256) void convnorm(const float* __restrict__ X,
    const float* __restrict__ W, const float* __restrict__ nw, float fs,
    float* __restrict__ Y)
{
  __shared__ float Xs[67][65];
  __shared__ float nwS[64];
  const int blk = blockIdx.x;
  const int tt = blk & 31, hh = (blk >> 5) & 15, b = blk >> 9;
  const int t0 = tt * 64;
  const int d = threadIdx.x & 63, tq = threadIdx.x >> 6;
  for (int e = threadIdx.x; e < 67 * 64; e += 256) {
    int r = e >> 6, dd = e & 63;
    int t = t0 - 3 + r;
    Xs[r][dd] = (t >= 0) ? X[((size_t)b * T_ + t) * D_ + hh * 64 + dd] : 0.f;
  }
  if (NORM && threadIdx.x < 64) nwS[threadIdx.x] = nw[threadIdx.x];
  __syncthreads();
  const float4 w = *(const float4*)(W + (hh * 64 + d) * 4);
  #pragma unroll 4
  for (int it = 0; it < 16; ++it) {
    const int lt = tq * 16 + it;
    float a = fmaf(w.x, Xs[lt][d], fmaf(w.y, Xs[lt + 1][d],
              fmaf(w.z, Xs[lt + 2][d], w.w * Xs[lt + 3][d])));
    float y = a / (1.f + __expf(-a));
    if (NORM) {
      float ss = y * y;
      #pragma unroll
      for (int m = 1; m < 64; m <<= 1) ss += __shfl_xor(ss, m);
      float z = y * rsqrtf(ss * (1.f / 64.f) + 1e-6f) * nwS[d];
      float s2 = z * z;
      #pragma unroll
      for (int m = 1; m < 64; m <<= 1) s2 += __shfl_xor(s2, m);
      y = z * rsqrtf(s2 + 1e-6f) * fs;
    }
    Y[((size_t)b * T_ + t0 + lt) * D_ + hh * 64 + d] = y;
  }
}

// ---------------- P1: MFMA A = scale(K K^T), blocked MFMA solve -> U, W ----------------
__global__ __launch_bounds__(256) void p1_chunk(
    const float* __restrict__ Kc, const float* __restrict__ Vc,
    const float* __restrict__ Gg, const float* __restrict__ Bb,
    float* __restrict__ Ubuf, float* __restrict__ Wbuf, float* __restrict__ Gcum)
{
  __shared__ u16 Kbf[64][72];
  __shared__ float Am[64][68];
  __shared__ float XT[128][68];   // XT[col][t]; cols 0..63 U-rhs, 64..127 W-rhs
  __shared__ float gc[64], bet[64];
  const int bhc = blockIdx.x;
  const int bh = bhc >> 5, c = bhc & 31;
  const int b = bh >> 4, h = bh & 15;
  const int tid = threadIdx.x;
  const int lane = tid & 63, wave = tid >> 6;
  const int lr = lane & 15, lkq = lane >> 4;
  const size_t rowbase = ((size_t)b*T_ + c*64)*H_ + h;

  if (tid < 64) {
    float gv = Gg[rowbase + (size_t)tid*H_];
    #pragma unroll
    for (int off = 1; off < 64; off <<= 1) {
      float up = __shfl_up(gv, off, 64);
      if (tid >= off) gv += up;
    }
    gc[tid] = gv;
    Gcum[(size_t)bhc*64 + tid] = gv;
    bet[tid] = Bb[rowbase + (size_t)tid*H_];
  }
  // stage K -> bf16 LDS
  for (int e4 = tid; e4 < 1024; e4 += 256) {
    int t = e4 >> 4, d4 = (e4 & 15) * 4;
    float4 v = *(const float4*)&Kc[(rowbase + (size_t)t*H_)*64 + d4];
    u16 tmp[4] = {f2bf(v.x), f2bf(v.y), f2bf(v.z), f2bf(v.w)};
    *(uint2*)&Kbf[t][d4] = *(uint2*)tmp;
  }
  __syncthreads();

  // A-phase: wave w computes t-strip [16w,16w+16) x all s
  {
    bf16x8 afA[2];
    #pragma unroll
    for (int ks = 0; ks < 2; ++ks)
      afA[ks] = *(const bf16x8*)&Kbf[16*wave + lr][ks*32 + lkq*8];
    #pragma unroll
    for (int j = 0; j < 4; ++j) {
      f32x4 accA = f32x4{0.f, 0.f, 0.f, 0.f};
      #pragma unroll
      for (int ks = 0; ks < 2; ++ks) {
        bf16x8 bfr = *(const bf16x8*)&Kbf[16*j + lr][ks*32 + lkq*8];
        accA = __builtin_amdgcn_mfma_f32_16x16x32_bf16(afA[ks], bfr, accA, 0, 0, 0);
      }
      const int s = 16*j + lr;
      #pragma unroll
      for (int r = 0; r < 4; ++r) {
        int t = 16*wave + lkq*4 + r;
        Am[t][s] = (s < t) ? bet[t] * __expf(gc[t] - gc[s]) * accA[r] : 0.f;
      }
    }
  }
  // RHS fill
  for (int e4 = tid; e4 < 1024; e4 += 256) {
    int t = e4 >> 4, j4 = (e4 & 15) * 4;
    float bt = bet[t];
    float ek = bt * __expf(gc[t]);
    float4 vv = *(const float4*)&Vc[(rowbase + (size_t)t*H_)*64 + j4];
    XT[j4+0][t] = bt * vv.x; XT[j4+1][t] = bt * vv.y;
    XT[j4+2][t] = bt * vv.z; XT[j4+3][t] = bt * vv.w;
    XT[64+j4+0][t] = ek * bf2f(Kbf[t][j4+0]);
    XT[64+j4+1][t] = ek * bf2f(Kbf[t][j4+1]);
    XT[64+j4+2][t] = ek * bf2f(Kbf[t][j4+2]);
    XT[64+j4+3][t] = ek * bf2f(Kbf[t][j4+3]);
  }
  __syncthreads();

  // blocked forward substitution: 4 stages of 16 rows
  for (int st = 0; st < 4; ++st) {
    if (st > 0) {
      const int nks = (st == 3) ? 2 : 1;
      f32x4 accU0 = f32x4{0.f,0.f,0.f,0.f}, accU1 = f32x4{0.f,0.f,0.f,0.f};
      for (int ks = 0; ks < nks; ++ks) {
        const int m0 = ks*32 + lkq*8;
        bf16x8 af;
        if (m0 + 8 <= 16*st) {
          float4 a0 = *(const float4*)&Am[16*st + lr][m0];
          float4 a1 = *(const float4*)&Am[16*st + lr][m0 + 4];
          af = pack8(a0, a1);
        } else {
          af = bf16x8{0,0,0,0,0,0,0,0};
        }
        {
          const int cb = (wave*2 + 0) * 16;
          float4 b0 = *(const float4*)&XT[cb + lr][m0];
          float4 b1 = *(const float4*)&XT[cb + lr][m0 + 4];
          accU0 = __builtin_amdgcn_mfma_f32_16x16x32_bf16(af, pack8(b0, b1), accU0, 0, 0, 0);
        }
        {
          const int cb = (wave*2 + 1) * 16;
          float4 b0 = *(const float4*)&XT[cb + lr][m0];
          float4 b1 = *(const float4*)&XT[cb + lr][m0 + 4];
          accU1 = __builtin_amdgcn_mfma_f32_16x16x32_bf16(af, pack8(b0, b1), accU1, 0, 0, 0);
        }
      }
      #pragma unroll
      for (int r = 0; r < 4; ++r) {
        const int t = 16*st + lkq*4 + r;
        XT[(wave*2+0)*16 + lr][t] -= accU0[r];
        XT[(wave*2+1)*16 + lr][t] -= accU1[r];
      }
      __syncthreads();
    }
    if (tid < 128) {
      const int bs = 16*st;
      float x[16];
      #pragma unroll
      for (int q = 0; q < 4; ++q)
        *(float4*)&x[q*4] = *(const float4*)&XT[tid][bs + q*4];
      #pragma unroll
      for (int tau = 1; tau < 16; ++tau) {
        float a = 0.f, a2 = 0.f;
        #pragma unroll
        for (int m = 0; m < tau; m += 2) {
          a = fmaf(Am[bs+tau][bs+m], x[m], a);
          if (m + 1 < tau) a2 = fmaf(Am[bs+tau][bs+m+1], x[m+1], a2);
        }
        x[tau] -= (a + a2);
      }
      #pragma unroll
      for (int q = 0; q < 4; ++q)
        *(float4*)&XT[tid][bs + q*4] = *(const float4*)&x[q*4];
    }
    __syncthreads();
  }

  for (int e = tid; e < 4096; e += 256) {
    int t = e >> 6, j = e & 63;
    Ubuf[(size_t)bhc*4096 + e] = XT[j][t];
    Wbuf[(size_t)bhc*4096 + e] = XT[64+j][t];
  }
}

// ---------------- P1b (MFMA): M = bC*I - Ksc^T W, N = Ksc^T U ----------------
__global__ __launch_bounds__(256) void p1b_mn(
    const float* __restrict__ Kc, const float* __restrict__ Gcum,
    const float* __restrict__ Ubuf, const float* __restrict__ Wbuf,
    float* __restrict__ Mbuf, float* __restrict__ Nbuf)
{
  __shared__ u16 KscT[64][72];   // [a][t] = e^{gC-gc_t} K[t][a]
  __shared__ u16 WT[64][72];     // [c][t] = W[t][c]
  __shared__ u16 UT[64][72];     // [c][t] = U[t][c]
  __shared__ float gcs[64];
  const int bhc = blockIdx.x;
  const int bh = bhc >> 5, c = bhc & 31;
  const int b = bh >> 4, h = bh & 15;
  const int tid = threadIdx.x;
  const int lane = tid & 63, wave = tid >> 6;
  const int lr = lane & 15, lkq = lane >> 4;
  const size_t rowbase = ((size_t)b*T_ + c*64)*H_ + h;
  if (tid < 64) gcs[tid] = Gcum[(size_t)bhc*64 + tid];
  __syncthreads();
  const float gC = gcs[63];
  for (int e4 = tid; e4 < 1024; e4 += 256) {
    int t = e4 >> 4, a4 = (e4 & 15) * 4;
    float sc = __expf(gC - gcs[t]);
    float4 kv = *(const float4*)&Kc[(rowbase + (size_t)t*H_)*64 + a4];
    KscT[a4+0][t] = f2bf(sc*kv.x); KscT[a4+1][t] = f2bf(sc*kv.y);
    KscT[a4+2][t] = f2bf(sc*kv.z); KscT[a4+3][t] = f2bf(sc*kv.w);
    float4 wv = *(const float4*)&Wbuf[(size_t)bhc*4096 + (size_t)t*64 + a4];
    WT[a4+0][t] = f2bf(wv.x); WT[a4+1][t] = f2bf(wv.y);
    WT[a4+2][t] = f2bf(wv.z); WT[a4+3][t] = f2bf(wv.w);
    float4 uv = *(const float4*)&Ubuf[(size_t)bhc*4096 + (size_t)t*64 + a4];
    UT[a4+0][t] = f2bf(uv.x); UT[a4+1][t] = f2bf(uv.y);
    UT[a4+2][t] = f2bf(uv.z); UT[a4+3][t] = f2bf(uv.w);
  }
  __syncthreads();

  bf16x8 af[2];
  #pragma unroll
  for (int ks = 0; ks < 2; ++ks)
    af[ks] = *(const bf16x8*)&KscT[16*wave + lr][ks*32 + lkq*8];
  const float bC = __expf(gC);
  const size_t ob = (size_t)bhc * 4096;
  #pragma unroll
  for (int j = 0; j < 4; ++j) {
    f32x4 aM = f32x4{0.f,0.f,0.f,0.f}, aN = f32x4{0.f,0.f,0.f,0.f};
    #pragma unroll
    for (int ks = 0; ks < 2; ++ks) {
      bf16x8 bw = *(const bf16x8*)&WT[16*j + lr][ks*32 + lkq*8];
      bf16x8 bu = *(const bf16x8*)&UT[16*j + lr][ks*32 + lkq*8];
      aM = __builtin_amdgcn_mfma_f32_16x16x32_bf16(af[ks], bw, aM, 0, 0, 0);
      aN = __builtin_amdgcn_mfma_f32_16x16x32_bf16(af[ks], bu, aN, 0, 0, 0);
    }
    const int cc = 16*j + lr;
    #pragma unroll
    for (int r = 0; r < 4; ++r) {
      const int a = 16*wave + lkq*4 + r;
      Mbuf[ob + (size_t)a*64 + cc] = (a == cc ? bC : 0.f) - aM[r];
      Nbuf[ob + (size_t)a*64 + cc] = aN[r];
    }
  }
}

// ---------------- pscanA: in-place group-of-4 prefix composition ----------------
// For group g (chunks 4g..4g+3): slot 4g+i-1 <- prefix_i (M,N) for i=2..4.
// prefix_i = T_{4g+i-1} o prefix_{i-1}: M' = Mnew@Mold, N' = Mnew@Nold + Nnew.
__global__ __launch_bounds__(256) void pscanA(float* __restrict__ Mbuf,
    float* __restrict__ Nbuf)
{
  __shared__ float OM[2][64][68];
  __shared__ float ON[2][64][68];
  __shared__ float NM[2][64][68];
  const int blk = blockIdx.x;            // 32 bh * 8 groups
  const int bh = blk >> 3, g = blk & 7;
  const size_t s0 = ((size_t)bh * 32 + g * 4) * 4096;
  const int tid = threadIdx.x;
  const int p0 = (tid >> 4) * 4;         // output rows a
  const int q0 = (tid & 15) * 4;         // output cols
  for (int e4 = tid; e4 < 1024; e4 += 256) {
    int r = e4 >> 4, c4 = (e4 & 15) * 4;
    *(float4*)&OM[0][r][c4] = *(const float4*)&Mbuf[s0 + (size_t)r*64 + c4];
    *(float4*)&ON[0][r][c4] = *(const float4*)&Nbuf[s0 + (size_t)r*64 + c4];
    *(float4*)&NM[0][r][c4] = *(const float4*)&Mbuf[s0 + 4096 + (size_t)r*64 + c4];
  }
  __syncthreads();
  for (int s = 0; s < 3; ++s) {
    const int cur = s & 1, nxt = cur ^ 1;
    const size_t wslot = s0 + (size_t)(s + 1) * 4096;
    if (s < 2) {
      for (int e4 = tid; e4 < 1024; e4 += 256) {
        int r = e4 >> 4, c4 = (e4 & 15) * 4;
        *(float4*)&NM[nxt][r][c4] = *(const float4*)&Mbuf[wslot + 4096 + (size_t)r*64 + c4];
      }
    }
    float aM[4][4], aN[4][4];
    #pragma unroll
    for (int r = 0; r < 4; ++r) {
      float4 nv = *(const float4*)&Nbuf[wslot + (size_t)(p0+r)*64 + q0];
      aM[r][0]=0.f; aM[r][1]=0.f; aM[r][2]=0.f; aM[r][3]=0.f;
      aN[r][0]=nv.x; aN[r][1]=nv.y; aN[r][2]=nv.z; aN[r][3]=nv.w;
    }
    for (int m4 = 0; m4 < 64; m4 += 4) {
      float xv[4][4];
      #pragma unroll
      for (int r = 0; r < 4; ++r) {
        float4 v = *(const float4*)&NM[cur][p0+r][m4];
        xv[r][0]=v.x; xv[r][1]=v.y; xv[r][2]=v.z; xv[r][3]=v.w;
      }
      #pragma unroll
      for (int mm = 0; mm < 4; ++mm) {
        float4 ym = *(const float4*)&OM[cur][m4+mm][q0];
        float4 yn = *(const float4*)&ON[cur][m4+mm][q0];
        #pragma unroll
        for (int r = 0; r < 4; ++r) {
          aM[r][0] = fmaf(xv[r][mm], ym.x, aM[r][0]);
          aM[r][1] = fmaf(xv[r][mm], ym.y, aM[r][1]);
          aM[r][2] = fmaf(xv[r][mm], ym.z, aM[r][2]);
          aM[r][3] = fmaf(xv[r][mm], ym.w, aM[r][3]);
          aN[r][0] = fmaf(xv[r][mm], yn.x, aN[r][0]);
          aN[r][1] = fmaf(xv[r][mm], yn.y, aN[r][1]);
          aN[r][2] = fmaf(xv[r][mm], yn.z, aN[r][2]);
          aN[r][3] = fmaf(xv[r][mm], yn.w, aN[r][3]);
        }
      }
    }
    #pragma unroll
    for (int r = 0; r < 4; ++r) {
      float4 vm = {aM[r][0], aM[r][1], aM[r][2], aM[r][3]};
      float4 vn = {aN[r][0], aN[r][1], aN[r][2], aN[r][3]};
      *(float4*)&Mbuf[wslot + (size_t)(p0+r)*64 + q0] = vm;
      *(float4*)&Nbuf[wslot + (size_t)(p0+r)*64 + q0] = vn;
      *(float4*)&OM[nxt][p0+r][q0] = vm;
      *(float4*)&ON[nxt][p0+r][q0] = vn;
    }
    __syncthreads();
  }
}

// ---------------- pscanB: serial carry over 8 group totals (ST-form) ----------------
// ST[j][k] = S^T. S0b[4(g+1)] = ST_new[j][a] = sum_k ST[j][k]*Mtot[a][k] + Ntot^T[j][a]
__global__ __launch_bounds__(256) void pscanB(const float* __restrict__ Mbuf,
    const float* __restrict__ Nbuf, float* __restrict__ S0b)
{
  __shared__ float ST[2][64][68];
  __shared__ float MT[64][68];
  const int bh = blockIdx.x;
  const size_t base = (size_t)bh * 32 * 4096;
  const int tid = threadIdx.x;
  const int j0 = (tid >> 4) * 4, a0 = tid & 15;
  for (int e4 = tid; e4 < 1024; e4 += 256) {
    int r = e4 >> 4, c4 = (e4 & 15) * 4;
    *(float4*)&ST[0][r][c4] = float4{0.f, 0.f, 0.f, 0.f};
    *(float4*)&S0b[base + (size_t)r*64 + c4] = float4{0.f, 0.f, 0.f, 0.f};
  }
  for (int g = 0; g < 7; ++g) {
    const int cur = g & 1, nxt = cur ^ 1;
    const size_t tslot = base + (size_t)(4*g + 3) * 4096;
    for (int e4 = tid; e4 < 1024; e4 += 256) {
      int r = e4 >> 4, c4 = (e4 & 15) * 4;
      *(float4*)&MT[r][c4] = *(const float4*)&Mbuf[tslot + (size_t)r*64 + c4];
    }
    float acc[4][4];
    #pragma unroll
    for (int r = 0; r < 4; ++r)
      #pragma unroll
      for (int s = 0; s < 4; ++s)
        acc[r][s] = Nbuf[tslot + (size_t)(a0 + 16*s)*64 + j0 + r];
    __syncthreads();
    for (int k4 = 0; k4 < 64; k4 += 4) {
      float4 xr[4];
      #pragma unroll
      for (int r = 0; r < 4; ++r) xr[r] = *(const float4*)&ST[cur][j0+r][k4];
      #pragma unroll
      for (int s = 0; s < 4; ++s) {
        float4 yv = *(const float4*)&MT[a0 + 16*s][k4];
        #pragma unroll
        for (int r = 0; r < 4; ++r) acc[r][s] = dot4(xr[r], yv, acc[r][s]);
      }
    }
    const size_t oslot = base + (size_t)(4*(g+1)) * 4096;
    #pragma unroll
    for (int r = 0; r < 4; ++r)
      #pragma unroll
      for (int s = 0; s < 4; ++s) {
        ST[nxt][j0+r][a0 + 16*s] = acc[r][s];
        S0b[oslot + (size_t)(j0+r)*64 + a0 + 16*s] = acc[r][s];
      }
    __syncthreads();
  }
}

// ---------------- pscanC: intra-group states (parallel) ----------------
// S0[4g+i] = prefix_i applied to S0[4g]:  ST_out[j][a] = sum_k STg[j][k]*MP[a][k] + NP^T[j][a]
__global__ __launch_bounds__(256) void pscanC(const float* __restrict__ Mbuf,
    const float* __restrict__ Nbuf, float* __restrict__ S0b)
{
  __shared__ float ST[64][68];
  __shared__ float MT[64][68];
  const int blk = blockIdx.x;            // 32 bh * 8 groups * 3
  const int bh = blk / 24, rem = blk % 24;
  const int g = rem / 3, i = rem % 3 + 1;
  const size_t base = (size_t)bh * 32 * 4096;
  const size_t pslot = base + (size_t)(4*g + i - 1) * 4096;
  const int tid = threadIdx.x;
  const int j0 = (tid >> 4) * 4, a0 = tid & 15;
  for (int e4 = tid; e4 < 1024; e4 += 256) {
    int r = e4 >> 4, c4 = (e4 & 15) * 4;
    *(float4*)&ST[r][c4] = *(const float4*)&S0b[base + (size_t)(4*g)*4096 + (size_t)r*64 + c4];
    *(float4*)&MT[r][c4] = *(const float4*)&Mbuf[pslot + (size_t)r*64 + c4];
  }
  float acc[4][4];
  #pragma unroll
  for (int r = 0; r < 4; ++r)
    #pragma unroll
    for (int s = 0; s < 4; ++s)
      acc[r][s] = Nbuf[pslot + (size_t)(a0 + 16*s)*64 + j0 + r];
  __syncthreads();
  for (int k4 = 0; k4 < 64; k4 += 4) {
    float4 xr[4];
    #pragma unroll
    for (int r = 0; r < 4; ++r) xr[r] = *(const float4*)&ST[j0+r][k4];
    #pragma unroll
    for (int s = 0; s < 4; ++s) {
      float4 yv = *(const float4*)&MT[a0 + 16*s][k4];
      #pragma unroll
      for (int r = 0; r < 4; ++r) acc[r][s] = dot4(xr[r], yv, acc[r][s]);
    }
  }
  const size_t oslot = base + (size_t)(4*g + i) * 4096;
  #pragma unroll
  for (int r = 0; r < 4; ++r)
    #pragma unroll
    for (int s = 0; s < 4; ++s)
      S0b[oslot + (size_t)(j0+r)*64 + a0 + 16*s] = acc[r][s];
}

// ---------------- P3: delta + outputs ----------------
__global__ __launch_bounds__(256) void p3_out(
    const float* __restrict__ Qc, const float* __restrict__ Kc,
    const float* __restrict__ Gcum, const float* __restrict__ S0b,
    const float* __restrict__ Ubuf, const float* __restrict__ Wbuf,
    float* __restrict__ O)
{
  __shared__ float Qs[64][68];
  __shared__ float KDs[64][68];
  __shared__ float PT[64][68];
  __shared__ float Ws[64][68];
  __shared__ float gcs[64];
  const int bhc = blockIdx.x;
  const int bh = bhc >> 5, c = bhc & 31;
  const int b = bh >> 4, h = bh & 15;
  const int tid = threadIdx.x;
  const size_t rowbase = ((size_t)b*T_ + c*64)*H_ + h;
  if (tid < 64) gcs[tid] = Gcum[(size_t)bhc*64 + tid];
  for (int e = tid; e < 4096; e += 256) {
    int r = e >> 6, d = e & 63;
    size_t ga = (rowbase + (size_t)r*H_)*64 + d;
    Qs[r][d]  = Qc[ga];
    KDs[r][d] = Kc[ga];
    PT[r][d]  = S0b[(size_t)bhc*4096 + e];
    Ws[r][d]  = Wbuf[(size_t)bhc*4096 + e];
  }
  __syncthreads();
  const int lane = tid & 63, wq = tid >> 6;
  float oacc[16], preg[16];
  #pragma unroll
  for (int it = 0; it < 16; ++it) { oacc[it] = 0.f; preg[it] = 0.f; }

  for (int i = 0; i < 64; i += 4) {
    float4 sv = *(const float4*)&PT[lane][i];
    #pragma unroll
    for (int it = 0; it < 16; ++it) {
      float4 qv = *(const float4*)&Qs[it*4 + wq][i];
      oacc[it] = dot4(qv, sv, oacc[it]);
    }
  }
  #pragma unroll
  for (int it = 0; it < 16; ++it) oacc[it] *= __expf(gcs[it*4 + wq]);

  for (int i = 0; i < 64; i += 4) {
    float4 kv = *(const float4*)&KDs[lane][i];
    #pragma unroll
    for (int it = 0; it < 16; ++it) {
      float4 qv = *(const float4*)&Qs[it*4 + wq][i];
      preg[it] = dot4(qv, kv, preg[it]);
    }
  }
  {
    const float gsl = gcs[lane];
    #pragma unroll
    for (int it = 0; it < 16; ++it) {
      int t = it*4 + wq;
      preg[it] = (lane <= t) ? __expf(gcs[t] - gsl) * preg[it] : 0.f;
    }
  }

  const int dt0 = (tid >> 4) << 2, dj0 = (tid & 15) << 2;
  float dacc[4][4];
  #pragma unroll
  for (int r = 0; r < 4; ++r) {
    float4 uv = *(const float4*)&Ubuf[(size_t)bhc*4096 + (size_t)(dt0+r)*64 + dj0];
    dacc[r][0] = uv.x; dacc[r][1] = uv.y; dacc[r][2] = uv.z; dacc[r][3] = uv.w;
  }
  for (int i = 0; i < 64; i += 4) {
    float4 wv[4], sv[4];
    #pragma unroll
    for (int r = 0; r < 4; ++r) wv[r] = *(const float4*)&Ws[dt0+r][i];
    #pragma unroll
    for (int m = 0; m < 4; ++m) sv[m] = *(const float4*)&PT[dj0+m][i];
    #pragma unroll
    for (int r = 0; r < 4; ++r)
      #pragma unroll
      for (int m = 0; m < 4; ++m)
        dacc[r][m] = ndot4(wv[r], sv[m], dacc[r][m]);
  }
  __syncthreads();
  #pragma unroll
  for (int it = 0; it < 16; ++it) PT[it*4 + wq][lane] = preg[it];
  #pragma unroll
  for (int r = 0; r < 4; ++r)
    #pragma unroll
    for (int m = 0; m < 4; ++m)
      KDs[dj0+m][dt0+r] = dacc[r][m];
  __syncthreads();

  for (int s = 0; s < 64; s += 4) {
    float4 dv = *(const float4*)&KDs[lane][s];
    #pragma unroll
    for (int it = 0; it < 16; ++it) {
      float4 pv = *(const float4*)&PT[it*4 + wq][s];
      oacc[it] = dot4(pv, dv, oacc[it]);
    }
  }
  #pragma unroll
  for (int it = 0; it < 16; ++it) {
    int t = it*4 + wq;
    O[(rowbase + (size_t)t*H_)*64 + lane] = oacc[it];
  }
}

// ---------------- o-norm * swish(gv) -> bf16 ----------------
__global__ __launch_bounds__(256) void ogate(const float* __restrict__ O,
    const float* __restrict__ GV, const float* __restrict__ w,
    u16* __restrict__ OG)
{
  const size_t gid = (size_t)blockIdx.x * 256 + threadIdx.x;
  const size_t vec = gid >> 6;
  const int lane = threadIdx.x & 63;
  float x = O[vec * 64 + lane];
  float ss = x * x;
  #pragma unroll
  for (int m = 1; m < 64; m <<= 1) ss += __shfl_xor(ss, m);
  float y = x * rsqrtf(ss * (1.f/64.f) + 1e-6f) * w[lane];
  float gv = GV[vec * 64 + lane];
  OG[vec * 64 + lane] = f2bf(y * gv / (1.f + __expf(-gv)));
}

extern "C" void kernel_launch(void* const* d_in, const int* in_sizes, int n_in,
                              void* d_out, int out_size, void* d_ws, size_t ws_size,
                              hipStream_t stream) {
  const float* h    = (const float*)d_in[0];
  const float* Wq   = (const float*)d_in[1];
  const float* Wk   = (const float*)d_in[2];
  const float* Wv   = (const float*)d_in[3];
  const float* Wa   = (const float*)d_in[4];
  const float* Wb   = (const float*)d_in[5];
  const float* Wg   = (const float*)d_in[6];
  const float* Wo   = (const float*)d_in[7];
  const float* qnw  = (const float*)d_in[8];
  const float* knw  = (const float*)d_in[9];
  const float* onw  = (const float*)d_in[10];
  const float* Alog = (const float*)d_in[11];
  const float* dtb  = (const float*)d_in[12];
  const float* cqw  = (const float*)d_in[13];
  const float* ckw  = (const float*)d_in[14];
  const float* cvw  = (const float*)d_in[15];
  float* out = (float*)d_out;
  float* ws  = (float*)d_ws;

  const size_t NB = (size_t)B_ * T_ * D_;
  float* qp   = ws;
  float* kp   = ws + 1*NB;
  float* vp   = ws + 2*NB;
  float* gvp  = ws + 3*NB;
  float* qc   = ws + 4*NB;
  float* kc   = ws + 5*NB;
  float* vc   = ws + 6*NB;
  float* mb   = ws + 7*NB;
  float* wbf  = ws + 8*NB;
  float* gb   = ws + 8*NB + 5*524288;
  float* bb   = gb + (size_t)B_*T_*H_;
  float* Gc   = bb + (size_t)B_*T_*H_;

  u16* h_bf  = (u16*)mb;
  u16* og_bf = (u16*)mb;
  u16* w_bf  = (u16*)wbf;
  u16* wq_bf = w_bf + 0*1048576;
  u16* wk_bf = w_bf + 1*1048576;
  u16* wv_bf = w_bf + 2*1048576;
  u16* wg_bf = w_bf + 3*1048576;
  u16* wo_bf = w_bf + 4*1048576;

  float* Ubuf = qp;
  float* Wbuf = kp;
  float* S0b  = vp;
  float* Mbuf = mb;
  float* Nbuf = vc;

  cvt_all<<<4608, 256, 0, stream>>>(h, Wq, Wk, Wv, Wg, Wo, h_bf, w_bf);

  gemm_bf16_4<<<dim3(32, 32), 256, 0, stream>>>(h_bf, wq_bf, wk_bf, wv_bf, wg_bf,
                                                 qp, kp, vp, gvp);
  smallproj<<<B_ * T_, 256, 0, stream>>>(h, Wa, Wb, Alog, dtb, gb, bb);

  convnorm<1><<<1024, 256, 0, stream>>>(qp, cqw, qnw, 0.125f, qc);
  convnorm<1><<<1024, 256, 0, stream>>>(kp, ckw, knw, 1.0f, kc);
  convnorm<0><<<1024, 256, 0, stream>>>(vp, cvw, qnw, 1.0f, vc);

  p1_chunk<<<B_*H_*NC_, 256, 0, stream>>>(kc, vc, gb, bb, Ubuf, Wbuf, Gc);
  p1b_mn<<<B_*H_*NC_, 256, 0, stream>>>(kc, Gc, Ubuf, Wbuf, Mbuf, Nbuf);
  pscanA<<<B_*H_*8, 256, 0, stream>>>(Mbuf, Nbuf);
  pscanB<<<B_*H_, 256, 0, stream>>>(Mbuf, Nbuf, S0b);
  pscanC<<<B_*H_*24, 256, 0, stream>>>(Mbuf, Nbuf, S0b);
  p3_out<<<B_*H_*NC_, 256, 0, stream>>>(qc, kc, Gc, S0b, Ubuf, Wbuf, out);

  ogate<<<B_*T_*D_/256, 256, 0, stream>>>(out, gvp, onw, og_bf);
  gemm_bf16_1<<<dim3(32, 8), 256, 0, stream>>>(og_bf, wo_bf, out);
}

// Round 8
// 313.937 us; speedup vs baseline: 12.8535x; 1.1483x over previous
//
#include <hip/hip_runtime.h>
#include <cstdint>
#include <cstddef>

#define B_ 2
#define T_ 2048
#define D_ 1024
#define H_ 16
#define HD_ 64
#define NC_ 32

typedef unsigned short u16;
typedef __attribute__((ext_vector_type(8))) short bf16x8;
typedef __attribute__((ext_vector_type(4))) float f32x4;

__device__ __forceinline__ float dot4(float4 a, float4 b, float acc) {
  return fmaf(a.x, b.x, fmaf(a.y, b.y, fmaf(a.z, b.z, fmaf(a.w, b.w, acc))));
}
__device__ __forceinline__ u16 f2bf(float f) {
  unsigned u = __float_as_uint(f);
  u += 0x7fffu + ((u >> 16) & 1u);
  return (u16)(u >> 16);
}
__device__ __forceinline__ float bf2f(u16 v) {
  return __uint_as_float(((unsigned)v) << 16);
}
__device__ __forceinline__ bf16x8 pack8(float4 a, float4 b) {
  union { u16 us[8]; bf16x8 v; } p;
  p.us[0] = f2bf(a.x); p.us[1] = f2bf(a.y); p.us[2] = f2bf(a.z); p.us[3] = f2bf(a.w);
  p.us[4] = f2bf(b.x); p.us[5] = f2bf(b.y); p.us[6] = f2bf(b.z); p.us[7] = f2bf(b.w);
  return p.v;
}
__device__ __forceinline__ void glds16(const u16* g, u16* l) {
  __builtin_amdgcn_global_load_lds(
      (const __attribute__((address_space(1))) void*)g,
      (__attribute__((address_space(3))) void*)l, 16, 0, 0);
}

// ---------------- fp32 -> bf16 conversion (h + 5 weights, one launch) ----------------
__global__ __launch_bounds__(256) void cvt_all(
    const float* __restrict__ h, const float* __restrict__ w0,
    const float* __restrict__ w1, const float* __restrict__ w2,
    const float* __restrict__ w3, const float* __restrict__ w4,
    u16* __restrict__ h_bf, u16* __restrict__ wb)
{
  const int blk = blockIdx.x;
  const float* src;
  u16* dst;
  int lb;
  if (blk < 2048) { src = h; dst = h_bf; lb = blk; }
  else {
    int k = (blk - 2048) >> 9, r = (blk - 2048) & 511;
    src = k == 0 ? w0 : k == 1 ? w1 : k == 2 ? w2 : k == 3 ? w3 : w4;
    dst = wb + (size_t)k * 1048576;
    lb = r;
  }
  int i = (lb * 256 + threadIdx.x) * 8;
  float4 v0 = *(const float4*)(src + i);
  float4 v1 = *(const float4*)(src + i + 4);
  union { u16 us[8]; uint4 u4; } p;
  p.us[0] = f2bf(v0.x); p.us[1] = f2bf(v0.y); p.us[2] = f2bf(v0.z); p.us[3] = f2bf(v0.w);
  p.us[4] = f2bf(v1.x); p.us[5] = f2bf(v1.y); p.us[6] = f2bf(v1.z); p.us[7] = f2bf(v1.w);
  *(uint4*)(dst + i) = p.u4;
}

// ---------------- bf16 MFMA GEMM core (m97-style: global_load_lds, linear LDS) ----------------
__device__ __forceinline__ void gemm_core(const u16* __restrict__ A,
    const u16* __restrict__ Bw, float* __restrict__ C,
    u16* As, u16* Bs, int row0, int col0, int K, int N)
{
  const int tid = threadIdx.x;
  const int lane = tid & 63, wave = tid >> 6;
  const int wr = (wave >> 1) * 64, wc = (wave & 1) * 64;
  const int lr = lane & 15, lk = (lane >> 4) * 8;
  const int rql = (lane >> 2);
  const int cql = (lane & 3) * 8;
  const u16* gA0 = A + (size_t)(row0 + wave * 16 + rql) * K + cql;
  const u16* gA1 = A + (size_t)(row0 + (wave + 4) * 16 + rql) * K + cql;
  const u16* gB0 = Bw + (size_t)(col0 + wave * 16 + rql) * K + cql;
  const u16* gB1 = Bw + (size_t)(col0 + (wave + 4) * 16 + rql) * K + cql;
  u16* lA0 = As + wave * 16 * 32;
  u16* lA1 = As + (wave + 4) * 16 * 32;
  u16* lB0 = Bs + wave * 16 * 32;
  u16* lB1 = Bs + (wave + 4) * 16 * 32;

  f32x4 acc[4][4];
  #pragma unroll
  for (int i = 0; i < 4; ++i)
    #pragma unroll
    for (int j = 0; j < 4; ++j) acc[i][j] = f32x4{0.f, 0.f, 0.f, 0.f};

  const int KT = K >> 5;
  for (int kt = 0; kt < KT; ++kt) {
    glds16(gA0 + kt * 32, lA0);
    glds16(gA1 + kt * 32, lA1);
    glds16(gB0 + kt * 32, lB0);
    glds16(gB1 + kt * 32, lB1);
    __syncthreads();
    bf16x8 af[4], bf[4];
    #pragma unroll
    for (int i = 0; i < 4; ++i) af[i] = *(const bf16x8*)&As[(wr + i * 16 + lr) * 32 + lk];
    #pragma unroll
    for (int j = 0; j < 4; ++j) bf[j] = *(const bf16x8*)&Bs[(wc + j * 16 + lr) * 32 + lk];
    #pragma unroll
    for (int i = 0; i < 4; ++i)
      #pragma unroll
      for (int j = 0; j < 4; ++j)
        acc[i][j] = __builtin_amdgcn_mfma_f32_16x16x32_bf16(af[i], bf[j], acc[i][j], 0, 0, 0);
    __syncthreads();
  }
  const int orow = row0 + wr + (lane >> 4) * 4;
  const int ocol = col0 + wc + lr;
  #pragma unroll
  for (int i = 0; i < 4; ++i)
    #pragma unroll
    for (int j = 0; j < 4; ++j)
      #pragma unroll
      for (int r = 0; r < 4; ++r)
        C[(size_t)(orow + i * 16 + r) * N + ocol + j * 16] = acc[i][j][r];
}

__global__ __launch_bounds__(256) void gemm_bf16_4(const u16* __restrict__ A,
    const u16* __restrict__ W0, const u16* __restrict__ W1,
    const u16* __restrict__ W2, const u16* __restrict__ W3,
    float* __restrict__ C0, float* __restrict__ C1,
    float* __restrict__ C2, float* __restrict__ C3)
{
  __shared__ u16 As[128 * 32];
  __shared__ u16 Bs[128 * 32];
  const int sel = blockIdx.y >> 3;
  const u16* Bw = sel == 0 ? W0 : sel == 1 ? W1 : sel == 2 ? W2 : W3;
  float* C = sel == 0 ? C0 : sel == 1 ? C1 : sel == 2 ? C2 : C3;
  gemm_core(A, Bw, C, As, Bs, blockIdx.x * 128, (blockIdx.y & 7) * 128, 1024, 1024);
}

__global__ __launch_bounds__(256) void gemm_bf16_1(const u16* __restrict__ A,
    const u16* __restrict__ Bw, float* __restrict__ C)
{
  __shared__ u16 As[128 * 32];
  __shared__ u16 Bs[128 * 32];
  gemm_core(A, Bw, C, As, Bs, blockIdx.x * 128, blockIdx.y * 128, 1024, 1024);
}

// ---------------- beta / g small projections ----------------
__global__ __launch_bounds__(256) void smallproj(const float* __restrict__ Hs,
    const float* __restrict__ Wa, const float* __restrict__ Wb,
    const float* __restrict__ Alog, const float* __restrict__ dtb,
    float* __restrict__ Gout, float* __restrict__ Bout)
{
  __shared__ float hs[D_];
  const int bt = blockIdx.x;
  for (int i = threadIdx.x; i < D_; i += 256) hs[i] = Hs[(size_t)bt * D_ + i];
  __syncthreads();
  const int grp = threadIdx.x >> 3, p = threadIdx.x & 7;
  const int head = grp & 15, which = grp >> 4;
  const float* Wr = (which ? Wb : Wa) + head * D_;
  float s = 0.f;
  for (int i = p; i < D_; i += 8) s = fmaf(hs[i], Wr[i], s);
  s += __shfl_xor(s, 1); s += __shfl_xor(s, 2); s += __shfl_xor(s, 4);
  if (p == 0) {
    if (which) {
      Bout[(size_t)bt * H_ + head] = 1.f / (1.f + __expf(-s));
    } else {
      float x = s + dtb[head];
      float sp = fmaxf(x, 0.f) + log1pf(__expf(-fabsf(x)));
      Gout[(size_t)bt * H_ + head] = -__expf(Alog[head]) * sp;
    }
  }
}

// ---------------- fused causal conv(K=4)+SiLU [+ RMSNorm+L2norm] ----------------
template<int NORM>
__global__ __launch_bounds__(256) void convnorm(const float* __restrict__ X,
    const float* __restrict__ W, const float* __restrict__ nw, float fs,
    float* __restrict__ Y)
{
  __shared__ float Xs[67][65];
  __shared__ float nwS[64];
  const int blk = blockIdx.x;
  const int tt = blk & 31, hh = (blk >> 5) & 15, b = blk >> 9;
  const int t0 = tt * 64;
  const int d = threadIdx.x & 63, tq = threadIdx.x >> 6;
  for (int e = threadIdx.x; e < 67 * 64; e += 256) {
    int r = e >> 6, dd = e & 63;
    int t = t0 - 3 + r;
    Xs[r][dd] = (t >= 0) ? X[((size_t)b * T_ + t) * D_ + hh * 64 + dd] : 0.f;
  }
  if (NORM && threadIdx.x < 64) nwS[threadIdx.x] = nw[threadIdx.x];
  __syncthreads();
  const float4 w = *(const float4*)(W + (hh * 64 + d) * 4);
  #pragma unroll 4
  for (int it = 0; it < 16; ++it) {
    const int lt = tq * 16 + it;
    float a = fmaf(w.x, Xs[lt][d], fmaf(w.y, Xs[lt + 1][d],
              fmaf(w.z, Xs[lt + 2][d], w.w * Xs[lt + 3][d])));
    float y = a / (1.f + __expf(-a));
    if (NORM) {
      float ss = y * y;
      #pragma unroll
      for (int m = 1; m < 64; m <<= 1) ss += __shfl_xor(ss, m);
      float z = y * rsqrtf(ss * (1.f / 64.f) + 1e-6f) * nwS[d];
      float s2 = z * z;
      #pragma unroll
      for (int m = 1; m < 64; m <<= 1) s2 += __shfl_xor(s2, m);
      y = z * rsqrtf(s2 + 1e-6f) * fs;
    }
    Y[((size_t)b * T_ + t0 + lt) * D_ + hh * 64 + d] = y;
  }
}

// ---------------- P1: MFMA A = scale(K K^T), blocked MFMA solve -> U, W ----------------
__global__ __launch_bounds__(256) void p1_chunk(
    const float* __restrict__ Kc, const float* __restrict__ Vc,
    const float* __restrict__ Gg, const float* __restrict__ Bb,
    float* __restrict__ Ubuf, float* __restrict__ Wbuf, float* __restrict__ Gcum)
{
  __shared__ u16 Kbf[64][72];
  __shared__ float Am[64][68];
  __shared__ float XT[128][68];   // XT[col][t]; cols 0..63 U-rhs, 64..127 W-rhs
  __shared__ float gc[64], bet[64];
  const int bhc = blockIdx.x;
  const int bh = bhc >> 5, c = bhc & 31;
  const int b = bh >> 4, h = bh & 15;
  const int tid = threadIdx.x;
  const int lane = tid & 63, wave = tid >> 6;
  const int lr = lane & 15, lkq = lane >> 4;
  const size_t rowbase = ((size_t)b*T_ + c*64)*H_ + h;

  if (tid < 64) {
    float gv = Gg[rowbase + (size_t)tid*H_];
    #pragma unroll
    for (int off = 1; off < 64; off <<= 1) {
      float up = __shfl_up(gv, off, 64);
      if (tid >= off) gv += up;
    }
    gc[tid] = gv;
    Gcum[(size_t)bhc*64 + tid] = gv;
    bet[tid] = Bb[rowbase + (size_t)tid*H_];
  }
  // stage K -> bf16 LDS
  for (int e4 = tid; e4 < 1024; e4 += 256) {
    int t = e4 >> 4, d4 = (e4 & 15) * 4;
    float4 v = *(const float4*)&Kc[(rowbase + (size_t)t*H_)*64 + d4];
    u16 tmp[4] = {f2bf(v.x), f2bf(v.y), f2bf(v.z), f2bf(v.w)};
    *(uint2*)&Kbf[t][d4] = *(uint2*)tmp;
  }
  __syncthreads();

  // A-phase: wave w computes t-strip [16w,16w+16) x all s
  {
    bf16x8 afA[2];
    #pragma unroll
    for (int ks = 0; ks < 2; ++ks)
      afA[ks] = *(const bf16x8*)&Kbf[16*wave + lr][ks*32 + lkq*8];
    #pragma unroll
    for (int j = 0; j < 4; ++j) {
      f32x4 accA = f32x4{0.f, 0.f, 0.f, 0.f};
      #pragma unroll
      for (int ks = 0; ks < 2; ++ks) {
        bf16x8 bfr = *(const bf16x8*)&Kbf[16*j + lr][ks*32 + lkq*8];
        accA = __builtin_amdgcn_mfma_f32_16x16x32_bf16(afA[ks], bfr, accA, 0, 0, 0);
      }
      const int s = 16*j + lr;
      #pragma unroll
      for (int r = 0; r < 4; ++r) {
        int t = 16*wave + lkq*4 + r;
        Am[t][s] = (s < t) ? bet[t] * __expf(gc[t] - gc[s]) * accA[r] : 0.f;
      }
    }
  }
  // RHS fill
  for (int e4 = tid; e4 < 1024; e4 += 256) {
    int t = e4 >> 4, j4 = (e4 & 15) * 4;
    float bt = bet[t];
    float ek = bt * __expf(gc[t]);
    float4 vv = *(const float4*)&Vc[(rowbase + (size_t)t*H_)*64 + j4];
    XT[j4+0][t] = bt * vv.x; XT[j4+1][t] = bt * vv.y;
    XT[j4+2][t] = bt * vv.z; XT[j4+3][t] = bt * vv.w;
    XT[64+j4+0][t] = ek * bf2f(Kbf[t][j4+0]);
    XT[64+j4+1][t] = ek * bf2f(Kbf[t][j4+1]);
    XT[64+j4+2][t] = ek * bf2f(Kbf[t][j4+2]);
    XT[64+j4+3][t] = ek * bf2f(Kbf[t][j4+3]);
  }
  __syncthreads();

  // blocked forward substitution: 4 stages of 16 rows
  for (int st = 0; st < 4; ++st) {
    if (st > 0) {
      const int nks = (st == 3) ? 2 : 1;
      f32x4 accU0 = f32x4{0.f,0.f,0.f,0.f}, accU1 = f32x4{0.f,0.f,0.f,0.f};
      for (int ks = 0; ks < nks; ++ks) {
        const int m0 = ks*32 + lkq*8;
        bf16x8 af;
        if (m0 + 8 <= 16*st) {
          float4 a0 = *(const float4*)&Am[16*st + lr][m0];
          float4 a1 = *(const float4*)&Am[16*st + lr][m0 + 4];
          af = pack8(a0, a1);
        } else {
          af = bf16x8{0,0,0,0,0,0,0,0};
        }
        {
          const int cb = (wave*2 + 0) * 16;
          float4 b0 = *(const float4*)&XT[cb + lr][m0];
          float4 b1 = *(const float4*)&XT[cb + lr][m0 + 4];
          accU0 = __builtin_amdgcn_mfma_f32_16x16x32_bf16(af, pack8(b0, b1), accU0, 0, 0, 0);
        }
        {
          const int cb = (wave*2 + 1) * 16;
          float4 b0 = *(const float4*)&XT[cb + lr][m0];
          float4 b1 = *(const float4*)&XT[cb + lr][m0 + 4];
          accU1 = __builtin_amdgcn_mfma_f32_16x16x32_bf16(af, pack8(b0, b1), accU1, 0, 0, 0);
        }
      }
      #pragma unroll
      for (int r = 0; r < 4; ++r) {
        const int t = 16*st + lkq*4 + r;
        XT[(wave*2+0)*16 + lr][t] -= accU0[r];
        XT[(wave*2+1)*16 + lr][t] -= accU1[r];
      }
      __syncthreads();
    }
    if (tid < 128) {
      const int bs = 16*st;
      float x[16];
      #pragma unroll
      for (int q = 0; q < 4; ++q)
        *(float4*)&x[q*4] = *(const float4*)&XT[tid][bs + q*4];
      #pragma unroll
      for (int tau = 1; tau < 16; ++tau) {
        float a = 0.f, a2 = 0.f;
        #pragma unroll
        for (int m = 0; m < tau; m += 2) {
          a = fmaf(Am[bs+tau][bs+m], x[m], a);
          if (m + 1 < tau) a2 = fmaf(Am[bs+tau][bs+m+1], x[m+1], a2);
        }
        x[tau] -= (a + a2);
      }
      #pragma unroll
      for (int q = 0; q < 4; ++q)
        *(float4*)&XT[tid][bs + q*4] = *(const float4*)&x[q*4];
    }
    __syncthreads();
  }

  for (int e = tid; e < 4096; e += 256) {
    int t = e >> 6, j = e & 63;
    Ubuf[(size_t)bhc*4096 + e] = XT[j][t];
    Wbuf[(size_t)bhc*4096 + e] = XT[64+j][t];
  }
}

// ---------------- P1b (MFMA): M = bC*I - Ksc^T W, N = Ksc^T U ----------------
__global__ __launch_bounds__(256) void p1b_mn(
    const float* __restrict__ Kc, const float* __restrict__ Gcum,
    const float* __restrict__ Ubuf, const float* __restrict__ Wbuf,
    float* __restrict__ Mbuf, float* __restrict__ Nbuf)
{
  __shared__ u16 KscT[64][72];   // [a][t] = e^{gC-gc_t} K[t][a]
  __shared__ u16 WT[64][72];     // [c][t] = W[t][c]
  __shared__ u16 UT[64][72];     // [c][t] = U[t][c]
  __shared__ float gcs[64];
  const int bhc = blockIdx.x;
  const int bh = bhc >> 5, c = bhc & 31;
  const int b = bh >> 4, h = bh & 15;
  const int tid = threadIdx.x;
  const int lane = tid & 63, wave = tid >> 6;
  const int lr = lane & 15, lkq = lane >> 4;
  const size_t rowbase = ((size_t)b*T_ + c*64)*H_ + h;
  if (tid < 64) gcs[tid] = Gcum[(size_t)bhc*64 + tid];
  __syncthreads();
  const float gC = gcs[63];
  for (int e4 = tid; e4 < 1024; e4 += 256) {
    int t = e4 >> 4, a4 = (e4 & 15) * 4;
    float sc = __expf(gC - gcs[t]);
    float4 kv = *(const float4*)&Kc[(rowbase + (size_t)t*H_)*64 + a4];
    KscT[a4+0][t] = f2bf(sc*kv.x); KscT[a4+1][t] = f2bf(sc*kv.y);
    KscT[a4+2][t] = f2bf(sc*kv.z); KscT[a4+3][t] = f2bf(sc*kv.w);
    float4 wv = *(const float4*)&Wbuf[(size_t)bhc*4096 + (size_t)t*64 + a4];
    WT[a4+0][t] = f2bf(wv.x); WT[a4+1][t] = f2bf(wv.y);
    WT[a4+2][t] = f2bf(wv.z); WT[a4+3][t] = f2bf(wv.w);
    float4 uv = *(const float4*)&Ubuf[(size_t)bhc*4096 + (size_t)t*64 + a4];
    UT[a4+0][t] = f2bf(uv.x); UT[a4+1][t] = f2bf(uv.y);
    UT[a4+2][t] = f2bf(uv.z); UT[a4+3][t] = f2bf(uv.w);
  }
  __syncthreads();

  bf16x8 af[2];
  #pragma unroll
  for (int ks = 0; ks < 2; ++ks)
    af[ks] = *(const bf16x8*)&KscT[16*wave + lr][ks*32 + lkq*8];
  const float bC = __expf(gC);
  const size_t ob = (size_t)bhc * 4096;
  #pragma unroll
  for (int j = 0; j < 4; ++j) {
    f32x4 aM = f32x4{0.f,0.f,0.f,0.f}, aN = f32x4{0.f,0.f,0.f,0.f};
    #pragma unroll
    for (int ks = 0; ks < 2; ++ks) {
      bf16x8 bw = *(const bf16x8*)&WT[16*j + lr][ks*32 + lkq*8];
      bf16x8 bu = *(const bf16x8*)&UT[16*j + lr][ks*32 + lkq*8];
      aM = __builtin_amdgcn_mfma_f32_16x16x32_bf16(af[ks], bw, aM, 0, 0, 0);
      aN = __builtin_amdgcn_mfma_f32_16x16x32_bf16(af[ks], bu, aN, 0, 0, 0);
    }
    const int cc = 16*j + lr;
    #pragma unroll
    for (int r = 0; r < 4; ++r) {
      const int a = 16*wave + lkq*4 + r;
      Mbuf[ob + (size_t)a*64 + cc] = (a == cc ? bC : 0.f) - aM[r];
      Nbuf[ob + (size_t)a*64 + cc] = aN[r];
    }
  }
}

// ---------------- pscanA: in-place group-of-4 prefix composition ----------------
__global__ __launch_bounds__(256) void pscanA(float* __restrict__ Mbuf,
    float* __restrict__ Nbuf)
{
  __shared__ float OM[2][64][68];
  __shared__ float ON[2][64][68];
  __shared__ float NM[2][64][68];
  const int blk = blockIdx.x;            // 32 bh * 8 groups
  const int bh = blk >> 3, g = blk & 7;
  const size_t s0 = ((size_t)bh * 32 + g * 4) * 4096;
  const int tid = threadIdx.x;
  const int p0 = (tid >> 4) * 4;
  const int q0 = (tid & 15) * 4;
  for (int e4 = tid; e4 < 1024; e4 += 256) {
    int r = e4 >> 4, c4 = (e4 & 15) * 4;
    *(float4*)&OM[0][r][c4] = *(const float4*)&Mbuf[s0 + (size_t)r*64 + c4];
    *(float4*)&ON[0][r][c4] = *(const float4*)&Nbuf[s0 + (size_t)r*64 + c4];
    *(float4*)&NM[0][r][c4] = *(const float4*)&Mbuf[s0 + 4096 + (size_t)r*64 + c4];
  }
  __syncthreads();
  for (int s = 0; s < 3; ++s) {
    const int cur = s & 1, nxt = cur ^ 1;
    const size_t wslot = s0 + (size_t)(s + 1) * 4096;
    if (s < 2) {
      for (int e4 = tid; e4 < 1024; e4 += 256) {
        int r = e4 >> 4, c4 = (e4 & 15) * 4;
        *(float4*)&NM[nxt][r][c4] = *(const float4*)&Mbuf[wslot + 4096 + (size_t)r*64 + c4];
      }
    }
    float aM[4][4], aN[4][4];
    #pragma unroll
    for (int r = 0; r < 4; ++r) {
      float4 nv = *(const float4*)&Nbuf[wslot + (size_t)(p0+r)*64 + q0];
      aM[r][0]=0.f; aM[r][1]=0.f; aM[r][2]=0.f; aM[r][3]=0.f;
      aN[r][0]=nv.x; aN[r][1]=nv.y; aN[r][2]=nv.z; aN[r][3]=nv.w;
    }
    for (int m4 = 0; m4 < 64; m4 += 4) {
      float xv[4][4];
      #pragma unroll
      for (int r = 0; r < 4; ++r) {
        float4 v = *(const float4*)&NM[cur][p0+r][m4];
        xv[r][0]=v.x; xv[r][1]=v.y; xv[r][2]=v.z; xv[r][3]=v.w;
      }
      #pragma unroll
      for (int mm = 0; mm < 4; ++mm) {
        float4 ym = *(const float4*)&OM[cur][m4+mm][q0];
        float4 yn = *(const float4*)&ON[cur][m4+mm][q0];
        #pragma unroll
        for (int r = 0; r < 4; ++r) {
          aM[r][0] = fmaf(xv[r][mm], ym.x, aM[r][0]);
          aM[r][1] = fmaf(xv[r][mm], ym.y, aM[r][1]);
          aM[r][2] = fmaf(xv[r][mm], ym.z, aM[r][2]);
          aM[r][3] = fmaf(xv[r][mm], ym.w, aM[r][3]);
          aN[r][0] = fmaf(xv[r][mm], yn.x, aN[r][0]);
          aN[r][1] = fmaf(xv[r][mm], yn.y, aN[r][1]);
          aN[r][2] = fmaf(xv[r][mm], yn.z, aN[r][2]);
          aN[r][3] = fmaf(xv[r][mm], yn.w, aN[r][3]);
        }
      }
    }
    #pragma unroll
    for (int r = 0; r < 4; ++r) {
      float4 vm = {aM[r][0], aM[r][1], aM[r][2], aM[r][3]};
      float4 vn = {aN[r][0], aN[r][1], aN[r][2], aN[r][3]};
      *(float4*)&Mbuf[wslot + (size_t)(p0+r)*64 + q0] = vm;
      *(float4*)&Nbuf[wslot + (size_t)(p0+r)*64 + q0] = vn;
      *(float4*)&OM[nxt][p0+r][q0] = vm;
      *(float4*)&ON[nxt][p0+r][q0] = vn;
    }
    __syncthreads();
  }
}

// ---------------- pscanB: serial carry over 8 group totals (ST-form) ----------------
__global__ __launch_bounds__(256) void pscanB(const float* __restrict__ Mbuf,
    const float* __restrict__ Nbuf, float* __restrict__ S0b)
{
  __shared__ float ST[2][64][68];
  __shared__ float MT[64][68];
  const int bh = blockIdx.x;
  const size_t base = (size_t)bh * 32 * 4096;
  const int tid = threadIdx.x;
  const int j0 = (tid >> 4) * 4, a0 = tid & 15;
  for (int e4 = tid; e4 < 1024; e4 += 256) {
    int r = e4 >> 4, c4 = (e4 & 15) * 4;
    *(float4*)&ST[0][r][c4] = float4{0.f, 0.f, 0.f, 0.f};
    *(float4*)&S0b[base + (size_t)r*64 + c4] = float4{0.f, 0.f, 0.f, 0.f};
  }
  for (int g = 0; g < 7; ++g) {
    const int cur = g & 1, nxt = cur ^ 1;
    const size_t tslot = base + (size_t)(4*g + 3) * 4096;
    for (int e4 = tid; e4 < 1024; e4 += 256) {
      int r = e4 >> 4, c4 = (e4 & 15) * 4;
      *(float4*)&MT[r][c4] = *(const float4*)&Mbuf[tslot + (size_t)r*64 + c4];
    }
    float acc[4][4];
    #pragma unroll
    for (int r = 0; r < 4; ++r)
      #pragma unroll
      for (int s = 0; s < 4; ++s)
        acc[r][s] = Nbuf[tslot + (size_t)(a0 + 16*s)*64 + j0 + r];
    __syncthreads();
    for (int k4 = 0; k4 < 64; k4 += 4) {
      float4 xr[4];
      #pragma unroll
      for (int r = 0; r < 4; ++r) xr[r] = *(const float4*)&ST[cur][j0+r][k4];
      #pragma unroll
      for (int s = 0; s < 4; ++s) {
        float4 yv = *(const float4*)&MT[a0 + 16*s][k4];
        #pragma unroll
        for (int r = 0; r < 4; ++r) acc[r][s] = dot4(xr[r], yv, acc[r][s]);
      }
    }
    const size_t oslot = base + (size_t)(4*(g+1)) * 4096;
    #pragma unroll
    for (int r = 0; r < 4; ++r)
      #pragma unroll
      for (int s = 0; s < 4; ++s) {
        ST[nxt][j0+r][a0 + 16*s] = acc[r][s];
        S0b[oslot + (size_t)(j0+r)*64 + a0 + 16*s] = acc[r][s];
      }
    __syncthreads();
  }
}

// ---------------- pscanC: intra-group states (parallel) ----------------
__global__ __launch_bounds__(256) void pscanC(const float* __restrict__ Mbuf,
    const float* __restrict__ Nbuf, float* __restrict__ S0b)
{
  __shared__ float ST[64][68];
  __shared__ float MT[64][68];
  const int blk = blockIdx.x;            // 32 bh * 8 groups * 3
  const int bh = blk / 24, rem = blk % 24;
  const int g = rem / 3, i = rem % 3 + 1;
  const size_t base = (size_t)bh * 32 * 4096;
  const size_t pslot = base + (size_t)(4*g + i - 1) * 4096;
  const int tid = threadIdx.x;
  const int j0 = (tid >> 4) * 4, a0 = tid & 15;
  for (int e4 = tid; e4 < 1024; e4 += 256) {
    int r = e4 >> 4, c4 = (e4 & 15) * 4;
    *(float4*)&ST[r][c4] = *(const float4*)&S0b[base + (size_t)(4*g)*4096 + (size_t)r*64 + c4];
    *(float4*)&MT[r][c4] = *(const float4*)&Mbuf[pslot + (size_t)r*64 + c4];
  }
  float acc[4][4];
  #pragma unroll
  for (int r = 0; r < 4; ++r)
    #pragma unroll
    for (int s = 0; s < 4; ++s)
      acc[r][s] = Nbuf[pslot + (size_t)(a0 + 16*s)*64 + j0 + r];
  __syncthreads();
  for (int k4 = 0; k4 < 64; k4 += 4) {
    float4 xr[4];
    #pragma unroll
    for (int r = 0; r < 4; ++r) xr[r] = *(const float4*)&ST[j0+r][k4];
    #pragma unroll
    for (int s = 0; s < 4; ++s) {
      float4 yv = *(const float4*)&MT[a0 + 16*s][k4];
      #pragma unroll
      for (int r = 0; r < 4; ++r) acc[r][s] = dot4(xr[r], yv, acc[r][s]);
    }
  }
  const size_t oslot = base + (size_t)(4*g + i) * 4096;
  #pragma unroll
  for (int r = 0; r < 4; ++r)
    #pragma unroll
    for (int s = 0; s < 4; ++s)
      S0b[oslot + (size_t)(j0+r)*64 + a0 + 16*s] = acc[r][s];
}

// ---------------- P3 (MFMA): delta + outputs ----------------
// O = e^{gc} Q@S0 + tril(decay o QK^T) @ (U - W@S0)
__global__ __launch_bounds__(256) void p3_out(
    const float* __restrict__ Qc, const float* __restrict__ Kc,
    const float* __restrict__ Gcum, const float* __restrict__ S0b,
    const float* __restrict__ Ubuf, const float* __restrict__ Wbuf,
    float* __restrict__ O)
{
  __shared__ u16 Qbf[64][72];
  __shared__ u16 Kbf[64][72];
  __shared__ u16 S0T[64][72];    // [j][i] (S0b layout)
  __shared__ u16 Wbf[64][72];
  __shared__ u16 Pbf[64][72];    // [t][s]
  __shared__ u16 DsT[64][72];    // [j][s]
  __shared__ float gcs[64];
  const int bhc = blockIdx.x;
  const int bh = bhc >> 5, c = bhc & 31;
  const int b = bh >> 4, h = bh & 15;
  const int tid = threadIdx.x;
  const int lane = tid & 63, wave = tid >> 6;
  const int lr = lane & 15, lkq = lane >> 4;
  const size_t rowbase = ((size_t)b*T_ + c*64)*H_ + h;
  if (tid < 64) gcs[tid] = Gcum[(size_t)bhc*64 + tid];
  for (int e4 = tid; e4 < 1024; e4 += 256) {
    int t = e4 >> 4, d4 = (e4 & 15) * 4;
    size_t ga = (rowbase + (size_t)t*H_)*64 + d4;
    float4 qv = *(const float4*)&Qc[ga];
    float4 kv = *(const float4*)&Kc[ga];
    float4 sv = *(const float4*)&S0b[(size_t)bhc*4096 + (size_t)t*64 + d4];
    float4 wv = *(const float4*)&Wbuf[(size_t)bhc*4096 + (size_t)t*64 + d4];
    u16 aq[4] = {f2bf(qv.x), f2bf(qv.y), f2bf(qv.z), f2bf(qv.w)};
    u16 ak[4] = {f2bf(kv.x), f2bf(kv.y), f2bf(kv.z), f2bf(kv.w)};
    u16 as[4] = {f2bf(sv.x), f2bf(sv.y), f2bf(sv.z), f2bf(sv.w)};
    u16 aw[4] = {f2bf(wv.x), f2bf(wv.y), f2bf(wv.z), f2bf(wv.w)};
    *(uint2*)&Qbf[t][d4] = *(uint2*)aq;
    *(uint2*)&Kbf[t][d4] = *(uint2*)ak;
    *(uint2*)&S0T[t][d4] = *(uint2*)as;
    *(uint2*)&Wbf[t][d4] = *(uint2*)aw;
  }
  __syncthreads();

  const int trow0 = 16*wave + lkq*4;
  bf16x8 aq[2], aw[2];
  #pragma unroll
  for (int ks = 0; ks < 2; ++ks) {
    aq[ks] = *(const bf16x8*)&Qbf[16*wave + lr][ks*32 + lkq*8];
    aw[ks] = *(const bf16x8*)&Wbf[16*wave + lr][ks*32 + lkq*8];
  }
  float gct[4], egt[4];
  #pragma unroll
  for (int r = 0; r < 4; ++r) { gct[r] = gcs[trow0 + r]; egt[r] = __expf(gct[r]); }

  // Phase B: P[t][s] = (s<=t) e^{gc_t-gc_s} q_t.k_s   (wave's t-strip)
  #pragma unroll
  for (int j = 0; j < 4; ++j) {
    f32x4 pa = f32x4{0.f,0.f,0.f,0.f};
    #pragma unroll
    for (int ks = 0; ks < 2; ++ks) {
      bf16x8 bk = *(const bf16x8*)&Kbf[16*j + lr][ks*32 + lkq*8];
      pa = __builtin_amdgcn_mfma_f32_16x16x32_bf16(aq[ks], bk, pa, 0, 0, 0);
    }
    const int s = 16*j + lr;
    const float gs = gcs[s];
    #pragma unroll
    for (int r = 0; r < 4; ++r) {
      const int t = trow0 + r;
      float val = (s <= t) ? __expf(gct[r] - gs) * pa[r] : 0.f;
      Pbf[t][s] = f2bf(val);
    }
  }

  // Phase D: delta[s][j] = U[s][j] - (W@S0)[s][j]  (wave's s-strip), store DsT[j][s]
  #pragma unroll
  for (int j = 0; j < 4; ++j) {
    f32x4 da = f32x4{0.f,0.f,0.f,0.f};
    #pragma unroll
    for (int ks = 0; ks < 2; ++ks) {
      bf16x8 bs = *(const bf16x8*)&S0T[16*j + lr][ks*32 + lkq*8];
      da = __builtin_amdgcn_mfma_f32_16x16x32_bf16(aw[ks], bs, da, 0, 0, 0);
    }
    const int jj = 16*j + lr;
    #pragma unroll
    for (int r = 0; r < 4; ++r) {
      const int s = trow0 + r;
      float dv = Ubuf[(size_t)bhc*4096 + (size_t)s*64 + jj] - da[r];
      DsT[jj][s] = f2bf(dv);
    }
  }

  // Phase A: oacc = e^{gc_t} * (Q @ S0)  (wave's t-strip)
  f32x4 oacc[4];
  #pragma unroll
  for (int j = 0; j < 4; ++j) {
    f32x4 oa = f32x4{0.f,0.f,0.f,0.f};
    #pragma unroll
    for (int ks = 0; ks < 2; ++ks) {
      bf16x8 bs = *(const bf16x8*)&S0T[16*j + lr][ks*32 + lkq*8];
      oa = __builtin_amdgcn_mfma_f32_16x16x32_bf16(aq[ks], bs, oa, 0, 0, 0);
    }
    #pragma unroll
    for (int r = 0; r < 4; ++r) oa[r] *= egt[r];
    oacc[j] = oa;
  }
  __syncthreads();   // DsT complete across waves (Pbf is wave-local)

  // Phase C: oacc += P @ delta
  bf16x8 ap[2];
  #pragma unroll
  for (int ks = 0; ks < 2; ++ks)
    ap[ks] = *(const bf16x8*)&Pbf[16*wave + lr][ks*32 + lkq*8];
  #pragma unroll
  for (int j = 0; j < 4; ++j) {
    #pragma unroll
    for (int ks = 0; ks < 2; ++ks) {
      bf16x8 bd = *(const bf16x8*)&DsT[16*j + lr][ks*32 + lkq*8];
      oacc[j] = __builtin_amdgcn_mfma_f32_16x16x32_bf16(ap[ks], bd, oacc[j], 0, 0, 0);
    }
  }
  #pragma unroll
  for (int j = 0; j < 4; ++j) {
    const int jj = 16*j + lr;
    #pragma unroll
    for (int r = 0; r < 4; ++r) {
      const int t = trow0 + r;
      O[(rowbase + (size_t)t*H_)*64 + jj] = oacc[j][r];
    }
  }
}

// ---------------- o-norm * swish(gv) -> bf16 ----------------
__global__ __launch_bounds__(256) void ogate(const float* __restrict__ O,
    const float* __restrict__ GV, const float* __restrict__ w,
    u16* __restrict__ OG)
{
  const size_t gid = (size_t)blockIdx.x * 256 + threadIdx.x;
  const size_t vec = gid >> 6;
  const int lane = threadIdx.x & 63;
  float x = O[vec * 64 + lane];
  float ss = x * x;
  #pragma unroll
  for (int m = 1; m < 64; m <<= 1) ss += __shfl_xor(ss, m);
  float y = x * rsqrtf(ss * (1.f/64.f) + 1e-6f) * w[lane];
  float gv = GV[vec * 64 + lane];
  OG[vec * 64 + lane] = f2bf(y * gv / (1.f + __expf(-gv)));
}

extern "C" void kernel_launch(void* const* d_in, const int* in_sizes, int n_in,
                              void* d_out, int out_size, void* d_ws, size_t ws_size,
                              hipStream_t stream) {
  const float* h    = (const float*)d_in[0];
  const float* Wq   = (const float*)d_in[1];
  const float* Wk   = (const float*)d_in[2];
  const float* Wv   = (const float*)d_in[3];
  const float* Wa   = (const float*)d_in[4];
  const float* Wb   = (const float*)d_in[5];
  const float* Wg   = (const float*)d_in[6];
  const float* Wo   = (const float*)d_in[7];
  const float* qnw  = (const float*)d_in[8];
  const float* knw  = (const float*)d_in[9];
  const float* onw  = (const float*)d_in[10];
  const float* Alog = (const float*)d_in[11];
  const float* dtb  = (const float*)d_in[12];
  const float* cqw  = (const float*)d_in[13];
  const float* ckw  = (const float*)d_in[14];
  const float* cvw  = (const float*)d_in[15];
  float* out = (float*)d_out;
  float* ws  = (float*)d_ws;

  const size_t NB = (size_t)B_ * T_ * D_;
  float* qp   = ws;
  float* kp   = ws + 1*NB;
  float* vp   = ws + 2*NB;
  float* gvp  = ws + 3*NB;
  float* qc   = ws + 4*NB;
  float* kc   = ws + 5*NB;
  float* vc   = ws + 6*NB;
  float* mb   = ws + 7*NB;
  float* wbf  = ws + 8*NB;
  float* gb   = ws + 8*NB + 5*524288;
  float* bb   = gb + (size_t)B_*T_*H_;
  float* Gc   = bb + (size_t)B_*T_*H_;

  u16* h_bf  = (u16*)mb;
  u16* og_bf = (u16*)mb;
  u16* w_bf  = (u16*)wbf;
  u16* wq_bf = w_bf + 0*1048576;
  u16* wk_bf = w_bf + 1*1048576;
  u16* wv_bf = w_bf + 2*1048576;
  u16* wg_bf = w_bf + 3*1048576;
  u16* wo_bf = w_bf + 4*1048576;

  float* Ubuf = qp;
  float* Wbuf = kp;
  float* S0b  = vp;
  float* Mbuf = mb;
  float* Nbuf = vc;

  cvt_all<<<4608, 256, 0, stream>>>(h, Wq, Wk, Wv, Wg, Wo, h_bf, w_bf);

  gemm_bf16_4<<<dim3(32, 32), 256, 0, stream>>>(h_bf, wq_bf, wk_bf, wv_bf, wg_bf,
                                                 qp, kp, vp, gvp);
  smallproj<<<B_ * T_, 256, 0, stream>>>(h, Wa, Wb, Alog, dtb, gb, bb);

  convnorm<1><<<1024, 256, 0, stream>>>(qp, cqw, qnw, 0.125f, qc);
  convnorm<1><<<1024, 256, 0, stream>>>(kp, ckw, knw, 1.0f, kc);
  convnorm<0><<<1024, 256, 0, stream>>>(vp, cvw, qnw, 1.0f, vc);

  p1_chunk<<<B_*H_*NC_, 256, 0, stream>>>(kc, vc, gb, bb, Ubuf, Wbuf, Gc);
  p1b_mn<<<B_*H_*NC_, 256, 0, stream>>>(kc, Gc, Ubuf, Wbuf, Mbuf, Nbuf);
  pscanA<<<B_*H_*8, 256, 0, stream>>>(Mbuf, Nbuf);
  pscanB<<<B_*H_, 256, 0, stream>>>(Mbuf, Nbuf, S0b);
  pscanC<<<B_*H_*24, 256, 0, stream>>>(Mbuf, Nbuf, S0b);
  p3_out<<<B_*H_*NC_, 256, 0, stream>>>(qc, kc, Gc, S0b, Ubuf, Wbuf, out);

  ogate<<<B_*T_*D_/256, 256, 0, stream>>>(out, gvp, onw, og_bf);
  gemm_bf16_1<<<dim3(32, 8), 256, 0, stream>>>(og_bf, wo_bf, out);
}

// Round 9
// 296.230 us; speedup vs baseline: 13.6218x; 1.0598x over previous
//
#include <hip/hip_runtime.h>
#include <cstdint>
#include <cstddef>

#define B_ 2
#define T_ 2048
#define D_ 1024
#define H_ 16
#define HD_ 64
#define NC_ 32

typedef unsigned short u16;
typedef __attribute__((ext_vector_type(8))) short bf16x8;
typedef __attribute__((ext_vector_type(4))) float f32x4;

__device__ __forceinline__ float dot4(float4 a, float4 b, float acc) {
  return fmaf(a.x, b.x, fmaf(a.y, b.y, fmaf(a.z, b.z, fmaf(a.w, b.w, acc))));
}
__device__ __forceinline__ u16 f2bf(float f) {
  unsigned u = __float_as_uint(f);
  u += 0x7fffu + ((u >> 16) & 1u);
  return (u16)(u >> 16);
}
__device__ __forceinline__ float bf2f(u16 v) {
  return __uint_as_float(((unsigned)v) << 16);
}
__device__ __forceinline__ bf16x8 pack8(float4 a, float4 b) {
  union { u16 us[8]; bf16x8 v; } p;
  p.us[0] = f2bf(a.x); p.us[1] = f2bf(a.y); p.us[2] = f2bf(a.z); p.us[3] = f2bf(a.w);
  p.us[4] = f2bf(b.x); p.us[5] = f2bf(b.y); p.us[6] = f2bf(b.z); p.us[7] = f2bf(b.w);
  return p.v;
}
__device__ __forceinline__ void glds16(const u16* g, u16* l) {
  __builtin_amdgcn_global_load_lds(
      (const __attribute__((address_space(1))) void*)g,
      (__attribute__((address_space(3))) void*)l, 16, 0, 0);
}

// ---------------- fp32 -> bf16 conversion (h + 5 weights, one launch) ----------------
__global__ __launch_bounds__(256) void cvt_all(
    const float* __restrict__ h, const float* __restrict__ w0,
    const float* __restrict__ w1, const float* __restrict__ w2,
    const float* __restrict__ w3, const float* __restrict__ w4,
    u16* __restrict__ h_bf, u16* __restrict__ wb)
{
  const int blk = blockIdx.x;
  const float* src;
  u16* dst;
  int lb;
  if (blk < 2048) { src = h; dst = h_bf; lb = blk; }
  else {
    int k = (blk - 2048) >> 9, r = (blk - 2048) & 511;
    src = k == 0 ? w0 : k == 1 ? w1 : k == 2 ? w2 : k == 3 ? w3 : w4;
    dst = wb + (size_t)k * 1048576;
    lb = r;
  }
  int i = (lb * 256 + threadIdx.x) * 8;
  float4 v0 = *(const float4*)(src + i);
  float4 v1 = *(const float4*)(src + i + 4);
  union { u16 us[8]; uint4 u4; } p;
  p.us[0] = f2bf(v0.x); p.us[1] = f2bf(v0.y); p.us[2] = f2bf(v0.z); p.us[3] = f2bf(v0.w);
  p.us[4] = f2bf(v1.x); p.us[5] = f2bf(v1.y); p.us[6] = f2bf(v1.z); p.us[7] = f2bf(v1.w);
  *(uint4*)(dst + i) = p.u4;
}

// ---------------- bf16 MFMA GEMM core (global_load_lds + chunk-XOR swizzle) ----------------
// LDS row = 32 u16 (64B) = 4 chunks of 16B. Physical chunk = logical ^ ((row>>1)&3):
// staging pre-swizzles the GLOBAL source chunk (LDS dest stays linear, rule #21),
// reads apply the same XOR -> 2 lanes/slot = conflict-free (m136: 2-way is free).
__device__ __forceinline__ void gemm_core(const u16* __restrict__ A,
    const u16* __restrict__ Bw, float* __restrict__ C,
    u16* As, u16* Bs, int row0, int col0, int K, int N)
{
  const int tid = threadIdx.x;
  const int lane = tid & 63, wave = tid >> 6;
  const int wr = (wave >> 1) * 64, wc = (wave & 1) * 64;
  const int lr = lane & 15;
  const int lkp = (((lane >> 4) ^ ((lr >> 1) & 3))) * 8;   // swizzled read chunk
  const int rql = (lane >> 2);                              // staging row in 16-block
  const int cql = (((lane & 3) ^ ((rql >> 1) & 3))) * 8;    // swizzled source chunk
  const u16* gA0 = A + (size_t)(row0 + wave * 16 + rql) * K + cql;
  const u16* gA1 = A + (size_t)(row0 + (wave + 4) * 16 + rql) * K + cql;
  const u16* gB0 = Bw + (size_t)(col0 + wave * 16 + rql) * K + cql;
  const u16* gB1 = Bw + (size_t)(col0 + (wave + 4) * 16 + rql) * K + cql;
  u16* lA0 = As + wave * 16 * 32;
  u16* lA1 = As + (wave + 4) * 16 * 32;
  u16* lB0 = Bs + wave * 16 * 32;
  u16* lB1 = Bs + (wave + 4) * 16 * 32;

  f32x4 acc[4][4];
  #pragma unroll
  for (int i = 0; i < 4; ++i)
    #pragma unroll
    for (int j = 0; j < 4; ++j) acc[i][j] = f32x4{0.f, 0.f, 0.f, 0.f};

  const int KT = K >> 5;
  for (int kt = 0; kt < KT; ++kt) {
    glds16(gA0 + kt * 32, lA0);
    glds16(gA1 + kt * 32, lA1);
    glds16(gB0 + kt * 32, lB0);
    glds16(gB1 + kt * 32, lB1);
    __syncthreads();
    bf16x8 af[4], bf[4];
    #pragma unroll
    for (int i = 0; i < 4; ++i) af[i] = *(const bf16x8*)&As[(wr + i * 16 + lr) * 32 + lkp];
    #pragma unroll
    for (int j = 0; j < 4; ++j) bf[j] = *(const bf16x8*)&Bs[(wc + j * 16 + lr) * 32 + lkp];
    #pragma unroll
    for (int i = 0; i < 4; ++i)
      #pragma unroll
      for (int j = 0; j < 4; ++j)
        acc[i][j] = __builtin_amdgcn_mfma_f32_16x16x32_bf16(af[i], bf[j], acc[i][j], 0, 0, 0);
    __syncthreads();
  }
  const int orow = row0 + wr + (lane >> 4) * 4;
  const int ocol = col0 + wc + lr;
  #pragma unroll
  for (int i = 0; i < 4; ++i)
    #pragma unroll
    for (int j = 0; j < 4; ++j)
      #pragma unroll
      for (int r = 0; r < 4; ++r)
        C[(size_t)(orow + i * 16 + r) * N + ocol + j * 16] = acc[i][j][r];
}

__global__ __launch_bounds__(256) void gemm_bf16_4(const u16* __restrict__ A,
    const u16* __restrict__ W0, const u16* __restrict__ W1,
    const u16* __restrict__ W2, const u16* __restrict__ W3,
    float* __restrict__ C0, float* __restrict__ C1,
    float* __restrict__ C2, float* __restrict__ C3)
{
  __shared__ u16 As[128 * 32];
  __shared__ u16 Bs[128 * 32];
  const int sel = blockIdx.y >> 3;
  const u16* Bw = sel == 0 ? W0 : sel == 1 ? W1 : sel == 2 ? W2 : W3;
  float* C = sel == 0 ? C0 : sel == 1 ? C1 : sel == 2 ? C2 : C3;
  gemm_core(A, Bw, C, As, Bs, blockIdx.x * 128, (blockIdx.y & 7) * 128, 1024, 1024);
}

__global__ __launch_bounds__(256) void gemm_bf16_1(const u16* __restrict__ A,
    const u16* __restrict__ Bw, float* __restrict__ C)
{
  __shared__ u16 As[128 * 32];
  __shared__ u16 Bs[128 * 32];
  gemm_core(A, Bw, C, As, Bs, blockIdx.x * 128, blockIdx.y * 128, 1024, 1024);
}

// ---------------- beta / g small projections ----------------
__global__ __launch_bounds__(256) void smallproj(const float* __restrict__ Hs,
    const float* __restrict__ Wa, const float* __restrict__ Wb,
    const float* __restrict__ Alog, const float* __restrict__ dtb,
    float* __restrict__ Gout, float* __restrict__ Bout)
{
  __shared__ float hs[D_];
  const int bt = blockIdx.x;
  for (int i = threadIdx.x; i < D_; i += 256) hs[i] = Hs[(size_t)bt * D_ + i];
  __syncthreads();
  const int grp = threadIdx.x >> 3, p = threadIdx.x & 7;
  const int head = grp & 15, which = grp >> 4;
  const float* Wr = (which ? Wb : Wa) + head * D_;
  float s = 0.f;
  for (int i = p; i < D_; i += 8) s = fmaf(hs[i], Wr[i], s);
  s += __shfl_xor(s, 1); s += __shfl_xor(s, 2); s += __shfl_xor(s, 4);
  if (p == 0) {
    if (which) {
      Bout[(size_t)bt * H_ + head] = 1.f / (1.f + __expf(-s));
    } else {
      float x = s + dtb[head];
      float sp = fmaxf(x, 0.f) + log1pf(__expf(-fabsf(x)));
      Gout[(size_t)bt * H_ + head] = -__expf(Alog[head]) * sp;
    }
  }
}

// ---------------- fused causal conv(K=4)+SiLU [+ RMSNorm+L2norm], q/k/v in one grid ----------------
__global__ __launch_bounds__(256) void convnorm3(
    const float* __restrict__ Xq, const float* __restrict__ Xk, const float* __restrict__ Xv,
    const float* __restrict__ Wq, const float* __restrict__ Wk, const float* __restrict__ Wv,
    const float* __restrict__ qnw, const float* __restrict__ knw,
    float* __restrict__ Yq, float* __restrict__ Yk, float* __restrict__ Yv)
{
  __shared__ float Xs[67][65];
  __shared__ float nwS[64];
  const int which = blockIdx.x >> 10;       // 0=q, 1=k, 2=v
  const int blk = blockIdx.x & 1023;
  const int tt = blk & 31, hh = (blk >> 5) & 15, b = blk >> 9;
  const int t0 = tt * 64;
  const int d = threadIdx.x & 63, tq = threadIdx.x >> 6;
  const float* X = which == 0 ? Xq : which == 1 ? Xk : Xv;
  const float* W = which == 0 ? Wq : which == 1 ? Wk : Wv;
  float* Y = which == 0 ? Yq : which == 1 ? Yk : Yv;
  const int NORM = (which < 2);
  const float fs = (which == 0) ? 0.125f : 1.0f;
  for (int e = threadIdx.x; e < 67 * 64; e += 256) {
    int r = e >> 6, dd = e & 63;
    int t = t0 - 3 + r;
    Xs[r][dd] = (t >= 0) ? X[((size_t)b * T_ + t) * D_ + hh * 64 + dd] : 0.f;
  }
  if (NORM && threadIdx.x < 64) nwS[threadIdx.x] = (which == 0 ? qnw : knw)[threadIdx.x];
  __syncthreads();
  const float4 w = *(const float4*)(W + (hh * 64 + d) * 4);
  #pragma unroll 4
  for (int it = 0; it < 16; ++it) {
    const int lt = tq * 16 + it;
    float a = fmaf(w.x, Xs[lt][d], fmaf(w.y, Xs[lt + 1][d],
              fmaf(w.z, Xs[lt + 2][d], w.w * Xs[lt + 3][d])));
    float y = a / (1.f + __expf(-a));
    if (NORM) {
      float ss = y * y;
      #pragma unroll
      for (int m = 1; m < 64; m <<= 1) ss += __shfl_xor(ss, m);
      float z = y * rsqrtf(ss * (1.f / 64.f) + 1e-6f) * nwS[d];
      float s2 = z * z;
      #pragma unroll
      for (int m = 1; m < 64; m <<= 1) s2 += __shfl_xor(s2, m);
      y = z * rsqrtf(s2 + 1e-6f) * fs;
    }
    Y[((size_t)b * T_ + t0 + lt) * D_ + hh * 64 + d] = y;
  }
}

// ---------------- P1: MFMA A = scale(K K^T), blocked MFMA solve -> U, W ----------------
__global__ __launch_bounds__(256) void p1_chunk(
    const float* __restrict__ Kc, const float* __restrict__ Vc,
    const float* __restrict__ Gg, const float* __restrict__ Bb,
    float* __restrict__ Ubuf, float* __restrict__ Wbuf, float* __restrict__ Gcum)
{
  __shared__ u16 Kbf[64][72];
  __shared__ float Am[64][68];
  __shared__ float XT[128][68];   // XT[col][t]; cols 0..63 U-rhs, 64..127 W-rhs
  __shared__ float gc[64], bet[64];
  const int bhc = blockIdx.x;
  const int bh = bhc >> 5, c = bhc & 31;
  const int b = bh >> 4, h = bh & 15;
  const int tid = threadIdx.x;
  const int lane = tid & 63, wave = tid >> 6;
  const int lr = lane & 15, lkq = lane >> 4;
  const size_t rowbase = ((size_t)b*T_ + c*64)*H_ + h;

  if (tid < 64) {
    float gv = Gg[rowbase + (size_t)tid*H_];
    #pragma unroll
    for (int off = 1; off < 64; off <<= 1) {
      float up = __shfl_up(gv, off, 64);
      if (tid >= off) gv += up;
    }
    gc[tid] = gv;
    Gcum[(size_t)bhc*64 + tid] = gv;
    bet[tid] = Bb[rowbase + (size_t)tid*H_];
  }
  // stage K -> bf16 LDS
  for (int e4 = tid; e4 < 1024; e4 += 256) {
    int t = e4 >> 4, d4 = (e4 & 15) * 4;
    float4 v = *(const float4*)&Kc[(rowbase + (size_t)t*H_)*64 + d4];
    u16 tmp[4] = {f2bf(v.x), f2bf(v.y), f2bf(v.z), f2bf(v.w)};
    *(uint2*)&Kbf[t][d4] = *(uint2*)tmp;
  }
  __syncthreads();

  // A-phase: wave w computes t-strip [16w,16w+16) x all s
  {
    bf16x8 afA[2];
    #pragma unroll
    for (int ks = 0; ks < 2; ++ks)
      afA[ks] = *(const bf16x8*)&Kbf[16*wave + lr][ks*32 + lkq*8];
    #pragma unroll
    for (int j = 0; j < 4; ++j) {
      f32x4 accA = f32x4{0.f, 0.f, 0.f, 0.f};
      #pragma unroll
      for (int ks = 0; ks < 2; ++ks) {
        bf16x8 bfr = *(const bf16x8*)&Kbf[16*j + lr][ks*32 + lkq*8];
        accA = __builtin_amdgcn_mfma_f32_16x16x32_bf16(afA[ks], bfr, accA, 0, 0, 0);
      }
      const int s = 16*j + lr;
      #pragma unroll
      for (int r = 0; r < 4; ++r) {
        int t = 16*wave + lkq*4 + r;
        Am[t][s] = (s < t) ? bet[t] * __expf(gc[t] - gc[s]) * accA[r] : 0.f;
      }
    }
  }
  // RHS fill
  for (int e4 = tid; e4 < 1024; e4 += 256) {
    int t = e4 >> 4, j4 = (e4 & 15) * 4;
    float bt = bet[t];
    float ek = bt * __expf(gc[t]);
    float4 vv = *(const float4*)&Vc[(rowbase + (size_t)t*H_)*64 + j4];
    XT[j4+0][t] = bt * vv.x; XT[j4+1][t] = bt * vv.y;
    XT[j4+2][t] = bt * vv.z; XT[j4+3][t] = bt * vv.w;
    XT[64+j4+0][t] = ek * bf2f(Kbf[t][j4+0]);
    XT[64+j4+1][t] = ek * bf2f(Kbf[t][j4+1]);
    XT[64+j4+2][t] = ek * bf2f(Kbf[t][j4+2]);
    XT[64+j4+3][t] = ek * bf2f(Kbf[t][j4+3]);
  }
  __syncthreads();

  // blocked forward substitution: 4 stages of 16 rows
  for (int st = 0; st < 4; ++st) {
    if (st > 0) {
      const int nks = (st == 3) ? 2 : 1;
      f32x4 accU0 = f32x4{0.f,0.f,0.f,0.f}, accU1 = f32x4{0.f,0.f,0.f,0.f};
      for (int ks = 0; ks < nks; ++ks) {
        const int m0 = ks*32 + lkq*8;
        bf16x8 af;
        if (m0 + 8 <= 16*st) {
          float4 a0 = *(const float4*)&Am[16*st + lr][m0];
          float4 a1 = *(const float4*)&Am[16*st + lr][m0 + 4];
          af = pack8(a0, a1);
        } else {
          af = bf16x8{0,0,0,0,0,0,0,0};
        }
        {
          const int cb = (wave*2 + 0) * 16;
          float4 b0 = *(const float4*)&XT[cb + lr][m0];
          float4 b1 = *(const float4*)&XT[cb + lr][m0 + 4];
          accU0 = __builtin_amdgcn_mfma_f32_16x16x32_bf16(af, pack8(b0, b1), accU0, 0, 0, 0);
        }
        {
          const int cb = (wave*2 + 1) * 16;
          float4 b0 = *(const float4*)&XT[cb + lr][m0];
          float4 b1 = *(const float4*)&XT[cb + lr][m0 + 4];
          accU1 = __builtin_amdgcn_mfma_f32_16x16x32_bf16(af, pack8(b0, b1), accU1, 0, 0, 0);
        }
      }
      #pragma unroll
      for (int r = 0; r < 4; ++r) {
        const int t = 16*st + lkq*4 + r;
        XT[(wave*2+0)*16 + lr][t] -= accU0[r];
        XT[(wave*2+1)*16 + lr][t] -= accU1[r];
      }
      __syncthreads();
    }
    if (tid < 128) {
      const int bs = 16*st;
      float x[16];
      #pragma unroll
      for (int q = 0; q < 4; ++q)
        *(float4*)&x[q*4] = *(const float4*)&XT[tid][bs + q*4];
      #pragma unroll
      for (int tau = 1; tau < 16; ++tau) {
        float a = 0.f, a2 = 0.f;
        #pragma unroll
        for (int m = 0; m < tau; m += 2) {
          a = fmaf(Am[bs+tau][bs+m], x[m], a);
          if (m + 1 < tau) a2 = fmaf(Am[bs+tau][bs+m+1], x[m+1], a2);
        }
        x[tau] -= (a + a2);
      }
      #pragma unroll
      for (int q = 0; q < 4; ++q)
        *(float4*)&XT[tid][bs + q*4] = *(const float4*)&x[q*4];
    }
    __syncthreads();
  }

  for (int e = tid; e < 4096; e += 256) {
    int t = e >> 6, j = e & 63;
    Ubuf[(size_t)bhc*4096 + e] = XT[j][t];
    Wbuf[(size_t)bhc*4096 + e] = XT[64+j][t];
  }
}

// ---------------- P1b (MFMA): M = bC*I - Ksc^T W, N = Ksc^T U ----------------
__global__ __launch_bounds__(256) void p1b_mn(
    const float* __restrict__ Kc, const float* __restrict__ Gcum,
    const float* __restrict__ Ubuf, const float* __restrict__ Wbuf,
    float* __restrict__ Mbuf, float* __restrict__ Nbuf)
{
  __shared__ u16 KscT[64][72];   // [a][t] = e^{gC-gc_t} K[t][a]
  __shared__ u16 WT[64][72];     // [c][t] = W[t][c]
  __shared__ u16 UT[64][72];     // [c][t] = U[t][c]
  __shared__ float gcs[64];
  const int bhc = blockIdx.x;
  const int bh = bhc >> 5, c = bhc & 31;
  const int b = bh >> 4, h = bh & 15;
  const int tid = threadIdx.x;
  const int lane = tid & 63, wave = tid >> 6;
  const int lr = lane & 15, lkq = lane >> 4;
  const size_t rowbase = ((size_t)b*T_ + c*64)*H_ + h;
  if (tid < 64) gcs[tid] = Gcum[(size_t)bhc*64 + tid];
  __syncthreads();
  const float gC = gcs[63];
  for (int e4 = tid; e4 < 1024; e4 += 256) {
    int t = e4 >> 4, a4 = (e4 & 15) * 4;
    float sc = __expf(gC - gcs[t]);
    float4 kv = *(const float4*)&Kc[(rowbase + (size_t)t*H_)*64 + a4];
    KscT[a4+0][t] = f2bf(sc*kv.x); KscT[a4+1][t] = f2bf(sc*kv.y);
    KscT[a4+2][t] = f2bf(sc*kv.z); KscT[a4+3][t] = f2bf(sc*kv.w);
    float4 wv = *(const float4*)&Wbuf[(size_t)bhc*4096 + (size_t)t*64 + a4];
    WT[a4+0][t] = f2bf(wv.x); WT[a4+1][t] = f2bf(wv.y);
    WT[a4+2][t] = f2bf(wv.z); WT[a4+3][t] = f2bf(wv.w);
    float4 uv = *(const float4*)&Ubuf[(size_t)bhc*4096 + (size_t)t*64 + a4];
    UT[a4+0][t] = f2bf(uv.x); UT[a4+1][t] = f2bf(uv.y);
    UT[a4+2][t] = f2bf(uv.z); UT[a4+3][t] = f2bf(uv.w);
  }
  __syncthreads();

  bf16x8 af[2];
  #pragma unroll
  for (int ks = 0; ks < 2; ++ks)
    af[ks] = *(const bf16x8*)&KscT[16*wave + lr][ks*32 + lkq*8];
  const float bC = __expf(gC);
  const size_t ob = (size_t)bhc * 4096;
  #pragma unroll
  for (int j = 0; j < 4; ++j) {
    f32x4 aM = f32x4{0.f,0.f,0.f,0.f}, aN = f32x4{0.f,0.f,0.f,0.f};
    #pragma unroll
    for (int ks = 0; ks < 2; ++ks) {
      bf16x8 bw = *(const bf16x8*)&WT[16*j + lr][ks*32 + lkq*8];
      bf16x8 bu = *(const bf16x8*)&UT[16*j + lr][ks*32 + lkq*8];
      aM = __builtin_amdgcn_mfma_f32_16x16x32_bf16(af[ks], bw, aM, 0, 0, 0);
      aN = __builtin_amdgcn_mfma_f32_16x16x32_bf16(af[ks], bu, aN, 0, 0, 0);
    }
    const int cc = 16*j + lr;
    #pragma unroll
    for (int r = 0; r < 4; ++r) {
      const int a = 16*wave + lkq*4 + r;
      Mbuf[ob + (size_t)a*64 + cc] = (a == cc ? bC : 0.f) - aM[r];
      Nbuf[ob + (size_t)a*64 + cc] = aN[r];
    }
  }
}

// ---------------- pscanA: in-place group-of-4 prefix composition ----------------
__global__ __launch_bounds__(256) void pscanA(float* __restrict__ Mbuf,
    float* __restrict__ Nbuf)
{
  __shared__ float OM[2][64][68];
  __shared__ float ON[2][64][68];
  __shared__ float NM[2][64][68];
  const int blk = blockIdx.x;            // 32 bh * 8 groups
  const int bh = blk >> 3, g = blk & 7;
  const size_t s0 = ((size_t)bh * 32 + g * 4) * 4096;
  const int tid = threadIdx.x;
  const int p0 = (tid >> 4) * 4;
  const int q0 = (tid & 15) * 4;
  for (int e4 = tid; e4 < 1024; e4 += 256) {
    int r = e4 >> 4, c4 = (e4 & 15) * 4;
    *(float4*)&OM[0][r][c4] = *(const float4*)&Mbuf[s0 + (size_t)r*64 + c4];
    *(float4*)&ON[0][r][c4] = *(const float4*)&Nbuf[s0 + (size_t)r*64 + c4];
    *(float4*)&NM[0][r][c4] = *(const float4*)&Mbuf[s0 + 4096 + (size_t)r*64 + c4];
  }
  __syncthreads();
  for (int s = 0; s < 3; ++s) {
    const int cur = s & 1, nxt = cur ^ 1;
    const size_t wslot = s0 + (size_t)(s + 1) * 4096;
    if (s < 2) {
      for (int e4 = tid; e4 < 1024; e4 += 256) {
        int r = e4 >> 4, c4 = (e4 & 15) * 4;
        *(float4*)&NM[nxt][r][c4] = *(const float4*)&Mbuf[wslot + 4096 + (size_t)r*64 + c4];
      }
    }
    float aM[4][4], aN[4][4];
    #pragma unroll
    for (int r = 0; r < 4; ++r) {
      float4 nv = *(const float4*)&Nbuf[wslot + (size_t)(p0+r)*64 + q0];
      aM[r][0]=0.f; aM[r][1]=0.f; aM[r][2]=0.f; aM[r][3]=0.f;
      aN[r][0]=nv.x; aN[r][1]=nv.y; aN[r][2]=nv.z; aN[r][3]=nv.w;
    }
    for (int m4 = 0; m4 < 64; m4 += 4) {
      float xv[4][4];
      #pragma unroll
      for (int r = 0; r < 4; ++r) {
        float4 v = *(const float4*)&NM[cur][p0+r][m4];
        xv[r][0]=v.x; xv[r][1]=v.y; xv[r][2]=v.z; xv[r][3]=v.w;
      }
      #pragma unroll
      for (int mm = 0; mm < 4; ++mm) {
        float4 ym = *(const float4*)&OM[cur][m4+mm][q0];
        float4 yn = *(const float4*)&ON[cur][m4+mm][q0];
        #pragma unroll
        for (int r = 0; r < 4; ++r) {
          aM[r][0] = fmaf(xv[r][mm], ym.x, aM[r][0]);
          aM[r][1] = fmaf(xv[r][mm], ym.y, aM[r][1]);
          aM[r][2] = fmaf(xv[r][mm], ym.z, aM[r][2]);
          aM[r][3] = fmaf(xv[r][mm], ym.w, aM[r][3]);
          aN[r][0] = fmaf(xv[r][mm], yn.x, aN[r][0]);
          aN[r][1] = fmaf(xv[r][mm], yn.y, aN[r][1]);
          aN[r][2] = fmaf(xv[r][mm], yn.z, aN[r][2]);
          aN[r][3] = fmaf(xv[r][mm], yn.w, aN[r][3]);
        }
      }
    }
    #pragma unroll
    for (int r = 0; r < 4; ++r) {
      float4 vm = {aM[r][0], aM[r][1], aM[r][2], aM[r][3]};
      float4 vn = {aN[r][0], aN[r][1], aN[r][2], aN[r][3]};
      *(float4*)&Mbuf[wslot + (size_t)(p0+r)*64 + q0] = vm;
      *(float4*)&Nbuf[wslot + (size_t)(p0+r)*64 + q0] = vn;
      *(float4*)&OM[nxt][p0+r][q0] = vm;
      *(float4*)&ON[nxt][p0+r][q0] = vn;
    }
    __syncthreads();
  }
}

// ---------------- pscanB: serial carry over 8 group totals (ST-form) ----------------
__global__ __launch_bounds__(256) void pscanB(const float* __restrict__ Mbuf,
    const float* __restrict__ Nbuf, float* __restrict__ S0b)
{
  __shared__ float ST[2][64][68];
  __shared__ float MT[64][68];
  const int bh = blockIdx.x;
  const size_t base = (size_t)bh * 32 * 4096;
  const int tid = threadIdx.x;
  const int j0 = (tid >> 4) * 4, a0 = tid & 15;
  for (int e4 = tid; e4 < 1024; e4 += 256) {
    int r = e4 >> 4, c4 = (e4 & 15) * 4;
    *(float4*)&ST[0][r][c4] = float4{0.f, 0.f, 0.f, 0.f};
    *(float4*)&S0b[base + (size_t)r*64 + c4] = float4{0.f, 0.f, 0.f, 0.f};
  }
  for (int g = 0; g < 7; ++g) {
    const int cur = g & 1, nxt = cur ^ 1;
    const size_t tslot = base + (size_t)(4*g + 3) * 4096;
    for (int e4 = tid; e4 < 1024; e4 += 256) {
      int r = e4 >> 4, c4 = (e4 & 15) * 4;
      *(float4*)&MT[r][c4] = *(const float4*)&Mbuf[tslot + (size_t)r*64 + c4];
    }
    float acc[4][4];
    #pragma unroll
    for (int r = 0; r < 4; ++r)
      #pragma unroll
      for (int s = 0; s < 4; ++s)
        acc[r][s] = Nbuf[tslot + (size_t)(a0 + 16*s)*64 + j0 + r];
    __syncthreads();
    for (int k4 = 0; k4 < 64; k4 += 4) {
      float4 xr[4];
      #pragma unroll
      for (int r = 0; r < 4; ++r) xr[r] = *(const float4*)&ST[cur][j0+r][k4];
      #pragma unroll
      for (int s = 0; s < 4; ++s) {
        float4 yv = *(const float4*)&MT[a0 + 16*s][k4];
        #pragma unroll
        for (int r = 0; r < 4; ++r) acc[r][s] = dot4(xr[r], yv, acc[r][s]);
      }
    }
    const size_t oslot = base + (size_t)(4*(g+1)) * 4096;
    #pragma unroll
    for (int r = 0; r < 4; ++r)
      #pragma unroll
      for (int s = 0; s < 4; ++s) {
        ST[nxt][j0+r][a0 + 16*s] = acc[r][s];
        S0b[oslot + (size_t)(j0+r)*64 + a0 + 16*s] = acc[r][s];
      }
    __syncthreads();
  }
}

// ---------------- pscanC: intra-group states (parallel) ----------------
__global__ __launch_bounds__(256) void pscanC(const float* __restrict__ Mbuf,
    const float* __restrict__ Nbuf, float* __restrict__ S0b)
{
  __shared__ float ST[64][68];
  __shared__ float MT[64][68];
  const int blk = blockIdx.x;            // 32 bh * 8 groups * 3
  const int bh = blk / 24, rem = blk % 24;
  const int g = rem / 3, i = rem % 3 + 1;
  const size_t base = (size_t)bh * 32 * 4096;
  const size_t pslot = base + (size_t)(4*g + i - 1) * 4096;
  const int tid = threadIdx.x;
  const int j0 = (tid >> 4) * 4, a0 = tid & 15;
  for (int e4 = tid; e4 < 1024; e4 += 256) {
    int r = e4 >> 4, c4 = (e4 & 15) * 4;
    *(float4*)&ST[r][c4] = *(const float4*)&S0b[base + (size_t)(4*g)*4096 + (size_t)r*64 + c4];
    *(float4*)&MT[r][c4] = *(const float4*)&Mbuf[pslot + (size_t)r*64 + c4];
  }
  float acc[4][4];
  #pragma unroll
  for (int r = 0; r < 4; ++r)
    #pragma unroll
    for (int s = 0; s < 4; ++s)
      acc[r][s] = Nbuf[pslot + (size_t)(a0 + 16*s)*64 + j0 + r];
  __syncthreads();
  for (int k4 = 0; k4 < 64; k4 += 4) {
    float4 xr[4];
    #pragma unroll
    for (int r = 0; r < 4; ++r) xr[r] = *(const float4*)&ST[j0+r][k4];
    #pragma unroll
    for (int s = 0; s < 4; ++s) {
      float4 yv = *(const float4*)&MT[a0 + 16*s][k4];
      #pragma unroll
      for (int r = 0; r < 4; ++r) acc[r][s] = dot4(xr[r], yv, acc[r][s]);
    }
  }
  const size_t oslot = base + (size_t)(4*g + i) * 4096;
  #pragma unroll
  for (int r = 0; r < 4; ++r)
    #pragma unroll
    for (int s = 0; s < 4; ++s)
      S0b[oslot + (size_t)(j0+r)*64 + a0 + 16*s] = acc[r][s];
}

// ---------------- P3 (MFMA): delta + outputs ----------------
// O = e^{gc} Q@S0 + tril(decay o QK^T) @ (U - W@S0)
__global__ __launch_bounds__(256) void p3_out(
    const float* __restrict__ Qc, const float* __restrict__ Kc,
    const float* __restrict__ Gcum, const float* __restrict__ S0b,
    const float* __restrict__ Ubuf, const float* __restrict__ Wbuf,
    float* __restrict__ O)
{
  __shared__ u16 Qbf[64][72];
  __shared__ u16 Kbf[64][72];
  __shared__ u16 S0T[64][72];    // [j][i] (S0b layout)
  __shared__ u16 Wbf[64][72];
  __shared__ u16 Pbf[64][72];    // [t][s]
  __shared__ u16 DsT[64][72];    // [j][s]
  __shared__ float gcs[64];
  const int bhc = blockIdx.x;
  const int bh = bhc >> 5, c = bhc & 31;
  const int b = bh >> 4, h = bh & 15;
  const int tid = threadIdx.x;
  const int lane = tid & 63, wave = tid >> 6;
  const int lr = lane & 15, lkq = lane >> 4;
  const size_t rowbase = ((size_t)b*T_ + c*64)*H_ + h;
  if (tid < 64) gcs[tid] = Gcum[(size_t)bhc*64 + tid];
  for (int e4 = tid; e4 < 1024; e4 += 256) {
    int t = e4 >> 4, d4 = (e4 & 15) * 4;
    size_t ga = (rowbase + (size_t)t*H_)*64 + d4;
    float4 qv = *(const float4*)&Qc[ga];
    float4 kv = *(const float4*)&Kc[ga];
    float4 sv = *(const float4*)&S0b[(size_t)bhc*4096 + (size_t)t*64 + d4];
    float4 wv = *(const float4*)&Wbuf[(size_t)bhc*4096 + (size_t)t*64 + d4];
    u16 aq[4] = {f2bf(qv.x), f2bf(qv.y), f2bf(qv.z), f2bf(qv.w)};
    u16 ak[4] = {f2bf(kv.x), f2bf(kv.y), f2bf(kv.z), f2bf(kv.w)};
    u16 as[4] = {f2bf(sv.x), f2bf(sv.y), f2bf(sv.z), f2bf(sv.w)};
    u16 aw[4] = {f2bf(wv.x), f2bf(wv.y), f2bf(wv.z), f2bf(wv.w)};
    *(uint2*)&Qbf[t][d4] = *(uint2*)aq;
    *(uint2*)&Kbf[t][d4] = *(uint2*)ak;
    *(uint2*)&S0T[t][d4] = *(uint2*)as;
    *(uint2*)&Wbf[t][d4] = *(uint2*)aw;
  }
  __syncthreads();

  const int trow0 = 16*wave + lkq*4;
  bf16x8 aq[2], aw[2];
  #pragma unroll
  for (int ks = 0; ks < 2; ++ks) {
    aq[ks] = *(const bf16x8*)&Qbf[16*wave + lr][ks*32 + lkq*8];
    aw[ks] = *(const bf16x8*)&Wbf[16*wave + lr][ks*32 + lkq*8];
  }
  float gct[4], egt[4];
  #pragma unroll
  for (int r = 0; r < 4; ++r) { gct[r] = gcs[trow0 + r]; egt[r] = __expf(gct[r]); }

  // Phase B: P[t][s] = (s<=t) e^{gc_t-gc_s} q_t.k_s   (wave's t-strip)
  #pragma unroll
  for (int j = 0; j < 4; ++j) {
    f32x4 pa = f32x4{0.f,0.f,0.f,0.f};
    #pragma unroll
    for (int ks = 0; ks < 2; ++ks) {
      bf16x8 bk = *(const bf16x8*)&Kbf[16*j + lr][ks*32 + lkq*8];
      pa = __builtin_amdgcn_mfma_f32_16x16x32_bf16(aq[ks], bk, pa, 0, 0, 0);
    }
    const int s = 16*j + lr;
    const float gs = gcs[s];
    #pragma unroll
    for (int r = 0; r < 4; ++r) {
      const int t = trow0 + r;
      float val = (s <= t) ? __expf(gct[r] - gs) * pa[r] : 0.f;
      Pbf[t][s] = f2bf(val);
    }
  }

  // Phase D: delta[s][j] = U[s][j] - (W@S0)[s][j]  (wave's s-strip), store DsT[j][s]
  #pragma unroll
  for (int j = 0; j < 4; ++j) {
    f32x4 da = f32x4{0.f,0.f,0.f,0.f};
    #pragma unroll
    for (int ks = 0; ks < 2; ++ks) {
      bf16x8 bs = *(const bf16x8*)&S0T[16*j + lr][ks*32 + lkq*8];
      da = __builtin_amdgcn_mfma_f32_16x16x32_bf16(aw[ks], bs, da, 0, 0, 0);
    }
    const int jj = 16*j + lr;
    #pragma unroll
    for (int r = 0; r < 4; ++r) {
      const int s = trow0 + r;
      float dv = Ubuf[(size_t)bhc*4096 + (size_t)s*64 + jj] - da[r];
      DsT[jj][s] = f2bf(dv);
    }
  }

  // Phase A: oacc = e^{gc_t} * (Q @ S0)  (wave's t-strip)
  f32x4 oacc[4];
  #pragma unroll
  for (int j = 0; j < 4; ++j) {
    f32x4 oa = f32x4{0.f,0.f,0.f,0.f};
    #pragma unroll
    for (int ks = 0; ks < 2; ++ks) {
      bf16x8 bs = *(const bf16x8*)&S0T[16*j + lr][ks*32 + lkq*8];
      oa = __builtin_amdgcn_mfma_f32_16x16x32_bf16(aq[ks], bs, oa, 0, 0, 0);
    }
    #pragma unroll
    for (int r = 0; r < 4; ++r) oa[r] *= egt[r];
    oacc[j] = oa;
  }
  __syncthreads();   // DsT complete across waves (Pbf is wave-local)

  // Phase C: oacc += P @ delta
  bf16x8 ap[2];
  #pragma unroll
  for (int ks = 0; ks < 2; ++ks)
    ap[ks] = *(const bf16x8*)&Pbf[16*wave + lr][ks*32 + lkq*8];
  #pragma unroll
  for (int j = 0; j < 4; ++j) {
    #pragma unroll
    for (int ks = 0; ks < 2; ++ks) {
      bf16x8 bd = *(const bf16x8*)&DsT[16*j + lr][ks*32 + lkq*8];
      oacc[j] = __builtin_amdgcn_mfma_f32_16x16x32_bf16(ap[ks], bd, oacc[j], 0, 0, 0);
    }
  }
  #pragma unroll
  for (int j = 0; j < 4; ++j) {
    const int jj = 16*j + lr;
    #pragma unroll
    for (int r = 0; r < 4; ++r) {
      const int t = trow0 + r;
      O[(rowbase + (size_t)t*H_)*64 + jj] = oacc[j][r];
    }
  }
}

// ---------------- o-norm * swish(gv) -> bf16 ----------------
__global__ __launch_bounds__(256) void ogate(const float* __restrict__ O,
    const float* __restrict__ GV, const float* __restrict__ w,
    u16* __restrict__ OG)
{
  const size_t gid = (size_t)blockIdx.x * 256 + threadIdx.x;
  const size_t vec = gid >> 6;
  const int lane = threadIdx.x & 63;
  float x = O[vec * 64 + lane];
  float ss = x * x;
  #pragma unroll
  for (int m = 1; m < 64; m <<= 1) ss += __shfl_xor(ss, m);
  float y = x * rsqrtf(ss * (1.f/64.f) + 1e-6f) * w[lane];
  float gv = GV[vec * 64 + lane];
  OG[vec * 64 + lane] = f2bf(y * gv / (1.f + __expf(-gv)));
}

extern "C" void kernel_launch(void* const* d_in, const int* in_sizes, int n_in,
                              void* d_out, int out_size, void* d_ws, size_t ws_size,
                              hipStream_t stream) {
  const float* h    = (const float*)d_in[0];
  const float* Wq   = (const float*)d_in[1];
  const float* Wk   = (const float*)d_in[2];
  const float* Wv   = (const float*)d_in[3];
  const float* Wa   = (const float*)d_in[4];
  const float* Wb   = (const float*)d_in[5];
  const float* Wg   = (const float*)d_in[6];
  const float* Wo   = (const float*)d_in[7];
  const float* qnw  = (const float*)d_in[8];
  const float* knw  = (const float*)d_in[9];
  const float* onw  = (const float*)d_in[10];
  const float* Alog = (const float*)d_in[11];
  const float* dtb  = (const float*)d_in[12];
  const float* cqw  = (const float*)d_in[13];
  const float* ckw  = (const float*)d_in[14];
  const float* cvw  = (const float*)d_in[15];
  float* out = (float*)d_out;
  float* ws  = (float*)d_ws;

  const size_t NB = (size_t)B_ * T_ * D_;
  float* qp   = ws;
  float* kp   = ws + 1*NB;
  float* vp   = ws + 2*NB;
  float* gvp  = ws + 3*NB;
  float* qc   = ws + 4*NB;
  float* kc   = ws + 5*NB;
  float* vc   = ws + 6*NB;
  float* mb   = ws + 7*NB;
  float* wbf  = ws + 8*NB;
  float* gb   = ws + 8*NB + 5*524288;
  float* bb   = gb + (size_t)B_*T_*H_;
  float* Gc   = bb + (size_t)B_*T_*H_;

  u16* h_bf  = (u16*)mb;
  u16* og_bf = (u16*)mb;
  u16* w_bf  = (u16*)wbf;
  u16* wq_bf = w_bf + 0*1048576;
  u16* wk_bf = w_bf + 1*1048576;
  u16* wv_bf = w_bf + 2*1048576;
  u16* wg_bf = w_bf + 3*1048576;
  u16* wo_bf = w_bf + 4*1048576;

  float* Ubuf = qp;
  float* Wbuf = kp;
  float* S0b  = vp;
  float* Mbuf = mb;
  float* Nbuf = vc;

  cvt_all<<<4608, 256, 0, stream>>>(h, Wq, Wk, Wv, Wg, Wo, h_bf, w_bf);

  gemm_bf16_4<<<dim3(32, 32), 256, 0, stream>>>(h_bf, wq_bf, wk_bf, wv_bf, wg_bf,
                                                 qp, kp, vp, gvp);
  smallproj<<<B_ * T_, 256, 0, stream>>>(h, Wa, Wb, Alog, dtb, gb, bb);

  convnorm3<<<3072, 256, 0, stream>>>(qp, kp, vp, cqw, ckw, cvw, qnw, knw,
                                      qc, kc, vc);

  p1_chunk<<<B_*H_*NC_, 256, 0, stream>>>(kc, vc, gb, bb, Ubuf, Wbuf, Gc);
  p1b_mn<<<B_*H_*NC_, 256, 0, stream>>>(kc, Gc, Ubuf, Wbuf, Mbuf, Nbuf);
  pscanA<<<B_*H_*8, 256, 0, stream>>>(Mbuf, Nbuf);
  pscanB<<<B_*H_, 256, 0, stream>>>(Mbuf, Nbuf, S0b);
  pscanC<<<B_*H_*24, 256, 0, stream>>>(Mbuf, Nbuf, S0b);
  p3_out<<<B_*H_*NC_, 256, 0, stream>>>(qc, kc, Gc, S0b, Ubuf, Wbuf, out);

  ogate<<<B_*T_*D_/256, 256, 0, stream>>>(out, gvp, onw, og_bf);
  gemm_bf16_1<<<dim3(32, 8), 256, 0, stream>>>(og_bf, wo_bf, out);
}

// Round 10
// 281.354 us; speedup vs baseline: 14.3421x; 1.0529x over previous
//
#include <hip/hip_runtime.h>
#include <cstdint>
#include <cstddef>

#define B_ 2
#define T_ 2048
#define D_ 1024
#define H_ 16
#define HD_ 64
#define NC_ 32

typedef unsigned short u16;
typedef __attribute__((ext_vector_type(8))) short bf16x8;
typedef __attribute__((ext_vector_type(4))) float f32x4;

__device__ __forceinline__ float dot4(float4 a, float4 b, float acc) {
  return fmaf(a.x, b.x, fmaf(a.y, b.y, fmaf(a.z, b.z, fmaf(a.w, b.w, acc))));
}
__device__ __forceinline__ u16 f2bf(float f) {
  unsigned u = __float_as_uint(f);
  u += 0x7fffu + ((u >> 16) & 1u);
  return (u16)(u >> 16);
}
__device__ __forceinline__ float bf2f(u16 v) {
  return __uint_as_float(((unsigned)v) << 16);
}
__device__ __forceinline__ bf16x8 pack8(float4 a, float4 b) {
  union { u16 us[8]; bf16x8 v; } p;
  p.us[0] = f2bf(a.x); p.us[1] = f2bf(a.y); p.us[2] = f2bf(a.z); p.us[3] = f2bf(a.w);
  p.us[4] = f2bf(b.x); p.us[5] = f2bf(b.y); p.us[6] = f2bf(b.z); p.us[7] = f2bf(b.w);
  return p.v;
}
__device__ __forceinline__ void glds16(const u16* g, u16* l) {
  __builtin_amdgcn_global_load_lds(
      (const __attribute__((address_space(1))) void*)g,
      (__attribute__((address_space(3))) void*)l, 16, 0, 0);
}

// ---------------- fp32 -> bf16 conversion (h + 5 weights, one launch) ----------------
__global__ __launch_bounds__(256) void cvt_all(
    const float* __restrict__ h, const float* __restrict__ w0,
    const float* __restrict__ w1, const float* __restrict__ w2,
    const float* __restrict__ w3, const float* __restrict__ w4,
    u16* __restrict__ h_bf, u16* __restrict__ wb)
{
  const int blk = blockIdx.x;
  const float* src;
  u16* dst;
  int lb;
  if (blk < 2048) { src = h; dst = h_bf; lb = blk; }
  else {
    int k = (blk - 2048) >> 9, r = (blk - 2048) & 511;
    src = k == 0 ? w0 : k == 1 ? w1 : k == 2 ? w2 : k == 3 ? w3 : w4;
    dst = wb + (size_t)k * 1048576;
    lb = r;
  }
  int i = (lb * 256 + threadIdx.x) * 8;
  float4 v0 = *(const float4*)(src + i);
  float4 v1 = *(const float4*)(src + i + 4);
  union { u16 us[8]; uint4 u4; } p;
  p.us[0] = f2bf(v0.x); p.us[1] = f2bf(v0.y); p.us[2] = f2bf(v0.z); p.us[3] = f2bf(v0.w);
  p.us[4] = f2bf(v1.x); p.us[5] = f2bf(v1.y); p.us[6] = f2bf(v1.z); p.us[7] = f2bf(v1.w);
  *(uint4*)(dst + i) = p.u4;
}

// ---------------- bf16 MFMA GEMM core: 3-deep pipelined global_load_lds + chunk-XOR swizzle ----------------
// LDS row = 32 u16 (64B) = 4 chunks of 16B. Physical chunk = logical ^ ((row>>1)&3).
// Pipeline: STAGE(kt+2) -> vmcnt(8) -> barrier -> compute(kt) -> barrier.
// End barrier guards buffer reuse (STAGE of kt+2 overwrites kt-1's buffer).
__device__ __forceinline__ void gemm_core(const u16* __restrict__ A,
    const u16* __restrict__ Bw, float* __restrict__ C,
    u16* As, u16* Bs, int row0, int col0, int K, int N)
{
  const int tid = threadIdx.x;
  const int lane = tid & 63, wave = tid >> 6;
  const int wr = (wave >> 1) * 64, wc = (wave & 1) * 64;
  const int lr = lane & 15;
  const int lkp = (((lane >> 4) ^ ((lr >> 1) & 3))) * 8;   // swizzled read chunk
  const int rql = (lane >> 2);                              // staging row in 16-block
  const int cql = (((lane & 3) ^ ((rql >> 1) & 3))) * 8;    // swizzled source chunk
  const u16* gA0 = A + (size_t)(row0 + wave * 16 + rql) * K + cql;
  const u16* gA1 = A + (size_t)(row0 + (wave + 4) * 16 + rql) * K + cql;
  const u16* gB0 = Bw + (size_t)(col0 + wave * 16 + rql) * K + cql;
  const u16* gB1 = Bw + (size_t)(col0 + (wave + 4) * 16 + rql) * K + cql;

  f32x4 acc[4][4];
  #pragma unroll
  for (int i = 0; i < 4; ++i)
    #pragma unroll
    for (int j = 0; j < 4; ++j) acc[i][j] = f32x4{0.f, 0.f, 0.f, 0.f};

  auto STAGE = [&](int buf, int kt) {
    u16* ab = As + buf * 4096;
    u16* bb = Bs + buf * 4096;
    glds16(gA0 + kt * 32, ab + wave * 512);
    glds16(gA1 + kt * 32, ab + (wave + 4) * 512);
    glds16(gB0 + kt * 32, bb + wave * 512);
    glds16(gB1 + kt * 32, bb + (wave + 4) * 512);
  };

  const int KT = K >> 5;
  STAGE(0, 0);
  STAGE(1, 1);
  int cur = 0;
  for (int kt = 0; kt < KT; ++kt) {
    if (kt + 2 < KT) {
      STAGE(cur == 0 ? 2 : (cur == 1 ? 0 : 1), kt + 2);
      asm volatile("s_waitcnt vmcnt(8)" ::: "memory");
    } else if (kt + 1 < KT) {
      asm volatile("s_waitcnt vmcnt(4)" ::: "memory");
    } else {
      asm volatile("s_waitcnt vmcnt(0)" ::: "memory");
    }
    __builtin_amdgcn_s_barrier();
    __builtin_amdgcn_sched_barrier(0);
    const u16* Asc = As + cur * 4096;
    const u16* Bsc = Bs + cur * 4096;
    bf16x8 af[4], bf[4];
    #pragma unroll
    for (int i = 0; i < 4; ++i) af[i] = *(const bf16x8*)&Asc[(wr + i * 16 + lr) * 32 + lkp];
    #pragma unroll
    for (int j = 0; j < 4; ++j) bf[j] = *(const bf16x8*)&Bsc[(wc + j * 16 + lr) * 32 + lkp];
    #pragma unroll
    for (int i = 0; i < 4; ++i)
      #pragma unroll
      for (int j = 0; j < 4; ++j)
        acc[i][j] = __builtin_amdgcn_mfma_f32_16x16x32_bf16(af[i], bf[j], acc[i][j], 0, 0, 0);
    __builtin_amdgcn_sched_barrier(0);
    __builtin_amdgcn_s_barrier();
    cur = (cur == 2) ? 0 : cur + 1;
  }
  const int orow = row0 + wr + (lane >> 4) * 4;
  const int ocol = col0 + wc + lr;
  #pragma unroll
  for (int i = 0; i < 4; ++i)
    #pragma unroll
    for (int j = 0; j < 4; ++j)
      #pragma unroll
      for (int r = 0; r < 4; ++r)
        C[(size_t)(orow + i * 16 + r) * N + ocol + j * 16] = acc[i][j][r];
}

__global__ __launch_bounds__(256) void gemm_bf16_4(const u16* __restrict__ A,
    const u16* __restrict__ W0, const u16* __restrict__ W1,
    const u16* __restrict__ W2, const u16* __restrict__ W3,
    float* __restrict__ C0, float* __restrict__ C1,
    float* __restrict__ C2, float* __restrict__ C3)
{
  __shared__ u16 As[3 * 128 * 32];
  __shared__ u16 Bs[3 * 128 * 32];
  const int sel = blockIdx.y >> 3;
  const u16* Bw = sel == 0 ? W0 : sel == 1 ? W1 : sel == 2 ? W2 : W3;
  float* C = sel == 0 ? C0 : sel == 1 ? C1 : sel == 2 ? C2 : C3;
  gemm_core(A, Bw, C, As, Bs, blockIdx.x * 128, (blockIdx.y & 7) * 128, 1024, 1024);
}

__global__ __launch_bounds__(256) void gemm_bf16_1(const u16* __restrict__ A,
    const u16* __restrict__ Bw, float* __restrict__ C)
{
  __shared__ u16 As[3 * 128 * 32];
  __shared__ u16 Bs[3 * 128 * 32];
  gemm_core(A, Bw, C, As, Bs, blockIdx.x * 128, blockIdx.y * 128, 1024, 1024);
}

// ---------------- beta / g small projections ----------------
__global__ __launch_bounds__(256) void smallproj(const float* __restrict__ Hs,
    const float* __restrict__ Wa, const float* __restrict__ Wb,
    const float* __restrict__ Alog, const float* __restrict__ dtb,
    float* __restrict__ Gout, float* __restrict__ Bout)
{
  __shared__ float hs[D_];
  const int bt = blockIdx.x;
  for (int i = threadIdx.x; i < D_; i += 256) hs[i] = Hs[(size_t)bt * D_ + i];
  __syncthreads();
  const int grp = threadIdx.x >> 3, p = threadIdx.x & 7;
  const int head = grp & 15, which = grp >> 4;
  const float* Wr = (which ? Wb : Wa) + head * D_;
  float s = 0.f;
  for (int i = p; i < D_; i += 8) s = fmaf(hs[i], Wr[i], s);
  s += __shfl_xor(s, 1); s += __shfl_xor(s, 2); s += __shfl_xor(s, 4);
  if (p == 0) {
    if (which) {
      Bout[(size_t)bt * H_ + head] = 1.f / (1.f + __expf(-s));
    } else {
      float x = s + dtb[head];
      float sp = fmaxf(x, 0.f) + log1pf(__expf(-fabsf(x)));
      Gout[(size_t)bt * H_ + head] = -__expf(Alog[head]) * sp;
    }
  }
}

// ---------------- fused causal conv(K=4)+SiLU [+ RMSNorm+L2norm], q/k/v in one grid ----------------
__global__ __launch_bounds__(256) void convnorm3(
    const float* __restrict__ Xq, const float* __restrict__ Xk, const float* __restrict__ Xv,
    const float* __restrict__ Wq, const float* __restrict__ Wk, const float* __restrict__ Wv,
    const float* __restrict__ qnw, const float* __restrict__ knw,
    float* __restrict__ Yq, float* __restrict__ Yk, float* __restrict__ Yv)
{
  __shared__ float Xs[67][65];
  __shared__ float nwS[64];
  const int which = blockIdx.x >> 10;       // 0=q, 1=k, 2=v
  const int blk = blockIdx.x & 1023;
  const int tt = blk & 31, hh = (blk >> 5) & 15, b = blk >> 9;
  const int t0 = tt * 64;
  const int d = threadIdx.x & 63, tq = threadIdx.x >> 6;
  const float* X = which == 0 ? Xq : which == 1 ? Xk : Xv;
  const float* W = which == 0 ? Wq : which == 1 ? Wk : Wv;
  float* Y = which == 0 ? Yq : which == 1 ? Yk : Yv;
  const int NORM = (which < 2);
  const float fs = (which == 0) ? 0.125f : 1.0f;
  for (int e = threadIdx.x; e < 67 * 64; e += 256) {
    int r = e >> 6, dd = e & 63;
    int t = t0 - 3 + r;
    Xs[r][dd] = (t >= 0) ? X[((size_t)b * T_ + t) * D_ + hh * 64 + dd] : 0.f;
  }
  if (NORM && threadIdx.x < 64) nwS[threadIdx.x] = (which == 0 ? qnw : knw)[threadIdx.x];
  __syncthreads();
  const float4 w = *(const float4*)(W + (hh * 64 + d) * 4);
  #pragma unroll 4
  for (int it = 0; it < 16; ++it) {
    const int lt = tq * 16 + it;
    float a = fmaf(w.x, Xs[lt][d], fmaf(w.y, Xs[lt + 1][d],
              fmaf(w.z, Xs[lt + 2][d], w.w * Xs[lt + 3][d])));
    float y = a / (1.f + __expf(-a));
    if (NORM) {
      float ss = y * y;
      #pragma unroll
      for (int m = 1; m < 64; m <<= 1) ss += __shfl_xor(ss, m);
      float z = y * rsqrtf(ss * (1.f / 64.f) + 1e-6f) * nwS[d];
      float s2 = z * z;
      #pragma unroll
      for (int m = 1; m < 64; m <<= 1) s2 += __shfl_xor(s2, m);
      y = z * rsqrtf(s2 + 1e-6f) * fs;
    }
    Y[((size_t)b * T_ + t0 + lt) * D_ + hh * 64 + d] = y;
  }
}

// ---------------- P1: MFMA A = scale(K K^T), blocked MFMA solve -> U, W ----------------
__global__ __launch_bounds__(256) void p1_chunk(
    const float* __restrict__ Kc, const float* __restrict__ Vc,
    const float* __restrict__ Gg, const float* __restrict__ Bb,
    float* __restrict__ Ubuf, float* __restrict__ Wbuf, float* __restrict__ Gcum)
{
  __shared__ u16 Kbf[64][72];
  __shared__ float Am[64][68];
  __shared__ float XT[128][68];   // XT[col][t]; cols 0..63 U-rhs, 64..127 W-rhs
  __shared__ float gc[64], bet[64];
  const int bhc = blockIdx.x;
  const int bh = bhc >> 5, c = bhc & 31;
  const int b = bh >> 4, h = bh & 15;
  const int tid = threadIdx.x;
  const int lane = tid & 63, wave = tid >> 6;
  const int lr = lane & 15, lkq = lane >> 4;
  const size_t rowbase = ((size_t)b*T_ + c*64)*H_ + h;

  if (tid < 64) {
    float gv = Gg[rowbase + (size_t)tid*H_];
    #pragma unroll
    for (int off = 1; off < 64; off <<= 1) {
      float up = __shfl_up(gv, off, 64);
      if (tid >= off) gv += up;
    }
    gc[tid] = gv;
    Gcum[(size_t)bhc*64 + tid] = gv;
    bet[tid] = Bb[rowbase + (size_t)tid*H_];
  }
  for (int e4 = tid; e4 < 1024; e4 += 256) {
    int t = e4 >> 4, d4 = (e4 & 15) * 4;
    float4 v = *(const float4*)&Kc[(rowbase + (size_t)t*H_)*64 + d4];
    u16 tmp[4] = {f2bf(v.x), f2bf(v.y), f2bf(v.z), f2bf(v.w)};
    *(uint2*)&Kbf[t][d4] = *(uint2*)tmp;
  }
  __syncthreads();

  {
    bf16x8 afA[2];
    #pragma unroll
    for (int ks = 0; ks < 2; ++ks)
      afA[ks] = *(const bf16x8*)&Kbf[16*wave + lr][ks*32 + lkq*8];
    #pragma unroll
    for (int j = 0; j < 4; ++j) {
      f32x4 accA = f32x4{0.f, 0.f, 0.f, 0.f};
      #pragma unroll
      for (int ks = 0; ks < 2; ++ks) {
        bf16x8 bfr = *(const bf16x8*)&Kbf[16*j + lr][ks*32 + lkq*8];
        accA = __builtin_amdgcn_mfma_f32_16x16x32_bf16(afA[ks], bfr, accA, 0, 0, 0);
      }
      const int s = 16*j + lr;
      #pragma unroll
      for (int r = 0; r < 4; ++r) {
        int t = 16*wave + lkq*4 + r;
        Am[t][s] = (s < t) ? bet[t] * __expf(gc[t] - gc[s]) * accA[r] : 0.f;
      }
    }
  }
  for (int e4 = tid; e4 < 1024; e4 += 256) {
    int t = e4 >> 4, j4 = (e4 & 15) * 4;
    float bt = bet[t];
    float ek = bt * __expf(gc[t]);
    float4 vv = *(const float4*)&Vc[(rowbase + (size_t)t*H_)*64 + j4];
    XT[j4+0][t] = bt * vv.x; XT[j4+1][t] = bt * vv.y;
    XT[j4+2][t] = bt * vv.z; XT[j4+3][t] = bt * vv.w;
    XT[64+j4+0][t] = ek * bf2f(Kbf[t][j4+0]);
    XT[64+j4+1][t] = ek * bf2f(Kbf[t][j4+1]);
    XT[64+j4+2][t] = ek * bf2f(Kbf[t][j4+2]);
    XT[64+j4+3][t] = ek * bf2f(Kbf[t][j4+3]);
  }
  __syncthreads();

  for (int st = 0; st < 4; ++st) {
    if (st > 0) {
      const int nks = (st == 3) ? 2 : 1;
      f32x4 accU0 = f32x4{0.f,0.f,0.f,0.f}, accU1 = f32x4{0.f,0.f,0.f,0.f};
      for (int ks = 0; ks < nks; ++ks) {
        const int m0 = ks*32 + lkq*8;
        bf16x8 af;
        if (m0 + 8 <= 16*st) {
          float4 a0 = *(const float4*)&Am[16*st + lr][m0];
          float4 a1 = *(const float4*)&Am[16*st + lr][m0 + 4];
          af = pack8(a0, a1);
        } else {
          af = bf16x8{0,0,0,0,0,0,0,0};
        }
        {
          const int cb = (wave*2 + 0) * 16;
          float4 b0 = *(const float4*)&XT[cb + lr][m0];
          float4 b1 = *(const float4*)&XT[cb + lr][m0 + 4];
          accU0 = __builtin_amdgcn_mfma_f32_16x16x32_bf16(af, pack8(b0, b1), accU0, 0, 0, 0);
        }
        {
          const int cb = (wave*2 + 1) * 16;
          float4 b0 = *(const float4*)&XT[cb + lr][m0];
          float4 b1 = *(const float4*)&XT[cb + lr][m0 + 4];
          accU1 = __builtin_amdgcn_mfma_f32_16x16x32_bf16(af, pack8(b0, b1), accU1, 0, 0, 0);
        }
      }
      #pragma unroll
      for (int r = 0; r < 4; ++r) {
        const int t = 16*st + lkq*4 + r;
        XT[(wave*2+0)*16 + lr][t] -= accU0[r];
        XT[(wave*2+1)*16 + lr][t] -= accU1[r];
      }
      __syncthreads();
    }
    if (tid < 128) {
      const int bs = 16*st;
      float x[16];
      #pragma unroll
      for (int q = 0; q < 4; ++q)
        *(float4*)&x[q*4] = *(const float4*)&XT[tid][bs + q*4];
      #pragma unroll
      for (int tau = 1; tau < 16; ++tau) {
        float a = 0.f, a2 = 0.f;
        #pragma unroll
        for (int m = 0; m < tau; m += 2) {
          a = fmaf(Am[bs+tau][bs+m], x[m], a);
          if (m + 1 < tau) a2 = fmaf(Am[bs+tau][bs+m+1], x[m+1], a2);
        }
        x[tau] -= (a + a2);
      }
      #pragma unroll
      for (int q = 0; q < 4; ++q)
        *(float4*)&XT[tid][bs + q*4] = *(const float4*)&x[q*4];
    }
    __syncthreads();
  }

  for (int e = tid; e < 4096; e += 256) {
    int t = e >> 6, j = e & 63;
    Ubuf[(size_t)bhc*4096 + e] = XT[j][t];
    Wbuf[(size_t)bhc*4096 + e] = XT[64+j][t];
  }
}

// ---------------- P1b (MFMA): M = bC*I - Ksc^T W, N = Ksc^T U ----------------
__global__ __launch_bounds__(256) void p1b_mn(
    const float* __restrict__ Kc, const float* __restrict__ Gcum,
    const float* __restrict__ Ubuf, const float* __restrict__ Wbuf,
    float* __restrict__ Mbuf, float* __restrict__ Nbuf)
{
  __shared__ u16 KscT[64][72];
  __shared__ u16 WT[64][72];
  __shared__ u16 UT[64][72];
  __shared__ float gcs[64];
  const int bhc = blockIdx.x;
  const int bh = bhc >> 5, c = bhc & 31;
  const int b = bh >> 4, h = bh & 15;
  const int tid = threadIdx.x;
  const int lane = tid & 63, wave = tid >> 6;
  const int lr = lane & 15, lkq = lane >> 4;
  const size_t rowbase = ((size_t)b*T_ + c*64)*H_ + h;
  if (tid < 64) gcs[tid] = Gcum[(size_t)bhc*64 + tid];
  __syncthreads();
  const float gC = gcs[63];
  for (int e4 = tid; e4 < 1024; e4 += 256) {
    int t = e4 >> 4, a4 = (e4 & 15) * 4;
    float sc = __expf(gC - gcs[t]);
    float4 kv = *(const float4*)&Kc[(rowbase + (size_t)t*H_)*64 + a4];
    KscT[a4+0][t] = f2bf(sc*kv.x); KscT[a4+1][t] = f2bf(sc*kv.y);
    KscT[a4+2][t] = f2bf(sc*kv.z); KscT[a4+3][t] = f2bf(sc*kv.w);
    float4 wv = *(const float4*)&Wbuf[(size_t)bhc*4096 + (size_t)t*64 + a4];
    WT[a4+0][t] = f2bf(wv.x); WT[a4+1][t] = f2bf(wv.y);
    WT[a4+2][t] = f2bf(wv.z); WT[a4+3][t] = f2bf(wv.w);
    float4 uv = *(const float4*)&Ubuf[(size_t)bhc*4096 + (size_t)t*64 + a4];
    UT[a4+0][t] = f2bf(uv.x); UT[a4+1][t] = f2bf(uv.y);
    UT[a4+2][t] = f2bf(uv.z); UT[a4+3][t] = f2bf(uv.w);
  }
  __syncthreads();

  bf16x8 af[2];
  #pragma unroll
  for (int ks = 0; ks < 2; ++ks)
    af[ks] = *(const bf16x8*)&KscT[16*wave + lr][ks*32 + lkq*8];
  const float bC = __expf(gC);
  const size_t ob = (size_t)bhc * 4096;
  #pragma unroll
  for (int j = 0; j < 4; ++j) {
    f32x4 aM = f32x4{0.f,0.f,0.f,0.f}, aN = f32x4{0.f,0.f,0.f,0.f};
    #pragma unroll
    for (int ks = 0; ks < 2; ++ks) {
      bf16x8 bw = *(const bf16x8*)&WT[16*j + lr][ks*32 + lkq*8];
      bf16x8 bu = *(const bf16x8*)&UT[16*j + lr][ks*32 + lkq*8];
      aM = __builtin_amdgcn_mfma_f32_16x16x32_bf16(af[ks], bw, aM, 0, 0, 0);
      aN = __builtin_amdgcn_mfma_f32_16x16x32_bf16(af[ks], bu, aN, 0, 0, 0);
    }
    const int cc = 16*j + lr;
    #pragma unroll
    for (int r = 0; r < 4; ++r) {
      const int a = 16*wave + lkq*4 + r;
      Mbuf[ob + (size_t)a*64 + cc] = (a == cc ? bC : 0.f) - aM[r];
      Nbuf[ob + (size_t)a*64 + cc] = aN[r];
    }
  }
}

// ---------------- pscanA: in-place group-of-4 prefix composition ----------------
__global__ __launch_bounds__(256) void pscanA(float* __restrict__ Mbuf,
    float* __restrict__ Nbuf)
{
  __shared__ float OM[2][64][68];
  __shared__ float ON[2][64][68];
  __shared__ float NM[2][64][68];
  const int blk = blockIdx.x;            // 32 bh * 8 groups
  const int bh = blk >> 3, g = blk & 7;
  const size_t s0 = ((size_t)bh * 32 + g * 4) * 4096;
  const int tid = threadIdx.x;
  const int p0 = (tid >> 4) * 4;
  const int q0 = (tid & 15) * 4;
  for (int e4 = tid; e4 < 1024; e4 += 256) {
    int r = e4 >> 4, c4 = (e4 & 15) * 4;
    *(float4*)&OM[0][r][c4] = *(const float4*)&Mbuf[s0 + (size_t)r*64 + c4];
    *(float4*)&ON[0][r][c4] = *(const float4*)&Nbuf[s0 + (size_t)r*64 + c4];
    *(float4*)&NM[0][r][c4] = *(const float4*)&Mbuf[s0 + 4096 + (size_t)r*64 + c4];
  }
  __syncthreads();
  for (int s = 0; s < 3; ++s) {
    const int cur = s & 1, nxt = cur ^ 1;
    const size_t wslot = s0 + (size_t)(s + 1) * 4096;
    if (s < 2) {
      for (int e4 = tid; e4 < 1024; e4 += 256) {
        int r = e4 >> 4, c4 = (e4 & 15) * 4;
        *(float4*)&NM[nxt][r][c4] = *(const float4*)&Mbuf[wslot + 4096 + (size_t)r*64 + c4];
      }
    }
    float aM[4][4], aN[4][4];
    #pragma unroll
    for (int r = 0; r < 4; ++r) {
      float4 nv = *(const float4*)&Nbuf[wslot + (size_t)(p0+r)*64 + q0];
      aM[r][0]=0.f; aM[r][1]=0.f; aM[r][2]=0.f; aM[r][3]=0.f;
      aN[r][0]=nv.x; aN[r][1]=nv.y; aN[r][2]=nv.z; aN[r][3]=nv.w;
    }
    for (int m4 = 0; m4 < 64; m4 += 4) {
      float xv[4][4];
      #pragma unroll
      for (int r = 0; r < 4; ++r) {
        float4 v = *(const float4*)&NM[cur][p0+r][m4];
        xv[r][0]=v.x; xv[r][1]=v.y; xv[r][2]=v.z; xv[r][3]=v.w;
      }
      #pragma unroll
      for (int mm = 0; mm < 4; ++mm) {
        float4 ym = *(const float4*)&OM[cur][m4+mm][q0];
        float4 yn = *(const float4*)&ON[cur][m4+mm][q0];
        #pragma unroll
        for (int r = 0; r < 4; ++r) {
          aM[r][0] = fmaf(xv[r][mm], ym.x, aM[r][0]);
          aM[r][1] = fmaf(xv[r][mm], ym.y, aM[r][1]);
          aM[r][2] = fmaf(xv[r][mm], ym.z, aM[r][2]);
          aM[r][3] = fmaf(xv[r][mm], ym.w, aM[r][3]);
          aN[r][0] = fmaf(xv[r][mm], yn.x, aN[r][0]);
          aN[r][1] = fmaf(xv[r][mm], yn.y, aN[r][1]);
          aN[r][2] = fmaf(xv[r][mm], yn.z, aN[r][2]);
          aN[r][3] = fmaf(xv[r][mm], yn.w, aN[r][3]);
        }
      }
    }
    #pragma unroll
    for (int r = 0; r < 4; ++r) {
      float4 vm = {aM[r][0], aM[r][1], aM[r][2], aM[r][3]};
      float4 vn = {aN[r][0], aN[r][1], aN[r][2], aN[r][3]};
      *(float4*)&Mbuf[wslot + (size_t)(p0+r)*64 + q0] = vm;
      *(float4*)&Nbuf[wslot + (size_t)(p0+r)*64 + q0] = vn;
      *(float4*)&OM[nxt][p0+r][q0] = vm;
      *(float4*)&ON[nxt][p0+r][q0] = vn;
    }
    __syncthreads();
  }
}

// ---------------- pscanB: serial carry over 8 group totals (ST-form) ----------------
__global__ __launch_bounds__(256) void pscanB(const float* __restrict__ Mbuf,
    const float* __restrict__ Nbuf, float* __restrict__ S0b)
{
  __shared__ float ST[2][64][68];
  __shared__ float MT[64][68];
  const int bh = blockIdx.x;
  const size_t base = (size_t)bh * 32 * 4096;
  const int tid = threadIdx.x;
  const int j0 = (tid >> 4) * 4, a0 = tid & 15;
  for (int e4 = tid; e4 < 1024; e4 += 256) {
    int r = e4 >> 4, c4 = (e4 & 15) * 4;
    *(float4*)&ST[0][r][c4] = float4{0.f, 0.f, 0.f, 0.f};
    *(float4*)&S0b[base + (size_t)r*64 + c4] = float4{0.f, 0.f, 0.f, 0.f};
  }
  for (int g = 0; g < 7; ++g) {
    const int cur = g & 1, nxt = cur ^ 1;
    const size_t tslot = base + (size_t)(4*g + 3) * 4096;
    for (int e4 = tid; e4 < 1024; e4 += 256) {
      int r = e4 >> 4, c4 = (e4 & 15) * 4;
      *(float4*)&MT[r][c4] = *(const float4*)&Mbuf[tslot + (size_t)r*64 + c4];
    }
    float acc[4][4];
    #pragma unroll
    for (int r = 0; r < 4; ++r)
      #pragma unroll
      for (int s = 0; s < 4; ++s)
        acc[r][s] = Nbuf[tslot + (size_t)(a0 + 16*s)*64 + j0 + r];
    __syncthreads();
    for (int k4 = 0; k4 < 64; k4 += 4) {
      float4 xr[4];
      #pragma unroll
      for (int r = 0; r < 4; ++r) xr[r] = *(const float4*)&ST[cur][j0+r][k4];
      #pragma unroll
      for (int s = 0; s < 4; ++s) {
        float4 yv = *(const float4*)&MT[a0 + 16*s][k4];
        #pragma unroll
        for (int r = 0; r < 4; ++r) acc[r][s] = dot4(xr[r], yv, acc[r][s]);
      }
    }
    const size_t oslot = base + (size_t)(4*(g+1)) * 4096;
    #pragma unroll
    for (int r = 0; r < 4; ++r)
      #pragma unroll
      for (int s = 0; s < 4; ++s) {
        ST[nxt][j0+r][a0 + 16*s] = acc[r][s];
        S0b[oslot + (size_t)(j0+r)*64 + a0 + 16*s] = acc[r][s];
      }
    __syncthreads();
  }
}

// ---------------- pscanC: intra-group states (parallel) ----------------
__global__ __launch_bounds__(256) void pscanC(const float* __restrict__ Mbuf,
    const float* __restrict__ Nbuf, float* __restrict__ S0b)
{
  __shared__ float ST[64][68];
  __shared__ float MT[64][68];
  const int blk = blockIdx.x;            // 32 bh * 8 groups * 3
  const int bh = blk / 24, rem = blk % 24;
  const int g = rem / 3, i = rem % 3 + 1;
  const size_t base = (size_t)bh * 32 * 4096;
  const size_t pslot = base + (size_t)(4*g + i - 1) * 4096;
  const int tid = threadIdx.x;
  const int j0 = (tid >> 4) * 4, a0 = tid & 15;
  for (int e4 = tid; e4 < 1024; e4 += 256) {
    int r = e4 >> 4, c4 = (e4 & 15) * 4;
    *(float4*)&ST[r][c4] = *(const float4*)&S0b[base + (size_t)(4*g)*4096 + (size_t)r*64 + c4];
    *(float4*)&MT[r][c4] = *(const float4*)&Mbuf[pslot + (size_t)r*64 + c4];
  }
  float acc[4][4];
  #pragma unroll
  for (int r = 0; r < 4; ++r)
    #pragma unroll
    for (int s = 0; s < 4; ++s)
      acc[r][s] = Nbuf[pslot + (size_t)(a0 + 16*s)*64 + j0 + r];
  __syncthreads();
  for (int k4 = 0; k4 < 64; k4 += 4) {
    float4 xr[4];
    #pragma unroll
    for (int r = 0; r < 4; ++r) xr[r] = *(const float4*)&ST[j0+r][k4];
    #pragma unroll
    for (int s = 0; s < 4; ++s) {
      float4 yv = *(const float4*)&MT[a0 + 16*s][k4];
      #pragma unroll
      for (int r = 0; r < 4; ++r) acc[r][s] = dot4(xr[r], yv, acc[r][s]);
    }
  }
  const size_t oslot = base + (size_t)(4*g + i) * 4096;
  #pragma unroll
  for (int r = 0; r < 4; ++r)
    #pragma unroll
    for (int s = 0; s < 4; ++s)
      S0b[oslot + (size_t)(j0+r)*64 + a0 + 16*s] = acc[r][s];
}

// ---------------- P3 (MFMA): delta + outputs + fused o-norm*swish gate -> bf16 ----------------
// O = e^{gc} Q@S0 + tril(decay o QK^T) @ (U - W@S0); og = rmsnorm(O)*onw * gv*sigmoid(gv)
__global__ __launch_bounds__(256) void p3_out(
    const float* __restrict__ Qc, const float* __restrict__ Kc,
    const float* __restrict__ Gcum, const float* __restrict__ S0b,
    const float* __restrict__ Ubuf, const float* __restrict__ Wbuf,
    const float* __restrict__ GV, const float* __restrict__ onw,
    u16* __restrict__ OG)
{
  __shared__ u16 Qbf[64][72];
  __shared__ u16 Kbf[64][72];
  __shared__ u16 S0T[64][72];
  __shared__ u16 Wbf[64][72];
  __shared__ u16 Pbf[64][72];
  __shared__ u16 DsT[64][72];
  __shared__ float gcs[64];
  __shared__ float onws[64];
  const int bhc = blockIdx.x;
  const int bh = bhc >> 5, c = bhc & 31;
  const int b = bh >> 4, h = bh & 15;
  const int tid = threadIdx.x;
  const int lane = tid & 63, wave = tid >> 6;
  const int lr = lane & 15, lkq = lane >> 4;
  const size_t rowbase = ((size_t)b*T_ + c*64)*H_ + h;
  if (tid < 64) { gcs[tid] = Gcum[(size_t)bhc*64 + tid]; onws[tid] = onw[tid]; }
  for (int e4 = tid; e4 < 1024; e4 += 256) {
    int t = e4 >> 4, d4 = (e4 & 15) * 4;
    size_t ga = (rowbase + (size_t)t*H_)*64 + d4;
    float4 qv = *(const float4*)&Qc[ga];
    float4 kv = *(const float4*)&Kc[ga];
    float4 sv = *(const float4*)&S0b[(size_t)bhc*4096 + (size_t)t*64 + d4];
    float4 wv = *(const float4*)&Wbuf[(size_t)bhc*4096 + (size_t)t*64 + d4];
    u16 aq[4] = {f2bf(qv.x), f2bf(qv.y), f2bf(qv.z), f2bf(qv.w)};
    u16 ak[4] = {f2bf(kv.x), f2bf(kv.y), f2bf(kv.z), f2bf(kv.w)};
    u16 as[4] = {f2bf(sv.x), f2bf(sv.y), f2bf(sv.z), f2bf(sv.w)};
    u16 aw[4] = {f2bf(wv.x), f2bf(wv.y), f2bf(wv.z), f2bf(wv.w)};
    *(uint2*)&Qbf[t][d4] = *(uint2*)aq;
    *(uint2*)&Kbf[t][d4] = *(uint2*)ak;
    *(uint2*)&S0T[t][d4] = *(uint2*)as;
    *(uint2*)&Wbf[t][d4] = *(uint2*)aw;
  }
  __syncthreads();

  const int trow0 = 16*wave + lkq*4;
  bf16x8 aq[2], aw[2];
  #pragma unroll
  for (int ks = 0; ks < 2; ++ks) {
    aq[ks] = *(const bf16x8*)&Qbf[16*wave + lr][ks*32 + lkq*8];
    aw[ks] = *(const bf16x8*)&Wbf[16*wave + lr][ks*32 + lkq*8];
  }
  float gct[4], egt[4];
  #pragma unroll
  for (int r = 0; r < 4; ++r) { gct[r] = gcs[trow0 + r]; egt[r] = __expf(gct[r]); }

  // Phase B: P[t][s] = (s<=t) e^{gc_t-gc_s} q_t.k_s
  #pragma unroll
  for (int j = 0; j < 4; ++j) {
    f32x4 pa = f32x4{0.f,0.f,0.f,0.f};
    #pragma unroll
    for (int ks = 0; ks < 2; ++ks) {
      bf16x8 bk = *(const bf16x8*)&Kbf[16*j + lr][ks*32 + lkq*8];
      pa = __builtin_amdgcn_mfma_f32_16x16x32_bf16(aq[ks], bk, pa, 0, 0, 0);
    }
    const int s = 16*j + lr;
    const float gs = gcs[s];
    #pragma unroll
    for (int r = 0; r < 4; ++r) {
      const int t = trow0 + r;
      float val = (s <= t) ? __expf(gct[r] - gs) * pa[r] : 0.f;
      Pbf[t][s] = f2bf(val);
    }
  }

  // Phase D: delta[s][j] = U[s][j] - (W@S0)[s][j], store DsT[j][s]
  #pragma unroll
  for (int j = 0; j < 4; ++j) {
    f32x4 da = f32x4{0.f,0.f,0.f,0.f};
    #pragma unroll
    for (int ks = 0; ks < 2; ++ks) {
      bf16x8 bs = *(const bf16x8*)&S0T[16*j + lr][ks*32 + lkq*8];
      da = __builtin_amdgcn_mfma_f32_16x16x32_bf16(aw[ks], bs, da, 0, 0, 0);
    }
    const int jj = 16*j + lr;
    #pragma unroll
    for (int r = 0; r < 4; ++r) {
      const int s = trow0 + r;
      float dv = Ubuf[(size_t)bhc*4096 + (size_t)s*64 + jj] - da[r];
      DsT[jj][s] = f2bf(dv);
    }
  }

  // Phase A: oacc = e^{gc_t} * (Q @ S0)
  f32x4 oacc[4];
  #pragma unroll
  for (int j = 0; j < 4; ++j) {
    f32x4 oa = f32x4{0.f,0.f,0.f,0.f};
    #pragma unroll
    for (int ks = 0; ks < 2; ++ks) {
      bf16x8 bs = *(const bf16x8*)&S0T[16*j + lr][ks*32 + lkq*8];
      oa = __builtin_amdgcn_mfma_f32_16x16x32_bf16(aq[ks], bs, oa, 0, 0, 0);
    }
    #pragma unroll
    for (int r = 0; r < 4; ++r) oa[r] *= egt[r];
    oacc[j] = oa;
  }
  __syncthreads();   // DsT complete across waves (Pbf is wave-local)

  // Phase C: oacc += P @ delta
  bf16x8 ap[2];
  #pragma unroll
  for (int ks = 0; ks < 2; ++ks)
    ap[ks] = *(const bf16x8*)&Pbf[16*wave + lr][ks*32 + lkq*8];
  #pragma unroll
  for (int j = 0; j < 4; ++j) {
    #pragma unroll
    for (int ks = 0; ks < 2; ++ks) {
      bf16x8 bd = *(const bf16x8*)&DsT[16*j + lr][ks*32 + lkq*8];
      oacc[j] = __builtin_amdgcn_mfma_f32_16x16x32_bf16(ap[ks], bd, oacc[j], 0, 0, 0);
    }
  }

  // Fused ogate: RMSNorm over row (64 cols spread over 4 regs x 16 lanes) + swish gate
  #pragma unroll
  for (int r = 0; r < 4; ++r) {
    float ss = 0.f;
    #pragma unroll
    for (int jq = 0; jq < 4; ++jq) ss = fmaf(oacc[jq][r], oacc[jq][r], ss);
    ss += __shfl_xor(ss, 1); ss += __shfl_xor(ss, 2);
    ss += __shfl_xor(ss, 4); ss += __shfl_xor(ss, 8);
    const float inv = rsqrtf(ss * (1.f/64.f) + 1e-6f);
    const int t = trow0 + r;
    const size_t rowoff = ((size_t)b*T_ + (size_t)c*64 + t) * D_ + h*64;
    #pragma unroll
    for (int jq = 0; jq < 4; ++jq) {
      const int jj = 16*jq + lr;
      float y = oacc[jq][r] * inv * onws[jj];
      float gv = GV[rowoff + jj];
      OG[rowoff + jj] = f2bf(y * gv / (1.f + __expf(-gv)));
    }
  }
}

extern "C" void kernel_launch(void* const* d_in, const int* in_sizes, int n_in,
                              void* d_out, int out_size, void* d_ws, size_t ws_size,
                              hipStream_t stream) {
  const float* h    = (const float*)d_in[0];
  const float* Wq   = (const float*)d_in[1];
  const float* Wk   = (const float*)d_in[2];
  const float* Wv   = (const float*)d_in[3];
  const float* Wa   = (const float*)d_in[4];
  const float* Wb   = (const float*)d_in[5];
  const float* Wg   = (const float*)d_in[6];
  const float* Wo   = (const float*)d_in[7];
  const float* qnw  = (const float*)d_in[8];
  const float* knw  = (const float*)d_in[9];
  const float* onw  = (const float*)d_in[10];
  const float* Alog = (const float*)d_in[11];
  const float* dtb  = (const float*)d_in[12];
  const float* cqw  = (const float*)d_in[13];
  const float* ckw  = (const float*)d_in[14];
  const float* cvw  = (const float*)d_in[15];
  float* out = (float*)d_out;
  float* ws  = (float*)d_ws;

  const size_t NB = (size_t)B_ * T_ * D_;
  float* qp   = ws;
  float* kp   = ws + 1*NB;
  float* vp   = ws + 2*NB;
  float* gvp  = ws + 3*NB;
  float* qc   = ws + 4*NB;
  float* kc   = ws + 5*NB;
  float* vc   = ws + 6*NB;
  float* mb   = ws + 7*NB;
  float* wbf  = ws + 8*NB;
  float* gb   = ws + 8*NB + 5*524288;
  float* bb   = gb + (size_t)B_*T_*H_;
  float* Gc   = bb + (size_t)B_*T_*H_;

  u16* h_bf  = (u16*)mb;
  u16* og_bf = (u16*)mb;
  u16* w_bf  = (u16*)wbf;
  u16* wq_bf = w_bf + 0*1048576;
  u16* wk_bf = w_bf + 1*1048576;
  u16* wv_bf = w_bf + 2*1048576;
  u16* wg_bf = w_bf + 3*1048576;
  u16* wo_bf = w_bf + 4*1048576;

  float* Ubuf = qp;
  float* Wbuf = kp;
  float* S0b  = vp;
  float* Mbuf = mb;
  float* Nbuf = vc;

  cvt_all<<<4608, 256, 0, stream>>>(h, Wq, Wk, Wv, Wg, Wo, h_bf, w_bf);

  gemm_bf16_4<<<dim3(32, 32), 256, 0, stream>>>(h_bf, wq_bf, wk_bf, wv_bf, wg_bf,
                                                 qp, kp, vp, gvp);
  smallproj<<<B_ * T_, 256, 0, stream>>>(h, Wa, Wb, Alog, dtb, gb, bb);

  convnorm3<<<3072, 256, 0, stream>>>(qp, kp, vp, cqw, ckw, cvw, qnw, knw,
                                      qc, kc, vc);

  p1_chunk<<<B_*H_*NC_, 256, 0, stream>>>(kc, vc, gb, bb, Ubuf, Wbuf, Gc);
  p1b_mn<<<B_*H_*NC_, 256, 0, stream>>>(kc, Gc, Ubuf, Wbuf, Mbuf, Nbuf);
  pscanA<<<B_*H_*8, 256, 0, stream>>>(Mbuf, Nbuf);
  pscanB<<<B_*H_, 256, 0, stream>>>(Mbuf, Nbuf, S0b);
  pscanC<<<B_*H_*24, 256, 0, stream>>>(Mbuf, Nbuf, S0b);
  p3_out<<<B_*H_*NC_, 256, 0, stream>>>(qc, kc, Gc, S0b, Ubuf, Wbuf,
                                        gvp, onw, og_bf);

  gemm_bf16_1<<<dim3(32, 8), 256, 0, stream>>>(og_bf, wo_bf, out);
}